// Round 14
// baseline (108.867 us; speedup 1.0000x reference)
//
#include <hip/hip_runtime.h>

typedef __attribute__((ext_vector_type(8))) short bf16x8;
typedef __attribute__((ext_vector_type(4))) float f32x4;

#define D_MODEL 256
#define SEQ     1024
#define NROWS   8192

__device__ __forceinline__ ushort f2bf(float f) {
  unsigned u = __float_as_uint(f);
  unsigned r = (u + 0x7FFFu + ((u >> 16) & 1u)) >> 16;
  return (ushort)r;
}
__device__ __forceinline__ float bf2f(ushort b) {
  return __uint_as_float(((unsigned)b) << 16);
}

// async global->LDS, 16B per lane; dst = wave-uniform base + lane*16
__device__ __forceinline__ void gld_lds16(const void* g, void* l) {
  __builtin_amdgcn_global_load_lds(
      (const __attribute__((address_space(1))) void*)g,
      (__attribute__((address_space(3))) void*)l, 16, 0, 0);
}

// XOR-swizzle of 8-element blocks within 64-col groups
__device__ __forceinline__ int swz(int col, int row7) {
  return (col & ~63) | ((((col >> 3) & 7) ^ row7) << 3) | (col & 7);
}

#define QSC 0.25507964954389985f   // log2(e) / sqrt(32)

// -------- 0. prep: weights fp32 -> bf16 pre-swizzled  +  pos table (8K distinct) --------
__global__ __launch_bounds__(256) void prep_kernel(
    const float* __restrict__ a, const float* __restrict__ b,
    const float* __restrict__ c, const float* __restrict__ d,
    ushort* __restrict__ oa, ushort* __restrict__ ob,
    ushort* __restrict__ oc, ushort* __restrict__ od,
    float* __restrict__ pos2)
{
  int i = blockIdx.x * 256 + threadIdx.x;  // 262144 total
  if (i < 196608) { int r = i >> 8, k = i & 255; oa[(r << 8) + swz(k, r & 7)] = f2bf(a[i]); }
  if (i <  65536) { int r = i >> 8, k = i & 255; ob[(r << 8) + swz(k, r & 7)] = f2bf(b[i]); }
  { int r = i >> 8,  k = i & 255;  oc[(r << 8)  + swz(k, r & 7)] = f2bf(c[i]); }
  { int r = i >> 10, k = i & 1023; od[(r << 10) + swz(k, r & 7)] = f2bf(d[i]); }
  // pos2[part][hw][cidx]: part 0 = y-enc (uses h), part 1 = x-enc (uses w)
  if (i < 8192) {
    int rem = i & 4095, hw = rem >> 7, cidx = rem & 127;
    const float sc = 6.28318530717958647692f / (32.0f + 1e-6f);
    float e = (float)(hw + 1) * sc;
    int j = cidx >> 1;
    float arg = e * exp2f((float)j * -0.20762050593046014f);  // 10000^(-j/64)
    pos2[i] = (cidx & 1) ? cosf(arg) : sinf(arg);
  }
}

// -------- 1. f_bf[row][swz(c)] = transpose(x/y) + 0.1*pos  (bf16 only) --------
__global__ __launch_bounds__(256) void build_f_kernel(
    const float* __restrict__ x, const float* __restrict__ y,
    const float* __restrict__ pos2, ushort* __restrict__ fb)
{
  __shared__ float T[64][65];
  int bx = blockIdx.x;                    // 8b * 16st * 4ct = 512
  int b = bx >> 6, st = (bx >> 2) & 15, ct = bx & 3;
  const float* src = (b < 4) ? x : y;
  int bb = b & 3;
  int tid = threadIdx.x;
  {
    int sl = tid & 63, c4 = tid >> 6;
    int s = st * 64 + sl;
    #pragma unroll
    for (int k = 0; k < 16; ++k) {
      int cl = c4 * 16 + k;
      T[cl][sl] = src[((size_t)((bb << 8) + ct * 64 + cl) << 10) + s];
    }
  }
  __syncthreads();
  {
    int cl = tid & 63, s4 = tid >> 6;
    int c = ct * 64 + cl;
    const float* pt = pos2 + (c >= 128 ? 4096 : 0) + (c & 127);
    #pragma unroll
    for (int k = 0; k < 16; ++k) {
      int sl = s4 * 16 + k;
      int s = st * 64 + sl;
      int hw = (c >= 128) ? (s & 31) : (s >> 5);
      float v = T[cl][sl] + 0.1f * pt[hw * 128];
      size_t row = (size_t)b * 1024 + s;
      fb[row * 256 + swz(c, s & 7)] = f2bf(v);
    }
  }
}

// -------- 2. MFMA GEMM (BN=128), global_load_lds, pre-swizzled inputs --------
// OUT_MODE: 2 = bf16 swizzled, 3 = qkv fused (Q scaled + linear, K linear, V -> vt swizzled)
template<int BM, int OUT_MODE, int RELU>
__global__ __launch_bounds__(256) void gemm_mfma_kernel(
    const ushort* __restrict__ A, const ushort* __restrict__ B,
    const float* __restrict__ bias, void* __restrict__ Cout,
    ushort* __restrict__ Vout, int M, int N, int K)
{
  constexpr int MI = BM / 32;
  __shared__ ushort Asw[BM * 64];
  __shared__ ushort Bsw[128 * 64];
  const int tid = threadIdx.x, lane = tid & 63, w = tid >> 6;
  const int m0 = blockIdx.y * BM, n0 = blockIdx.x * 128;
  const int wm0 = (w & 1) * (BM / 2), wn0 = (w >> 1) * 64;
  const int l15 = lane & 15, g = lane >> 4;
  const int r8 = lane >> 3, s8 = lane & 7;
  f32x4 acc[MI][4];
  #pragma unroll
  for (int i = 0; i < MI; ++i)
    #pragma unroll
    for (int j = 0; j < 4; ++j) acc[i][j] = (f32x4){0.f, 0.f, 0.f, 0.f};

  for (int kt = 0; kt < K; kt += 64) {
    __syncthreads();
    #pragma unroll
    for (int i = 0; i < BM / 32; ++i) {
      int row0 = w * (BM / 4) + i * 8;
      gld_lds16(A + (size_t)(m0 + row0 + r8) * K + kt + s8 * 8, &Asw[row0 * 64]);
    }
    #pragma unroll
    for (int i = 0; i < 4; ++i) {
      int row0 = w * 32 + i * 8;
      gld_lds16(B + (size_t)(n0 + row0 + r8) * K + kt + s8 * 8, &Bsw[row0 * 64]);
    }
    __syncthreads();
    #pragma unroll
    for (int ks = 0; ks < 2; ++ks) {
      bf16x8 af[MI], bfr[4];
      #pragma unroll
      for (int i = 0; i < MI; ++i) {
        int ra = wm0 + i * 16 + l15;
        af[i] = *(const bf16x8*)&Asw[ra * 64 + (((ks * 4 + g) ^ (ra & 7)) * 8)];
      }
      #pragma unroll
      for (int i = 0; i < 4; ++i) {
        int rb = wn0 + i * 16 + l15;
        bfr[i] = *(const bf16x8*)&Bsw[rb * 64 + (((ks * 4 + g) ^ (rb & 7)) * 8)];
      }
      __builtin_amdgcn_s_setprio(1);
      #pragma unroll
      for (int mi = 0; mi < MI; ++mi)
        #pragma unroll
        for (int ni = 0; ni < 4; ++ni)
          acc[mi][ni] = __builtin_amdgcn_mfma_f32_16x16x32_bf16(
              af[mi], bfr[ni], acc[mi][ni], 0, 0, 0);
      __builtin_amdgcn_s_setprio(0);
    }
  }

  float bv[4];
  #pragma unroll
  for (int ni = 0; ni < 4; ++ni) bv[ni] = bias[n0 + wn0 + ni * 16 + l15];
  #pragma unroll
  for (int mi = 0; mi < MI; ++mi)
    #pragma unroll
    for (int ni = 0; ni < 4; ++ni) {
      int n = n0 + wn0 + ni * 16 + l15;
      float qs = (OUT_MODE == 3 && n < 256) ? QSC : 1.0f;   // fold softmax scale into Q
      float v4[4];
      #pragma unroll
      for (int r = 0; r < 4; ++r) {
        float v = acc[mi][ni][r] + bv[ni];
        if (RELU) v = fmaxf(v, 0.0f);
        v4[r] = v * qs;
      }
      int mb = m0 + wm0 + mi * 16 + g * 4;       // first of 4 consecutive rows
      if (OUT_MODE == 3 && n >= 512) {
        // V column -> vt[bh][d][t], 8-block XOR swizzle on t within 64-groups
        int d = (n - 512) & 31, hh = (n - 512) >> 5;
        int bb = mb >> 10, t0 = mb & 1023;
        uint2 val;
        val.x = (unsigned)f2bf(v4[0]) | ((unsigned)f2bf(v4[1]) << 16);
        val.y = (unsigned)f2bf(v4[2]) | ((unsigned)f2bf(v4[3]) << 16);
        size_t idx = ((size_t)(bb * 8 + hh) * 32 + d) * 1024 + (t0 & ~63)
                   + ((((t0 >> 3) & 7) ^ (d & 7)) * 8) + (t0 & 7);
        *(uint2*)&Vout[idx] = val;
      } else {
        #pragma unroll
        for (int r = 0; r < 4; ++r) {
          size_t m = mb + r;
          if (OUT_MODE == 3) ((ushort*)Cout)[m * N + n] = f2bf(v4[r]);
          else               ((ushort*)Cout)[m * N + swz(n, (int)(m & 7))] = f2bf(v4[r]);
        }
      }
    }
}

// -------- 2b. GEMM (BM=32, BN=256=N) + fused residual + LayerNorm, 8 waves --------
// TRANS_OUT=0: outb = bf16 swizzled.  TRANS_OUT=1: transposed f32 d_out (coalesced via LDS).
template<int TRANS_OUT>
__global__ __launch_bounds__(512) void gemm_ln_kernel(
    const ushort* __restrict__ A, const ushort* __restrict__ B,
    const float* __restrict__ bias, const ushort* __restrict__ R,
    const float* __restrict__ gamma, const float* __restrict__ beta,
    float* __restrict__ out, ushort* __restrict__ outb, int K)
{
  __shared__ ushort Asw[32 * 64];
  __shared__ ushort Bsw[256 * 64];     // 32 KB; reused as f32 transpose tile in epilogue
  __shared__ float red[8][32][2];
  const int tid = threadIdx.x, lane = tid & 63, w = tid >> 6;   // w 0..7
  const int l15 = lane & 15, g4 = lane >> 4;
  const int r8 = lane >> 3, s8 = lane & 7;
  const int m0 = blockIdx.x * 32;
  const int wn0 = w * 32;
  f32x4 acc[2][2];
  #pragma unroll
  for (int i = 0; i < 2; ++i)
    #pragma unroll
    for (int j = 0; j < 2; ++j) acc[i][j] = (f32x4){0.f, 0.f, 0.f, 0.f};

  for (int kt = 0; kt < K; kt += 64) {
    __syncthreads();
    if (w < 4)
      gld_lds16(A + (size_t)(m0 + w * 8 + r8) * K + kt + s8 * 8, &Asw[(w * 8) * 64]);
    #pragma unroll
    for (int i = 0; i < 4; ++i) {
      int row0 = w * 32 + i * 8;
      gld_lds16(B + (size_t)(row0 + r8) * K + kt + s8 * 8, &Bsw[row0 * 64]);
    }
    __syncthreads();
    #pragma unroll
    for (int ks = 0; ks < 2; ++ks) {
      bf16x8 af[2], bfr[2];
      #pragma unroll
      for (int mi = 0; mi < 2; ++mi) {
        int ra = mi * 16 + l15;
        af[mi] = *(const bf16x8*)&Asw[ra * 64 + (((ks * 4 + g4) ^ (ra & 7)) * 8)];
      }
      #pragma unroll
      for (int ni = 0; ni < 2; ++ni) {
        int rb = wn0 + ni * 16 + l15;
        bfr[ni] = *(const bf16x8*)&Bsw[rb * 64 + (((ks * 4 + g4) ^ (rb & 7)) * 8)];
      }
      __builtin_amdgcn_s_setprio(1);
      #pragma unroll
      for (int mi = 0; mi < 2; ++mi)
        #pragma unroll
        for (int ni = 0; ni < 2; ++ni)
          acc[mi][ni] = __builtin_amdgcn_mfma_f32_16x16x32_bf16(
              af[mi], bfr[ni], acc[mi][ni], 0, 0, 0);
      __builtin_amdgcn_s_setprio(0);
    }
  }

  float bv[2], gv[2], bev[2];
  #pragma unroll
  for (int ni = 0; ni < 2; ++ni) {
    int n = wn0 + ni * 16 + l15;
    bv[ni] = bias[n]; gv[ni] = gamma[n]; bev[ni] = beta[n];
  }
  float s1[2][4], s2[2][4];
  #pragma unroll
  for (int mi = 0; mi < 2; ++mi)
    #pragma unroll
    for (int r = 0; r < 4; ++r) { s1[mi][r] = 0.f; s2[mi][r] = 0.f; }
  #pragma unroll
  for (int mi = 0; mi < 2; ++mi)
    #pragma unroll
    for (int ni = 0; ni < 2; ++ni)
      #pragma unroll
      for (int r = 0; r < 4; ++r) {
        int row = m0 + mi * 16 + g4 * 4 + r;
        int col = wn0 + ni * 16 + l15;
        float v = acc[mi][ni][r] + bv[ni] + bf2f(R[(size_t)row * 256 + swz(col, row & 7)]);
        acc[mi][ni][r] = v;
        s1[mi][r] += v;
        s2[mi][r] += v * v;
      }
  #pragma unroll
  for (int mi = 0; mi < 2; ++mi)
    #pragma unroll
    for (int r = 0; r < 4; ++r) {
      #pragma unroll
      for (int d = 1; d < 16; d <<= 1) {
        s1[mi][r] += __shfl_xor(s1[mi][r], d);
        s2[mi][r] += __shfl_xor(s2[mi][r], d);
      }
    }
  if (l15 == 0) {
    #pragma unroll
    for (int mi = 0; mi < 2; ++mi)
      #pragma unroll
      for (int r = 0; r < 4; ++r) {
        int rl = mi * 16 + g4 * 4 + r;
        red[w][rl][0] = s1[mi][r];
        red[w][rl][1] = s2[mi][r];
      }
  }
  __syncthreads();     // also guards Bsw reuse below (all K-loop reads done)
  float* Tr = (float*)Bsw;
  #pragma unroll
  for (int mi = 0; mi < 2; ++mi)
    #pragma unroll
    for (int r = 0; r < 4; ++r) {
      int rl = mi * 16 + g4 * 4 + r;
      float t1 = 0.f, t2 = 0.f;
      #pragma unroll
      for (int ww = 0; ww < 8; ++ww) { t1 += red[ww][rl][0]; t2 += red[ww][rl][1]; }
      float mu = t1 * (1.0f / 256.0f);
      float var = t2 * (1.0f / 256.0f) - mu * mu;
      float rstd = rsqrtf(var + 1e-5f);
      int row = m0 + rl;
      #pragma unroll
      for (int ni = 0; ni < 2; ++ni) {
        int col = wn0 + ni * 16 + l15;
        float res = (acc[mi][ni][r] - mu) * rstd * gv[ni] + bev[ni];
        if (!TRANS_OUT) {
          outb[(size_t)row * 256 + swz(col, row & 7)] = f2bf(res);
        } else {
          Tr[rl * 256 + col] = res;
        }
      }
    }
  if (TRANS_OUT) {
    __syncthreads();
    int b = m0 >> 10, sq0 = m0 & 1023;
    int c = tid & 255, half = tid >> 8;
    float* dst = out + ((size_t)b << 18) + ((size_t)c << 10) + sq0 + half * 16;
    #pragma unroll
    for (int st = 0; st < 4; ++st) {
      float4 v;
      v.x = Tr[(half * 16 + st * 4 + 0) * 256 + c];
      v.y = Tr[(half * 16 + st * 4 + 1) * 256 + c];
      v.z = Tr[(half * 16 + st * 4 + 2) * 256 + c];
      v.w = Tr[(half * 16 + st * 4 + 3) * 256 + c];
      *(float4*)(dst + st * 4) = v;
    }
  }
}

// -------- 3. MFMA flash attention: 4 waves, 64 q-rows, KVBLK=128, no-max softmax --------
__global__ __launch_bounds__(256) void attn_mfma_kernel(
    const ushort* __restrict__ qkv, const ushort* __restrict__ vtg,
    ushort* __restrict__ att)
{
  __shared__ ushort Ks[2][64 * 64];    // 16 KB: [64 r2][64] view of 128 K rows
  __shared__ ushort Vt[2][32 * 128];   // 16 KB
  __shared__ ushort Ps[4][16 * 64];    // 8 KB: per-wave [q=16][t'=64], tblk XOR swizzle
  const int tid = threadIdx.x, lane = tid & 63, w = tid >> 6;
  const int l15 = lane & 15, g = lane >> 4;
  const int qt = blockIdx.x, h = blockIdx.y, b = blockIdx.z;
  const size_t base = (size_t)b * SEQ * 768;
  const int q0 = qt * 64;
  const int bh = b * 8 + h;

  // Q fragment (pre-scaled by log2e/sqrt(32) in the QKV epilogue)
  bf16x8 qf = *(const bf16x8*)&qkv[base + (size_t)(q0 + w * 16 + l15) * 768 + h * 32 + g * 8];

  // K staging lane map (per 16-row chunk): [r2][slot], slot' = slot ^ (r2&7)
  const int kr2l  = lane >> 3;
  const int kslot = (lane & 7) ^ kr2l;
  const int krow  = 2 * kr2l + (kslot >> 2);
  const int kdoff = (kslot & 3) * 8;
  const int vd    = lane >> 4;          // V: d sub-row 0..3
  const int vt8   = (lane & 15) * 8;    // V: t offset

  float l_ = 0.f;
  f32x4 o[2];
  o[0] = (f32x4){0.f, 0.f, 0.f, 0.f};
  o[1] = (f32x4){0.f, 0.f, 0.f, 0.f};
  const f32x4 zero = (f32x4){0.f, 0.f, 0.f, 0.f};

  // Ps addresses (q = l15); write: tblk = 2*tt + (g>>1), dword slot (g&1)
  ushort* psw = &Ps[w][0];
  const int ps_q = l15 * 64;

  // stage tile 0
  #pragma unroll
  for (int i = 0; i < 2; ++i) {
    gld_lds16(qkv + base + (size_t)(w * 32 + i * 16 + krow) * 768 + 256 + h * 32 + kdoff,
              &Ks[0][(w * 16 + i * 8) * 64]);
    gld_lds16(vtg + ((size_t)bh * 32 + w * 8 + i * 4 + vd) * 1024 + vt8,
              &Vt[0][(w * 8 + i * 4) * 128]);
  }
  __syncthreads();

  int cur = 0;
  for (int t = 0; t < 8; ++t) {
    if (t < 7) {                         // prefetch next 128-row K/V tile
      int nkv = (t + 1) * 128;
      #pragma unroll
      for (int i = 0; i < 2; ++i) {
        gld_lds16(qkv + base + (size_t)(nkv + w * 32 + i * 16 + krow) * 768 + 256 + h * 32 + kdoff,
                  &Ks[cur ^ 1][(w * 16 + i * 8) * 64]);
        gld_lds16(vtg + ((size_t)bh * 32 + w * 8 + i * 4 + vd) * 1024 + nkv + vt8,
                  &Vt[cur ^ 1][(w * 8 + i * 4) * 128]);
      }
    }
    // S^T = K . Q^T : lane owns q = l15, t-rows ti*16 + g*4 + r, ti 0..7
    f32x4 s[8];
    __builtin_amdgcn_s_setprio(1);
    #pragma unroll
    for (int ti = 0; ti < 8; ++ti) {
      int r2   = ti * 8 + (l15 >> 1);
      int slot = (((l15 & 1) * 4 + g)) ^ (l15 >> 1);
      bf16x8 kf = *(const bf16x8*)&Ks[cur][r2 * 64 + slot * 8];
      s[ti] = __builtin_amdgcn_mfma_f32_16x16x32_bf16(kf, qf, zero, 0, 0, 0);
    }
    __builtin_amdgcn_s_setprio(0);

    // no-max softmax (scores log2-scaled, tiny variance -> exp2 can't overflow);
    // l_ accumulated per-lane, reduced ONCE after the loop.
    #pragma unroll
    for (int ti = 0; ti < 8; ++ti)
      #pragma unroll
      for (int r = 0; r < 4; ++r) {
        float p = __builtin_amdgcn_exp2f(s[ti][r]);
        s[ti][r] = p;
        l_ += p;
      }

    // V fragments (global ks 0..3)
    bf16x8 vb[4][2];
    #pragma unroll
    for (int ks = 0; ks < 4; ++ks)
      #pragma unroll
      for (int di = 0; di < 2; ++di) {
        int d = di * 16 + l15;
        vb[ks][di] = *(const bf16x8*)&Vt[cur][d * 128 + (ks >> 1) * 64 +
                                             ((((ks & 1) * 4 + g) ^ (d & 7)) * 8)];
      }

    // two half-passes over t: pack P -> wave-private swizzled LDS -> b128 A-frags
    #pragma unroll
    for (int p = 0; p < 2; ++p) {
      #pragma unroll
      for (int tt = 0; tt < 4; ++tt) {
        int ti = p * 4 + tt;
        unsigned lo, hi;
        asm("v_cvt_pk_bf16_f32 %0, %1, %2" : "=v"(lo) : "v"(s[ti][0]), "v"(s[ti][1]));
        asm("v_cvt_pk_bf16_f32 %0, %1, %2" : "=v"(hi) : "v"(s[ti][2]), "v"(s[ti][3]));
        uint2 val; val.x = lo; val.y = hi;
        int tblk = 2 * tt + (g >> 1);
        *(uint2*)&psw[ps_q + ((tblk ^ (l15 & 7)) << 3) + ((g & 1) << 2)] = val;
      }
      __builtin_amdgcn_s_setprio(1);
      #pragma unroll
      for (int ksp = 0; ksp < 2; ++ksp) {
        int tblk = 4 * ksp + g;
        bf16x8 pa = *(const bf16x8*)&psw[ps_q + ((tblk ^ (l15 & 7)) << 3)];
        int ks = p * 2 + ksp;
        #pragma unroll
        for (int di = 0; di < 2; ++di)
          o[di] = __builtin_amdgcn_mfma_f32_16x16x32_bf16(pa, vb[ks][di], o[di], 0, 0, 0);
      }
      __builtin_amdgcn_s_setprio(0);
    }
    __syncthreads();
    cur ^= 1;
  }

  // single l reduction (4 lanes per q share l15)
  l_ += __shfl_xor(l_, 16);
  l_ += __shfl_xor(l_, 32);

  // normalized store, swizzled bf16 [8192][256]
  #pragma unroll
  for (int r = 0; r < 4; ++r) {
    float lr = __shfl(l_, g * 4 + r);
    float inv = __builtin_amdgcn_rcpf(lr);
    size_t row = (size_t)b * SEQ + q0 + w * 16 + g * 4 + r;
    int rw7 = (g * 4 + r) & 7;
    #pragma unroll
    for (int di = 0; di < 2; ++di) {
      int col = h * 32 + di * 16 + l15;
      att[row * 256 + swz(col, rw7)] = f2bf(o[di][r] * inv);
    }
  }
}

extern "C" void kernel_launch(void* const* d_in, const int* in_sizes, int n_in,
                              void* d_out, int out_size, void* d_ws, size_t ws_size,
                              hipStream_t stream)
{
  const float* x    = (const float*)d_in[0];
  const float* y    = (const float*)d_in[1];
  const float* Wqkv = (const float*)d_in[3];
  const float* bqkv = (const float*)d_in[4];
  const float* Wo   = (const float*)d_in[5];
  const float* bo   = (const float*)d_in[6];
  const float* W1   = (const float*)d_in[7];
  const float* b1   = (const float*)d_in[8];
  const float* W2   = (const float*)d_in[9];
  const float* b2   = (const float*)d_in[10];
  const float* g1   = (const float*)d_in[11];
  const float* be1  = (const float*)d_in[12];
  const float* g2   = (const float*)d_in[13];
  const float* be2  = (const float*)d_in[14];

  float* ws = (float*)d_ws;
  ushort* f_bf   = (ushort*)(ws);                 // [0, 1M) floats: swizzled bf16
  ushort* qkv_bf = (ushort*)(ws + 1048576);       // [1M, 4M): Q(scaled),K linear
  ushort* vt_g   = (ushort*)(ws + 4194304);       // [4M, 5M): vt[bh][32][1024] swizzled
  ushort* att_bf = (ushort*)(ws + 5242880);       // [5M, 6M) swizzled
  ushort* f1_bf  = (ushort*)(ws + 6291456);       // [6M, 7M) swizzled
  ushort* h_bf   = (ushort*)(ws + 7340032);       // [7M, 11M) swizzled
  float*  pos    = ws + 11534336;                 // [11M, +8K) distinct-value table
  ushort* wq_bf  = (ushort*)(ws + 12582912);
  ushort* wo_bf  = wq_bf + 196608;
  ushort* w1_bf  = wo_bf + 65536;
  ushort* w2_bf  = w1_bf + 262144;

  prep_kernel<<<1024, 256, 0, stream>>>(Wqkv, Wo, W1, W2, wq_bf, wo_bf, w1_bf, w2_bf, pos);
  build_f_kernel<<<512, 256, 0, stream>>>(x, y, pos, f_bf);
  gemm_mfma_kernel<64, 3, 0><<<dim3(6, 128), 256, 0, stream>>>(
      f_bf, wq_bf, bqkv, qkv_bf, vt_g, NROWS, 768, 256);
  attn_mfma_kernel<<<dim3(16, 8, 8), 256, 0, stream>>>(qkv_bf, vt_g, att_bf);
  gemm_ln_kernel<0><<<256, 512, 0, stream>>>(att_bf, wo_bf, bo, f_bf, g1, be1, nullptr, f1_bf, 256);
  gemm_mfma_kernel<128, 2, 1><<<dim3(8, 64), 256, 0, stream>>>(
      f1_bf, w1_bf, b1, h_bf, nullptr, NROWS, 1024, 256);
  gemm_ln_kernel<1><<<256, 512, 0, stream>>>(h_bf, w2_bf, b2, f1_bf, g2, be2, (float*)d_out, nullptr, 1024);
}

// Round 15
// 89.147 us; speedup vs baseline: 1.2212x; 1.2212x over previous
//
#include <hip/hip_runtime.h>

typedef __attribute__((ext_vector_type(8))) short bf16x8;
typedef __attribute__((ext_vector_type(4))) float f32x4;

#define D_MODEL 256
#define SEQ     1024
#define NROWS   8192

__device__ __forceinline__ ushort f2bf(float f) {
  unsigned u = __float_as_uint(f);
  unsigned r = (u + 0x7FFFu + ((u >> 16) & 1u)) >> 16;
  return (ushort)r;
}
__device__ __forceinline__ float bf2f(ushort b) {
  return __uint_as_float(((unsigned)b) << 16);
}

// async global->LDS, 16B per lane; dst = wave-uniform base + lane*16
__device__ __forceinline__ void gld_lds16(const void* g, void* l) {
  __builtin_amdgcn_global_load_lds(
      (const __attribute__((address_space(1))) void*)g,
      (__attribute__((address_space(3))) void*)l, 16, 0, 0);
}

// XOR-swizzle of 8-element blocks within 64-col groups
__device__ __forceinline__ int swz(int col, int row7) {
  return (col & ~63) | ((((col >> 3) & 7) ^ row7) << 3) | (col & 7);
}

#define QSC 0.25507964954389985f   // log2(e) / sqrt(32)

// -------- 0. prep: weights fp32 -> bf16 pre-swizzled  +  pos table --------
__global__ __launch_bounds__(256) void prep_kernel(
    const float* __restrict__ a, const float* __restrict__ b,
    const float* __restrict__ c, const float* __restrict__ d,
    ushort* __restrict__ oa, ushort* __restrict__ ob,
    ushort* __restrict__ oc, ushort* __restrict__ od,
    float* __restrict__ pos)
{
  int i = blockIdx.x * 256 + threadIdx.x;  // 262144 total
  if (i < 196608) { int r = i >> 8, k = i & 255; oa[(r << 8) + swz(k, r & 7)] = f2bf(a[i]); }
  if (i <  65536) { int r = i >> 8, k = i & 255; ob[(r << 8) + swz(k, r & 7)] = f2bf(b[i]); }
  { int r = i >> 8,  k = i & 255;  oc[(r << 8)  + swz(k, r & 7)] = f2bf(c[i]); }
  { int r = i >> 10, k = i & 1023; od[(r << 10) + swz(k, r & 7)] = f2bf(d[i]); }
  // pos
  {
    int s = i >> 8, cc = i & 255;
    int hh = s >> 5, w = s & 31;
    const float sc = 6.28318530717958647692f / (32.0f + 1e-6f);
    float e;
    int c2 = cc;
    if (c2 < 128) { e = (float)(hh + 1) * sc; }
    else          { e = (float)(w  + 1) * sc; c2 -= 128; }
    int j = c2 >> 1;
    float arg = e * exp2f((float)j * -0.20762050593046014f);  // 10000^(-j/64)
    pos[i] = (c2 & 1) ? cosf(arg) : sinf(arg);
  }
}

// -------- 1. f_bf[row][swz(c)] = transpose(x/y) + 0.1*pos  (bf16 only) --------
__global__ __launch_bounds__(256) void build_f_kernel(
    const float* __restrict__ x, const float* __restrict__ y,
    const float* __restrict__ pos, ushort* __restrict__ fb)
{
  __shared__ float T[64][65];
  int bx = blockIdx.x;                    // 8b * 16st * 4ct = 512
  int b = bx >> 6, st = (bx >> 2) & 15, ct = bx & 3;
  const float* src = (b < 4) ? x : y;
  int bb = b & 3;
  int tid = threadIdx.x;
  {
    int sl = tid & 63, c4 = tid >> 6;
    int s = st * 64 + sl;
    #pragma unroll
    for (int k = 0; k < 16; ++k) {
      int cl = c4 * 16 + k;
      T[cl][sl] = src[((size_t)((bb << 8) + ct * 64 + cl) << 10) + s];
    }
  }
  __syncthreads();
  {
    int cl = tid & 63, s4 = tid >> 6;
    int c = ct * 64 + cl;
    #pragma unroll
    for (int k = 0; k < 16; ++k) {
      int sl = s4 * 16 + k;
      int s = st * 64 + sl;
      float v = T[cl][sl] + 0.1f * pos[s * 256 + c];
      size_t row = (size_t)b * 1024 + s;
      fb[row * 256 + swz(c, s & 7)] = f2bf(v);
    }
  }
}

// -------- 2. MFMA GEMM (BN=128), global_load_lds, pre-swizzled inputs --------
// OUT_MODE: 2 = bf16 swizzled, 3 = qkv fused (Q scaled + linear, K linear, V -> vt swizzled)
template<int BM, int OUT_MODE, int RELU>
__global__ __launch_bounds__(256) void gemm_mfma_kernel(
    const ushort* __restrict__ A, const ushort* __restrict__ B,
    const float* __restrict__ bias, void* __restrict__ Cout,
    ushort* __restrict__ Vout, int M, int N, int K)
{
  constexpr int MI = BM / 32;
  __shared__ ushort Asw[BM * 64];
  __shared__ ushort Bsw[128 * 64];
  const int tid = threadIdx.x, lane = tid & 63, w = tid >> 6;
  const int m0 = blockIdx.y * BM, n0 = blockIdx.x * 128;
  const int wm0 = (w & 1) * (BM / 2), wn0 = (w >> 1) * 64;
  const int l15 = lane & 15, g = lane >> 4;
  const int r8 = lane >> 3, s8 = lane & 7;
  f32x4 acc[MI][4];
  #pragma unroll
  for (int i = 0; i < MI; ++i)
    #pragma unroll
    for (int j = 0; j < 4; ++j) acc[i][j] = (f32x4){0.f, 0.f, 0.f, 0.f};

  for (int kt = 0; kt < K; kt += 64) {
    __syncthreads();
    #pragma unroll
    for (int i = 0; i < BM / 32; ++i) {
      int row0 = w * (BM / 4) + i * 8;
      gld_lds16(A + (size_t)(m0 + row0 + r8) * K + kt + s8 * 8, &Asw[row0 * 64]);
    }
    #pragma unroll
    for (int i = 0; i < 4; ++i) {
      int row0 = w * 32 + i * 8;
      gld_lds16(B + (size_t)(n0 + row0 + r8) * K + kt + s8 * 8, &Bsw[row0 * 64]);
    }
    __syncthreads();
    #pragma unroll
    for (int ks = 0; ks < 2; ++ks) {
      bf16x8 af[MI], bfr[4];
      #pragma unroll
      for (int i = 0; i < MI; ++i) {
        int ra = wm0 + i * 16 + l15;
        af[i] = *(const bf16x8*)&Asw[ra * 64 + (((ks * 4 + g) ^ (ra & 7)) * 8)];
      }
      #pragma unroll
      for (int i = 0; i < 4; ++i) {
        int rb = wn0 + i * 16 + l15;
        bfr[i] = *(const bf16x8*)&Bsw[rb * 64 + (((ks * 4 + g) ^ (rb & 7)) * 8)];
      }
      __builtin_amdgcn_s_setprio(1);
      #pragma unroll
      for (int mi = 0; mi < MI; ++mi)
        #pragma unroll
        for (int ni = 0; ni < 4; ++ni)
          acc[mi][ni] = __builtin_amdgcn_mfma_f32_16x16x32_bf16(
              af[mi], bfr[ni], acc[mi][ni], 0, 0, 0);
      __builtin_amdgcn_s_setprio(0);
    }
  }

  float bv[4];
  #pragma unroll
  for (int ni = 0; ni < 4; ++ni) bv[ni] = bias[n0 + wn0 + ni * 16 + l15];
  #pragma unroll
  for (int mi = 0; mi < MI; ++mi)
    #pragma unroll
    for (int ni = 0; ni < 4; ++ni) {
      int n = n0 + wn0 + ni * 16 + l15;
      float qs = (OUT_MODE == 3 && n < 256) ? QSC : 1.0f;   // fold softmax scale into Q
      float v4[4];
      #pragma unroll
      for (int r = 0; r < 4; ++r) {
        float v = acc[mi][ni][r] + bv[ni];
        if (RELU) v = fmaxf(v, 0.0f);
        v4[r] = v * qs;
      }
      int mb = m0 + wm0 + mi * 16 + g * 4;       // first of 4 consecutive rows
      if (OUT_MODE == 3 && n >= 512) {
        // V column -> vt[bh][d][t], 8-block XOR swizzle on t within 64-groups
        int d = (n - 512) & 31, hh = (n - 512) >> 5;
        int bb = mb >> 10, t0 = mb & 1023;
        uint2 val;
        val.x = (unsigned)f2bf(v4[0]) | ((unsigned)f2bf(v4[1]) << 16);
        val.y = (unsigned)f2bf(v4[2]) | ((unsigned)f2bf(v4[3]) << 16);
        size_t idx = ((size_t)(bb * 8 + hh) * 32 + d) * 1024 + (t0 & ~63)
                   + ((((t0 >> 3) & 7) ^ (d & 7)) * 8) + (t0 & 7);
        *(uint2*)&Vout[idx] = val;
      } else {
        #pragma unroll
        for (int r = 0; r < 4; ++r) {
          size_t m = mb + r;
          if (OUT_MODE == 3) ((ushort*)Cout)[m * N + n] = f2bf(v4[r]);
          else               ((ushort*)Cout)[m * N + swz(n, (int)(m & 7))] = f2bf(v4[r]);
        }
      }
    }
}

// -------- 2b. GEMM (BM=32, BN=256=N) + fused residual + LayerNorm, 8 waves --------
// TRANS_OUT=0: outb = bf16 swizzled.  TRANS_OUT=1: transposed f32 d_out (coalesced via LDS).
template<int TRANS_OUT>
__global__ __launch_bounds__(512) void gemm_ln_kernel(
    const ushort* __restrict__ A, const ushort* __restrict__ B,
    const float* __restrict__ bias, const ushort* __restrict__ R,
    const float* __restrict__ gamma, const float* __restrict__ beta,
    float* __restrict__ out, ushort* __restrict__ outb, int K)
{
  __shared__ ushort Asw[32 * 64];
  __shared__ ushort Bsw[256 * 64];     // 32 KB; reused as f32 transpose tile in epilogue
  __shared__ float red[8][32][2];
  const int tid = threadIdx.x, lane = tid & 63, w = tid >> 6;   // w 0..7
  const int l15 = lane & 15, g4 = lane >> 4;
  const int r8 = lane >> 3, s8 = lane & 7;
  const int m0 = blockIdx.x * 32;
  const int wn0 = w * 32;
  f32x4 acc[2][2];
  #pragma unroll
  for (int i = 0; i < 2; ++i)
    #pragma unroll
    for (int j = 0; j < 2; ++j) acc[i][j] = (f32x4){0.f, 0.f, 0.f, 0.f};

  for (int kt = 0; kt < K; kt += 64) {
    __syncthreads();
    if (w < 4)
      gld_lds16(A + (size_t)(m0 + w * 8 + r8) * K + kt + s8 * 8, &Asw[(w * 8) * 64]);
    #pragma unroll
    for (int i = 0; i < 4; ++i) {
      int row0 = w * 32 + i * 8;
      gld_lds16(B + (size_t)(row0 + r8) * K + kt + s8 * 8, &Bsw[row0 * 64]);
    }
    __syncthreads();
    #pragma unroll
    for (int ks = 0; ks < 2; ++ks) {
      bf16x8 af[2], bfr[2];
      #pragma unroll
      for (int mi = 0; mi < 2; ++mi) {
        int ra = mi * 16 + l15;
        af[mi] = *(const bf16x8*)&Asw[ra * 64 + (((ks * 4 + g4) ^ (ra & 7)) * 8)];
      }
      #pragma unroll
      for (int ni = 0; ni < 2; ++ni) {
        int rb = wn0 + ni * 16 + l15;
        bfr[ni] = *(const bf16x8*)&Bsw[rb * 64 + (((ks * 4 + g4) ^ (rb & 7)) * 8)];
      }
      __builtin_amdgcn_s_setprio(1);
      #pragma unroll
      for (int mi = 0; mi < 2; ++mi)
        #pragma unroll
        for (int ni = 0; ni < 2; ++ni)
          acc[mi][ni] = __builtin_amdgcn_mfma_f32_16x16x32_bf16(
              af[mi], bfr[ni], acc[mi][ni], 0, 0, 0);
      __builtin_amdgcn_s_setprio(0);
    }
  }

  float bv[2], gv[2], bev[2];
  #pragma unroll
  for (int ni = 0; ni < 2; ++ni) {
    int n = wn0 + ni * 16 + l15;
    bv[ni] = bias[n]; gv[ni] = gamma[n]; bev[ni] = beta[n];
  }
  float s1[2][4], s2[2][4];
  #pragma unroll
  for (int mi = 0; mi < 2; ++mi)
    #pragma unroll
    for (int r = 0; r < 4; ++r) { s1[mi][r] = 0.f; s2[mi][r] = 0.f; }
  #pragma unroll
  for (int mi = 0; mi < 2; ++mi)
    #pragma unroll
    for (int ni = 0; ni < 2; ++ni)
      #pragma unroll
      for (int r = 0; r < 4; ++r) {
        int row = m0 + mi * 16 + g4 * 4 + r;
        int col = wn0 + ni * 16 + l15;
        float v = acc[mi][ni][r] + bv[ni] + bf2f(R[(size_t)row * 256 + swz(col, row & 7)]);
        acc[mi][ni][r] = v;
        s1[mi][r] += v;
        s2[mi][r] += v * v;
      }
  #pragma unroll
  for (int mi = 0; mi < 2; ++mi)
    #pragma unroll
    for (int r = 0; r < 4; ++r) {
      #pragma unroll
      for (int d = 1; d < 16; d <<= 1) {
        s1[mi][r] += __shfl_xor(s1[mi][r], d);
        s2[mi][r] += __shfl_xor(s2[mi][r], d);
      }
    }
  if (l15 == 0) {
    #pragma unroll
    for (int mi = 0; mi < 2; ++mi)
      #pragma unroll
      for (int r = 0; r < 4; ++r) {
        int rl = mi * 16 + g4 * 4 + r;
        red[w][rl][0] = s1[mi][r];
        red[w][rl][1] = s2[mi][r];
      }
  }
  __syncthreads();     // also guards Bsw reuse below (all K-loop reads done)
  float* Tr = (float*)Bsw;
  #pragma unroll
  for (int mi = 0; mi < 2; ++mi)
    #pragma unroll
    for (int r = 0; r < 4; ++r) {
      int rl = mi * 16 + g4 * 4 + r;
      float t1 = 0.f, t2 = 0.f;
      #pragma unroll
      for (int ww = 0; ww < 8; ++ww) { t1 += red[ww][rl][0]; t2 += red[ww][rl][1]; }
      float mu = t1 * (1.0f / 256.0f);
      float var = t2 * (1.0f / 256.0f) - mu * mu;
      float rstd = rsqrtf(var + 1e-5f);
      int row = m0 + rl;
      #pragma unroll
      for (int ni = 0; ni < 2; ++ni) {
        int col = wn0 + ni * 16 + l15;
        float res = (acc[mi][ni][r] - mu) * rstd * gv[ni] + bev[ni];
        if (!TRANS_OUT) {
          outb[(size_t)row * 256 + swz(col, row & 7)] = f2bf(res);
        } else {
          Tr[rl * 256 + col] = res;
        }
      }
    }
  if (TRANS_OUT) {
    __syncthreads();
    int b = m0 >> 10, sq0 = m0 & 1023;
    int c = tid & 255, half = tid >> 8;
    float* dst = out + ((size_t)b << 18) + ((size_t)c << 10) + sq0 + half * 16;
    #pragma unroll
    for (int st = 0; st < 4; ++st) {
      float4 v;
      v.x = Tr[(half * 16 + st * 4 + 0) * 256 + c];
      v.y = Tr[(half * 16 + st * 4 + 1) * 256 + c];
      v.z = Tr[(half * 16 + st * 4 + 2) * 256 + c];
      v.w = Tr[(half * 16 + st * 4 + 3) * 256 + c];
      *(float4*)(dst + st * 4) = v;
    }
  }
}

// -------- 3. MFMA flash attention: KVBLK=128, no-max softmax, LDS-P redistribution --------
__global__ __launch_bounds__(256) void attn_mfma_kernel(
    const ushort* __restrict__ qkv, const ushort* __restrict__ vtg,
    ushort* __restrict__ att)
{
  __shared__ ushort Ks[2][64 * 64];    // 16 KB: [64 r2][64] view of 128 K rows
  __shared__ ushort Vt[2][32 * 128];   // 16 KB
  __shared__ ushort Ps[4][16 * 64];    // 8 KB: per-wave [q=16][t'=64], tblk XOR swizzle
  const int tid = threadIdx.x, lane = tid & 63, w = tid >> 6;
  const int l15 = lane & 15, g = lane >> 4;
  const int qt = blockIdx.x, h = blockIdx.y, b = blockIdx.z;
  const size_t base = (size_t)b * SEQ * 768;
  const int q0 = qt * 64;
  const int bh = b * 8 + h;

  // Q fragment (pre-scaled by log2e/sqrt(32) in the QKV epilogue)
  bf16x8 qf = *(const bf16x8*)&qkv[base + (size_t)(q0 + w * 16 + l15) * 768 + h * 32 + g * 8];

  // K staging lane map (per 16-row chunk): [r2][slot], slot' = slot ^ (r2&7)
  const int kr2l  = lane >> 3;
  const int kslot = (lane & 7) ^ kr2l;
  const int krow  = 2 * kr2l + (kslot >> 2);
  const int kdoff = (kslot & 3) * 8;
  const int vd    = lane >> 4;          // V: d sub-row 0..3
  const int vt8   = (lane & 15) * 8;    // V: t offset

  float l_ = 0.f;
  f32x4 o[2];
  o[0] = (f32x4){0.f, 0.f, 0.f, 0.f};
  o[1] = (f32x4){0.f, 0.f, 0.f, 0.f};
  const f32x4 zero = (f32x4){0.f, 0.f, 0.f, 0.f};

  // Ps addresses (q = l15); write: tblk = 2*tt + (g>>1), dword slot (g&1)
  ushort* psw = &Ps[w][0];
  const int ps_q = l15 * 64;

  // stage tile 0
  #pragma unroll
  for (int i = 0; i < 2; ++i) {
    gld_lds16(qkv + base + (size_t)(w * 32 + i * 16 + krow) * 768 + 256 + h * 32 + kdoff,
              &Ks[0][(w * 16 + i * 8) * 64]);
    gld_lds16(vtg + ((size_t)bh * 32 + w * 8 + i * 4 + vd) * 1024 + vt8,
              &Vt[0][(w * 8 + i * 4) * 128]);
  }
  __syncthreads();

  int cur = 0;
  for (int t = 0; t < 8; ++t) {
    if (t < 7) {                         // prefetch next 128-row K/V tile
      int nkv = (t + 1) * 128;
      #pragma unroll
      for (int i = 0; i < 2; ++i) {
        gld_lds16(qkv + base + (size_t)(nkv + w * 32 + i * 16 + krow) * 768 + 256 + h * 32 + kdoff,
                  &Ks[cur ^ 1][(w * 16 + i * 8) * 64]);
        gld_lds16(vtg + ((size_t)bh * 32 + w * 8 + i * 4 + vd) * 1024 + nkv + vt8,
                  &Vt[cur ^ 1][(w * 8 + i * 4) * 128]);
      }
    }
    // S^T = K . Q^T : lane owns q = l15, t-rows ti*16 + g*4 + r, ti 0..7
    f32x4 s[8];
    __builtin_amdgcn_s_setprio(1);
    #pragma unroll
    for (int ti = 0; ti < 8; ++ti) {
      int r2   = ti * 8 + (l15 >> 1);
      int slot = (((l15 & 1) * 4 + g)) ^ (l15 >> 1);
      bf16x8 kf = *(const bf16x8*)&Ks[cur][r2 * 64 + slot * 8];
      s[ti] = __builtin_amdgcn_mfma_f32_16x16x32_bf16(kf, qf, zero, 0, 0, 0);
    }
    __builtin_amdgcn_s_setprio(0);

    // no-max softmax: scores are log2-scaled with |s| << 127 (Q pre-scaled, tiny
    // score variance) -> exp2 cannot overflow; m==0 cancels in P/l exactly.
    float rs = 0.f;
    #pragma unroll
    for (int ti = 0; ti < 8; ++ti)
      #pragma unroll
      for (int r = 0; r < 4; ++r) {
        float p = __builtin_amdgcn_exp2f(s[ti][r]);
        s[ti][r] = p;
        rs += p;
      }
    rs += __shfl_xor(rs, 16);
    rs += __shfl_xor(rs, 32);
    l_ += rs;

    // V fragments (global ks 0..3)
    bf16x8 vb[4][2];
    #pragma unroll
    for (int ks = 0; ks < 4; ++ks)
      #pragma unroll
      for (int di = 0; di < 2; ++di) {
        int d = di * 16 + l15;
        vb[ks][di] = *(const bf16x8*)&Vt[cur][d * 128 + (ks >> 1) * 64 +
                                             ((((ks & 1) * 4 + g) ^ (d & 7)) * 8)];
      }

    // two half-passes over t: pack P -> wave-private swizzled LDS -> b128 A-frags
    #pragma unroll
    for (int p = 0; p < 2; ++p) {
      #pragma unroll
      for (int tt = 0; tt < 4; ++tt) {
        int ti = p * 4 + tt;
        unsigned lo, hi;
        asm("v_cvt_pk_bf16_f32 %0, %1, %2" : "=v"(lo) : "v"(s[ti][0]), "v"(s[ti][1]));
        asm("v_cvt_pk_bf16_f32 %0, %1, %2" : "=v"(hi) : "v"(s[ti][2]), "v"(s[ti][3]));
        uint2 val; val.x = lo; val.y = hi;
        int tblk = 2 * tt + (g >> 1);
        *(uint2*)&psw[ps_q + ((tblk ^ (l15 & 7)) << 3) + ((g & 1) << 2)] = val;
      }
      __builtin_amdgcn_s_setprio(1);
      #pragma unroll
      for (int ksp = 0; ksp < 2; ++ksp) {
        int tblk = 4 * ksp + g;
        bf16x8 pa = *(const bf16x8*)&psw[ps_q + ((tblk ^ (l15 & 7)) << 3)];
        int ks = p * 2 + ksp;
        #pragma unroll
        for (int di = 0; di < 2; ++di)
          o[di] = __builtin_amdgcn_mfma_f32_16x16x32_bf16(pa, vb[ks][di], o[di], 0, 0, 0);
      }
      __builtin_amdgcn_s_setprio(0);
    }
    __syncthreads();
    cur ^= 1;
  }

  // normalized store, swizzled bf16 [8192][256]
  #pragma unroll
  for (int r = 0; r < 4; ++r) {
    float lr = __shfl(l_, g * 4 + r);
    float inv = __builtin_amdgcn_rcpf(lr);
    size_t row = (size_t)b * SEQ + q0 + w * 16 + g * 4 + r;
    int rw7 = (g * 4 + r) & 7;
    #pragma unroll
    for (int di = 0; di < 2; ++di) {
      int col = h * 32 + di * 16 + l15;
      att[row * 256 + swz(col, rw7)] = f2bf(o[di][r] * inv);
    }
  }
}

extern "C" void kernel_launch(void* const* d_in, const int* in_sizes, int n_in,
                              void* d_out, int out_size, void* d_ws, size_t ws_size,
                              hipStream_t stream)
{
  const float* x    = (const float*)d_in[0];
  const float* y    = (const float*)d_in[1];
  const float* Wqkv = (const float*)d_in[3];
  const float* bqkv = (const float*)d_in[4];
  const float* Wo   = (const float*)d_in[5];
  const float* bo   = (const float*)d_in[6];
  const float* W1   = (const float*)d_in[7];
  const float* b1   = (const float*)d_in[8];
  const float* W2   = (const float*)d_in[9];
  const float* b2   = (const float*)d_in[10];
  const float* g1   = (const float*)d_in[11];
  const float* be1  = (const float*)d_in[12];
  const float* g2   = (const float*)d_in[13];
  const float* be2  = (const float*)d_in[14];

  float* ws = (float*)d_ws;
  ushort* f_bf   = (ushort*)(ws);                 // [0, 1M) floats: swizzled bf16
  ushort* qkv_bf = (ushort*)(ws + 1048576);       // [1M, 4M): Q(scaled),K linear
  ushort* vt_g   = (ushort*)(ws + 4194304);       // [4M, 5M): vt[bh][32][1024] swizzled
  ushort* att_bf = (ushort*)(ws + 5242880);       // [5M, 6M) swizzled
  ushort* f1_bf  = (ushort*)(ws + 6291456);       // [6M, 7M) swizzled
  ushort* h_bf   = (ushort*)(ws + 7340032);       // [7M, 11M) swizzled
  float*  pos    = ws + 11534336;                 // [11M, +1M) full table
  ushort* wq_bf  = (ushort*)(ws + 12582912);
  ushort* wo_bf  = wq_bf + 196608;
  ushort* w1_bf  = wo_bf + 65536;
  ushort* w2_bf  = w1_bf + 262144;

  prep_kernel<<<1024, 256, 0, stream>>>(Wqkv, Wo, W1, W2, wq_bf, wo_bf, w1_bf, w2_bf, pos);
  build_f_kernel<<<512, 256, 0, stream>>>(x, y, pos, f_bf);
  gemm_mfma_kernel<64, 3, 0><<<dim3(6, 128), 256, 0, stream>>>(
      f_bf, wq_bf, bqkv, qkv_bf, vt_g, NROWS, 768, 256);
  attn_mfma_kernel<<<dim3(16, 8, 8), 256, 0, stream>>>(qkv_bf, vt_g, att_bf);
  gemm_ln_kernel<0><<<256, 512, 0, stream>>>(att_bf, wo_bf, bo, f_bf, g1, be1, nullptr, f1_bf, 256);
  gemm_mfma_kernel<128, 2, 1><<<dim3(8, 64), 256, 0, stream>>>(
      f1_bf, w1_bf, b1, h_bf, nullptr, NROWS, 1024, 256);
  gemm_ln_kernel<1><<<256, 512, 0, stream>>>(h_bf, w2_bf, b2, f1_bf, g2, be2, (float*)d_out, nullptr, 1024);
}

// Round 16
// 88.263 us; speedup vs baseline: 1.2334x; 1.0100x over previous
//
#include <hip/hip_runtime.h>

typedef __attribute__((ext_vector_type(8))) short bf16x8;
typedef __attribute__((ext_vector_type(4))) float f32x4;

#define D_MODEL 256
#define SEQ     1024
#define NROWS   8192

__device__ __forceinline__ ushort f2bf(float f) {
  unsigned u = __float_as_uint(f);
  unsigned r = (u + 0x7FFFu + ((u >> 16) & 1u)) >> 16;
  return (ushort)r;
}
__device__ __forceinline__ float bf2f(ushort b) {
  return __uint_as_float(((unsigned)b) << 16);
}

// async global->LDS, 16B per lane; dst = wave-uniform base + lane*16
__device__ __forceinline__ void gld_lds16(const void* g, void* l) {
  __builtin_amdgcn_global_load_lds(
      (const __attribute__((address_space(1))) void*)g,
      (__attribute__((address_space(3))) void*)l, 16, 0, 0);
}

// XOR-swizzle of 8-element blocks within 64-col groups
__device__ __forceinline__ int swz(int col, int row7) {
  return (col & ~63) | ((((col >> 3) & 7) ^ row7) << 3) | (col & 7);
}

#define QSC 0.25507964954389985f   // log2(e) / sqrt(32)

// -------- 0. prep: weights fp32 -> bf16 pre-swizzled  +  pos table --------
__global__ __launch_bounds__(256) void prep_kernel(
    const float* __restrict__ a, const float* __restrict__ b,
    const float* __restrict__ c, const float* __restrict__ d,
    ushort* __restrict__ oa, ushort* __restrict__ ob,
    ushort* __restrict__ oc, ushort* __restrict__ od,
    float* __restrict__ pos)
{
  int i = blockIdx.x * 256 + threadIdx.x;  // 262144 total
  if (i < 196608) { int r = i >> 8, k = i & 255; oa[(r << 8) + swz(k, r & 7)] = f2bf(a[i]); }
  if (i <  65536) { int r = i >> 8, k = i & 255; ob[(r << 8) + swz(k, r & 7)] = f2bf(b[i]); }
  { int r = i >> 8,  k = i & 255;  oc[(r << 8)  + swz(k, r & 7)] = f2bf(c[i]); }
  { int r = i >> 10, k = i & 1023; od[(r << 10) + swz(k, r & 7)] = f2bf(d[i]); }
  // pos
  {
    int s = i >> 8, cc = i & 255;
    int hh = s >> 5, w = s & 31;
    const float sc = 6.28318530717958647692f / (32.0f + 1e-6f);
    float e;
    int c2 = cc;
    if (c2 < 128) { e = (float)(hh + 1) * sc; }
    else          { e = (float)(w  + 1) * sc; c2 -= 128; }
    int j = c2 >> 1;
    float arg = e * exp2f((float)j * -0.20762050593046014f);  // 10000^(-j/64)
    pos[i] = (c2 & 1) ? cosf(arg) : sinf(arg);
  }
}

// -------- 1. f_bf[row][swz(c)] = transpose(x/y) + 0.1*pos  (bf16 only) --------
__global__ __launch_bounds__(256) void build_f_kernel(
    const float* __restrict__ x, const float* __restrict__ y,
    const float* __restrict__ pos, ushort* __restrict__ fb)
{
  __shared__ float T[64][65];
  int bx = blockIdx.x;                    // 8b * 16st * 4ct = 512
  int b = bx >> 6, st = (bx >> 2) & 15, ct = bx & 3;
  const float* src = (b < 4) ? x : y;
  int bb = b & 3;
  int tid = threadIdx.x;
  {
    int sl = tid & 63, c4 = tid >> 6;
    int s = st * 64 + sl;
    #pragma unroll
    for (int k = 0; k < 16; ++k) {
      int cl = c4 * 16 + k;
      T[cl][sl] = src[((size_t)((bb << 8) + ct * 64 + cl) << 10) + s];
    }
  }
  __syncthreads();
  {
    int cl = tid & 63, s4 = tid >> 6;
    int c = ct * 64 + cl;
    #pragma unroll
    for (int k = 0; k < 16; ++k) {
      int sl = s4 * 16 + k;
      int s = st * 64 + sl;
      float v = T[cl][sl] + 0.1f * pos[s * 256 + c];
      size_t row = (size_t)b * 1024 + s;
      fb[row * 256 + swz(c, s & 7)] = f2bf(v);
    }
  }
}

// -------- 2. MFMA GEMM (BN=128), global_load_lds, pre-swizzled inputs --------
// OUT_MODE: 2 = bf16 swizzled, 3 = qkv fused (Q scaled + linear, K linear, V -> vt swizzled)
template<int BM, int OUT_MODE, int RELU>
__global__ __launch_bounds__(256) void gemm_mfma_kernel(
    const ushort* __restrict__ A, const ushort* __restrict__ B,
    const float* __restrict__ bias, void* __restrict__ Cout,
    ushort* __restrict__ Vout, int M, int N, int K)
{
  constexpr int MI = BM / 32;
  __shared__ ushort Asw[BM * 64];
  __shared__ ushort Bsw[128 * 64];
  const int tid = threadIdx.x, lane = tid & 63, w = tid >> 6;
  const int m0 = blockIdx.y * BM, n0 = blockIdx.x * 128;
  const int wm0 = (w & 1) * (BM / 2), wn0 = (w >> 1) * 64;
  const int l15 = lane & 15, g = lane >> 4;
  const int r8 = lane >> 3, s8 = lane & 7;
  f32x4 acc[MI][4];
  #pragma unroll
  for (int i = 0; i < MI; ++i)
    #pragma unroll
    for (int j = 0; j < 4; ++j) acc[i][j] = (f32x4){0.f, 0.f, 0.f, 0.f};

  for (int kt = 0; kt < K; kt += 64) {
    __syncthreads();
    #pragma unroll
    for (int i = 0; i < BM / 32; ++i) {
      int row0 = w * (BM / 4) + i * 8;
      gld_lds16(A + (size_t)(m0 + row0 + r8) * K + kt + s8 * 8, &Asw[row0 * 64]);
    }
    #pragma unroll
    for (int i = 0; i < 4; ++i) {
      int row0 = w * 32 + i * 8;
      gld_lds16(B + (size_t)(n0 + row0 + r8) * K + kt + s8 * 8, &Bsw[row0 * 64]);
    }
    __syncthreads();
    #pragma unroll
    for (int ks = 0; ks < 2; ++ks) {
      bf16x8 af[MI], bfr[4];
      #pragma unroll
      for (int i = 0; i < MI; ++i) {
        int ra = wm0 + i * 16 + l15;
        af[i] = *(const bf16x8*)&Asw[ra * 64 + (((ks * 4 + g) ^ (ra & 7)) * 8)];
      }
      #pragma unroll
      for (int i = 0; i < 4; ++i) {
        int rb = wn0 + i * 16 + l15;
        bfr[i] = *(const bf16x8*)&Bsw[rb * 64 + (((ks * 4 + g) ^ (rb & 7)) * 8)];
      }
      __builtin_amdgcn_s_setprio(1);
      #pragma unroll
      for (int mi = 0; mi < MI; ++mi)
        #pragma unroll
        for (int ni = 0; ni < 4; ++ni)
          acc[mi][ni] = __builtin_amdgcn_mfma_f32_16x16x32_bf16(
              af[mi], bfr[ni], acc[mi][ni], 0, 0, 0);
      __builtin_amdgcn_s_setprio(0);
    }
  }

  float bv[4];
  #pragma unroll
  for (int ni = 0; ni < 4; ++ni) bv[ni] = bias[n0 + wn0 + ni * 16 + l15];
  #pragma unroll
  for (int mi = 0; mi < MI; ++mi)
    #pragma unroll
    for (int ni = 0; ni < 4; ++ni) {
      int n = n0 + wn0 + ni * 16 + l15;
      float qs = (OUT_MODE == 3 && n < 256) ? QSC : 1.0f;   // fold softmax scale into Q
      float v4[4];
      #pragma unroll
      for (int r = 0; r < 4; ++r) {
        float v = acc[mi][ni][r] + bv[ni];
        if (RELU) v = fmaxf(v, 0.0f);
        v4[r] = v * qs;
      }
      int mb = m0 + wm0 + mi * 16 + g * 4;       // first of 4 consecutive rows
      if (OUT_MODE == 3 && n >= 512) {
        // V column -> vt[bh][d][t], 8-block XOR swizzle on t within 64-groups
        int d = (n - 512) & 31, hh = (n - 512) >> 5;
        int bb = mb >> 10, t0 = mb & 1023;
        uint2 val;
        val.x = (unsigned)f2bf(v4[0]) | ((unsigned)f2bf(v4[1]) << 16);
        val.y = (unsigned)f2bf(v4[2]) | ((unsigned)f2bf(v4[3]) << 16);
        size_t idx = ((size_t)(bb * 8 + hh) * 32 + d) * 1024 + (t0 & ~63)
                   + ((((t0 >> 3) & 7) ^ (d & 7)) * 8) + (t0 & 7);
        *(uint2*)&Vout[idx] = val;
      } else {
        #pragma unroll
        for (int r = 0; r < 4; ++r) {
          size_t m = mb + r;
          if (OUT_MODE == 3) ((ushort*)Cout)[m * N + n] = f2bf(v4[r]);
          else               ((ushort*)Cout)[m * N + swz(n, (int)(m & 7))] = f2bf(v4[r]);
        }
      }
    }
}

// -------- 2b. GEMM (BM=32, BN=256=N) + fused residual + LayerNorm, 8 waves --------
// TRANS_OUT=0: outb = bf16 swizzled.  TRANS_OUT=1: transposed f32 d_out (coalesced via LDS).
template<int TRANS_OUT>
__global__ __launch_bounds__(512) void gemm_ln_kernel(
    const ushort* __restrict__ A, const ushort* __restrict__ B,
    const float* __restrict__ bias, const ushort* __restrict__ R,
    const float* __restrict__ gamma, const float* __restrict__ beta,
    float* __restrict__ out, ushort* __restrict__ outb, int K)
{
  __shared__ ushort Asw[32 * 64];
  __shared__ ushort Bsw[256 * 64];     // 32 KB; reused as f32 transpose tile in epilogue
  __shared__ float red[8][32][2];
  const int tid = threadIdx.x, lane = tid & 63, w = tid >> 6;   // w 0..7
  const int l15 = lane & 15, g4 = lane >> 4;
  const int r8 = lane >> 3, s8 = lane & 7;
  const int m0 = blockIdx.x * 32;
  const int wn0 = w * 32;
  f32x4 acc[2][2];
  #pragma unroll
  for (int i = 0; i < 2; ++i)
    #pragma unroll
    for (int j = 0; j < 2; ++j) acc[i][j] = (f32x4){0.f, 0.f, 0.f, 0.f};

  for (int kt = 0; kt < K; kt += 64) {
    __syncthreads();
    if (w < 4)
      gld_lds16(A + (size_t)(m0 + w * 8 + r8) * K + kt + s8 * 8, &Asw[(w * 8) * 64]);
    #pragma unroll
    for (int i = 0; i < 4; ++i) {
      int row0 = w * 32 + i * 8;
      gld_lds16(B + (size_t)(row0 + r8) * K + kt + s8 * 8, &Bsw[row0 * 64]);
    }
    __syncthreads();
    #pragma unroll
    for (int ks = 0; ks < 2; ++ks) {
      bf16x8 af[2], bfr[2];
      #pragma unroll
      for (int mi = 0; mi < 2; ++mi) {
        int ra = mi * 16 + l15;
        af[mi] = *(const bf16x8*)&Asw[ra * 64 + (((ks * 4 + g4) ^ (ra & 7)) * 8)];
      }
      #pragma unroll
      for (int ni = 0; ni < 2; ++ni) {
        int rb = wn0 + ni * 16 + l15;
        bfr[ni] = *(const bf16x8*)&Bsw[rb * 64 + (((ks * 4 + g4) ^ (rb & 7)) * 8)];
      }
      __builtin_amdgcn_s_setprio(1);
      #pragma unroll
      for (int mi = 0; mi < 2; ++mi)
        #pragma unroll
        for (int ni = 0; ni < 2; ++ni)
          acc[mi][ni] = __builtin_amdgcn_mfma_f32_16x16x32_bf16(
              af[mi], bfr[ni], acc[mi][ni], 0, 0, 0);
      __builtin_amdgcn_s_setprio(0);
    }
  }

  float bv[2], gv[2], bev[2];
  #pragma unroll
  for (int ni = 0; ni < 2; ++ni) {
    int n = wn0 + ni * 16 + l15;
    bv[ni] = bias[n]; gv[ni] = gamma[n]; bev[ni] = beta[n];
  }
  float s1[2][4], s2[2][4];
  #pragma unroll
  for (int mi = 0; mi < 2; ++mi)
    #pragma unroll
    for (int r = 0; r < 4; ++r) { s1[mi][r] = 0.f; s2[mi][r] = 0.f; }
  #pragma unroll
  for (int mi = 0; mi < 2; ++mi)
    #pragma unroll
    for (int ni = 0; ni < 2; ++ni)
      #pragma unroll
      for (int r = 0; r < 4; ++r) {
        int row = m0 + mi * 16 + g4 * 4 + r;
        int col = wn0 + ni * 16 + l15;
        float v = acc[mi][ni][r] + bv[ni] + bf2f(R[(size_t)row * 256 + swz(col, row & 7)]);
        acc[mi][ni][r] = v;
        s1[mi][r] += v;
        s2[mi][r] += v * v;
      }
  #pragma unroll
  for (int mi = 0; mi < 2; ++mi)
    #pragma unroll
    for (int r = 0; r < 4; ++r) {
      #pragma unroll
      for (int d = 1; d < 16; d <<= 1) {
        s1[mi][r] += __shfl_xor(s1[mi][r], d);
        s2[mi][r] += __shfl_xor(s2[mi][r], d);
      }
    }
  if (l15 == 0) {
    #pragma unroll
    for (int mi = 0; mi < 2; ++mi)
      #pragma unroll
      for (int r = 0; r < 4; ++r) {
        int rl = mi * 16 + g4 * 4 + r;
        red[w][rl][0] = s1[mi][r];
        red[w][rl][1] = s2[mi][r];
      }
  }
  __syncthreads();     // also guards Bsw reuse below (all K-loop reads done)
  float* Tr = (float*)Bsw;
  #pragma unroll
  for (int mi = 0; mi < 2; ++mi)
    #pragma unroll
    for (int r = 0; r < 4; ++r) {
      int rl = mi * 16 + g4 * 4 + r;
      float t1 = 0.f, t2 = 0.f;
      #pragma unroll
      for (int ww = 0; ww < 8; ++ww) { t1 += red[ww][rl][0]; t2 += red[ww][rl][1]; }
      float mu = t1 * (1.0f / 256.0f);
      float var = t2 * (1.0f / 256.0f) - mu * mu;
      float rstd = rsqrtf(var + 1e-5f);
      int row = m0 + rl;
      #pragma unroll
      for (int ni = 0; ni < 2; ++ni) {
        int col = wn0 + ni * 16 + l15;
        float res = (acc[mi][ni][r] - mu) * rstd * gv[ni] + bev[ni];
        if (!TRANS_OUT) {
          outb[(size_t)row * 256 + swz(col, row & 7)] = f2bf(res);
        } else {
          Tr[rl * 256 + col] = res;
        }
      }
    }
  if (TRANS_OUT) {
    __syncthreads();
    int b = m0 >> 10, sq0 = m0 & 1023;
    int c = tid & 255, half = tid >> 8;
    float* dst = out + ((size_t)b << 18) + ((size_t)c << 10) + sq0 + half * 16;
    #pragma unroll
    for (int st = 0; st < 4; ++st) {
      float4 v;
      v.x = Tr[(half * 16 + st * 4 + 0) * 256 + c];
      v.y = Tr[(half * 16 + st * 4 + 1) * 256 + c];
      v.z = Tr[(half * 16 + st * 4 + 2) * 256 + c];
      v.w = Tr[(half * 16 + st * 4 + 3) * 256 + c];
      *(float4*)(dst + st * 4) = v;
    }
  }
}

// -------- 3. MFMA flash attention: KVBLK=128, no-max softmax, LDS-P redistribution --------
// vb loads moved into each half-pass (live-range cut); launch_bounds(256,4) pins
// VGPR <= 128 so all 4 blocks/CU are co-resident (LDS 40KB allows 4).
__global__ __launch_bounds__(256, 4) void attn_mfma_kernel(
    const ushort* __restrict__ qkv, const ushort* __restrict__ vtg,
    ushort* __restrict__ att)
{
  __shared__ ushort Ks[2][64 * 64];    // 16 KB: [64 r2][64] view of 128 K rows
  __shared__ ushort Vt[2][32 * 128];   // 16 KB
  __shared__ ushort Ps[4][16 * 64];    // 8 KB: per-wave [q=16][t'=64], tblk XOR swizzle
  const int tid = threadIdx.x, lane = tid & 63, w = tid >> 6;
  const int l15 = lane & 15, g = lane >> 4;
  const int qt = blockIdx.x, h = blockIdx.y, b = blockIdx.z;
  const size_t base = (size_t)b * SEQ * 768;
  const int q0 = qt * 64;
  const int bh = b * 8 + h;

  // Q fragment (pre-scaled by log2e/sqrt(32) in the QKV epilogue)
  bf16x8 qf = *(const bf16x8*)&qkv[base + (size_t)(q0 + w * 16 + l15) * 768 + h * 32 + g * 8];

  // K staging lane map (per 16-row chunk): [r2][slot], slot' = slot ^ (r2&7)
  const int kr2l  = lane >> 3;
  const int kslot = (lane & 7) ^ kr2l;
  const int krow  = 2 * kr2l + (kslot >> 2);
  const int kdoff = (kslot & 3) * 8;
  const int vd    = lane >> 4;          // V: d sub-row 0..3
  const int vt8   = (lane & 15) * 8;    // V: t offset

  float l_ = 0.f;
  f32x4 o[2];
  o[0] = (f32x4){0.f, 0.f, 0.f, 0.f};
  o[1] = (f32x4){0.f, 0.f, 0.f, 0.f};
  const f32x4 zero = (f32x4){0.f, 0.f, 0.f, 0.f};

  // Ps addresses (q = l15); write: tblk = 2*tt + (g>>1), dword slot (g&1)
  ushort* psw = &Ps[w][0];
  const int ps_q = l15 * 64;

  // stage tile 0
  #pragma unroll
  for (int i = 0; i < 2; ++i) {
    gld_lds16(qkv + base + (size_t)(w * 32 + i * 16 + krow) * 768 + 256 + h * 32 + kdoff,
              &Ks[0][(w * 16 + i * 8) * 64]);
    gld_lds16(vtg + ((size_t)bh * 32 + w * 8 + i * 4 + vd) * 1024 + vt8,
              &Vt[0][(w * 8 + i * 4) * 128]);
  }
  __syncthreads();

  int cur = 0;
  for (int t = 0; t < 8; ++t) {
    if (t < 7) {                         // prefetch next 128-row K/V tile
      int nkv = (t + 1) * 128;
      #pragma unroll
      for (int i = 0; i < 2; ++i) {
        gld_lds16(qkv + base + (size_t)(nkv + w * 32 + i * 16 + krow) * 768 + 256 + h * 32 + kdoff,
                  &Ks[cur ^ 1][(w * 16 + i * 8) * 64]);
        gld_lds16(vtg + ((size_t)bh * 32 + w * 8 + i * 4 + vd) * 1024 + nkv + vt8,
                  &Vt[cur ^ 1][(w * 8 + i * 4) * 128]);
      }
    }
    // S^T = K . Q^T : lane owns q = l15, t-rows ti*16 + g*4 + r, ti 0..7
    f32x4 s[8];
    __builtin_amdgcn_s_setprio(1);
    #pragma unroll
    for (int ti = 0; ti < 8; ++ti) {
      int r2   = ti * 8 + (l15 >> 1);
      int slot = (((l15 & 1) * 4 + g)) ^ (l15 >> 1);
      bf16x8 kf = *(const bf16x8*)&Ks[cur][r2 * 64 + slot * 8];
      s[ti] = __builtin_amdgcn_mfma_f32_16x16x32_bf16(kf, qf, zero, 0, 0, 0);
    }
    __builtin_amdgcn_s_setprio(0);

    // no-max softmax: scores are log2-scaled with |s| << 127 (Q pre-scaled, tiny
    // score variance) -> exp2 cannot overflow; m==0 cancels in P/l exactly.
    float rs = 0.f;
    #pragma unroll
    for (int ti = 0; ti < 8; ++ti)
      #pragma unroll
      for (int r = 0; r < 4; ++r) {
        float p = __builtin_amdgcn_exp2f(s[ti][r]);
        s[ti][r] = p;
        rs += p;
      }
    rs += __shfl_xor(rs, 16);
    rs += __shfl_xor(rs, 32);
    l_ += rs;

    // two half-passes over t: pack P -> wave-private swizzled LDS -> b128 A-frags;
    // V fragments loaded per-pass (halves vb live range vs all-up-front)
    #pragma unroll
    for (int p = 0; p < 2; ++p) {
      #pragma unroll
      for (int tt = 0; tt < 4; ++tt) {
        int ti = p * 4 + tt;
        unsigned lo, hi;
        asm("v_cvt_pk_bf16_f32 %0, %1, %2" : "=v"(lo) : "v"(s[ti][0]), "v"(s[ti][1]));
        asm("v_cvt_pk_bf16_f32 %0, %1, %2" : "=v"(hi) : "v"(s[ti][2]), "v"(s[ti][3]));
        uint2 val; val.x = lo; val.y = hi;
        int tblk = 2 * tt + (g >> 1);
        *(uint2*)&psw[ps_q + ((tblk ^ (l15 & 7)) << 3) + ((g & 1) << 2)] = val;
      }
      bf16x8 vb2[2][2];
      #pragma unroll
      for (int ksp = 0; ksp < 2; ++ksp)
        #pragma unroll
        for (int di = 0; di < 2; ++di) {
          int d = di * 16 + l15;
          vb2[ksp][di] = *(const bf16x8*)&Vt[cur][d * 128 + p * 64 +
                                                 (((ksp * 4 + g) ^ (d & 7)) * 8)];
        }
      __builtin_amdgcn_s_setprio(1);
      #pragma unroll
      for (int ksp = 0; ksp < 2; ++ksp) {
        int tblk = 4 * ksp + g;
        bf16x8 pa = *(const bf16x8*)&psw[ps_q + ((tblk ^ (l15 & 7)) << 3)];
        #pragma unroll
        for (int di = 0; di < 2; ++di)
          o[di] = __builtin_amdgcn_mfma_f32_16x16x32_bf16(pa, vb2[ksp][di], o[di], 0, 0, 0);
      }
      __builtin_amdgcn_s_setprio(0);
    }
    __syncthreads();
    cur ^= 1;
  }

  // normalized store, swizzled bf16 [8192][256]
  #pragma unroll
  for (int r = 0; r < 4; ++r) {
    float lr = __shfl(l_, g * 4 + r);
    float inv = __builtin_amdgcn_rcpf(lr);
    size_t row = (size_t)b * SEQ + q0 + w * 16 + g * 4 + r;
    int rw7 = (g * 4 + r) & 7;
    #pragma unroll
    for (int di = 0; di < 2; ++di) {
      int col = h * 32 + di * 16 + l15;
      att[row * 256 + swz(col, rw7)] = f2bf(o[di][r] * inv);
    }
  }
}

extern "C" void kernel_launch(void* const* d_in, const int* in_sizes, int n_in,
                              void* d_out, int out_size, void* d_ws, size_t ws_size,
                              hipStream_t stream)
{
  const float* x    = (const float*)d_in[0];
  const float* y    = (const float*)d_in[1];
  const float* Wqkv = (const float*)d_in[3];
  const float* bqkv = (const float*)d_in[4];
  const float* Wo   = (const float*)d_in[5];
  const float* bo   = (const float*)d_in[6];
  const float* W1   = (const float*)d_in[7];
  const float* b1   = (const float*)d_in[8];
  const float* W2   = (const float*)d_in[9];
  const float* b2   = (const float*)d_in[10];
  const float* g1   = (const float*)d_in[11];
  const float* be1  = (const float*)d_in[12];
  const float* g2   = (const float*)d_in[13];
  const float* be2  = (const float*)d_in[14];

  float* ws = (float*)d_ws;
  ushort* f_bf   = (ushort*)(ws);                 // [0, 1M) floats: swizzled bf16
  ushort* qkv_bf = (ushort*)(ws + 1048576);       // [1M, 4M): Q(scaled),K linear
  ushort* vt_g   = (ushort*)(ws + 4194304);       // [4M, 5M): vt[bh][32][1024] swizzled
  ushort* att_bf = (ushort*)(ws + 5242880);       // [5M, 6M) swizzled
  ushort* f1_bf  = (ushort*)(ws + 6291456);       // [6M, 7M) swizzled
  ushort* h_bf   = (ushort*)(ws + 7340032);       // [7M, 11M) swizzled
  float*  pos    = ws + 11534336;                 // [11M, +1M) full table
  ushort* wq_bf  = (ushort*)(ws + 12582912);
  ushort* wo_bf  = wq_bf + 196608;
  ushort* w1_bf  = wo_bf + 65536;
  ushort* w2_bf  = w1_bf + 262144;

  prep_kernel<<<1024, 256, 0, stream>>>(Wqkv, Wo, W1, W2, wq_bf, wo_bf, w1_bf, w2_bf, pos);
  build_f_kernel<<<512, 256, 0, stream>>>(x, y, pos, f_bf);
  gemm_mfma_kernel<64, 3, 0><<<dim3(6, 128), 256, 0, stream>>>(
      f_bf, wq_bf, bqkv, qkv_bf, vt_g, NROWS, 768, 256);
  attn_mfma_kernel<<<dim3(16, 8, 8), 256, 0, stream>>>(qkv_bf, vt_g, att_bf);
  gemm_ln_kernel<0><<<256, 512, 0, stream>>>(att_bf, wo_bf, bo, f_bf, g1, be1, nullptr, f1_bf, 256);
  gemm_mfma_kernel<128, 2, 1><<<dim3(8, 64), 256, 0, stream>>>(
      f1_bf, w1_bf, b1, h_bf, nullptr, NROWS, 1024, 256);
  gemm_ln_kernel<1><<<256, 512, 0, stream>>>(h_bf, w2_bf, b2, f1_bf, g2, be2, (float*)d_out, nullptr, 1024);
}

// Round 17
// 87.133 us; speedup vs baseline: 1.2494x; 1.0130x over previous
//
#include <hip/hip_runtime.h>

typedef __attribute__((ext_vector_type(8))) short bf16x8;
typedef __attribute__((ext_vector_type(4))) float f32x4;

#define D_MODEL 256
#define SEQ     1024
#define NROWS   8192

__device__ __forceinline__ ushort f2bf(float f) {
  unsigned u = __float_as_uint(f);
  unsigned r = (u + 0x7FFFu + ((u >> 16) & 1u)) >> 16;
  return (ushort)r;
}
__device__ __forceinline__ float bf2f(ushort b) {
  return __uint_as_float(((unsigned)b) << 16);
}

// async global->LDS, 16B per lane; dst = wave-uniform base + lane*16
__device__ __forceinline__ void gld_lds16(const void* g, void* l) {
  __builtin_amdgcn_global_load_lds(
      (const __attribute__((address_space(1))) void*)g,
      (__attribute__((address_space(3))) void*)l, 16, 0, 0);
}

// XOR-swizzle of 8-element blocks within 64-col groups
__device__ __forceinline__ int swz(int col, int row7) {
  return (col & ~63) | ((((col >> 3) & 7) ^ row7) << 3) | (col & 7);
}

#define QSC 0.25507964954389985f   // log2(e) / sqrt(32)

// -------- 0. prep: weights fp32 -> bf16 pre-swizzled  +  pos table --------
__global__ __launch_bounds__(256) void prep_kernel(
    const float* __restrict__ a, const float* __restrict__ b,
    const float* __restrict__ c, const float* __restrict__ d,
    ushort* __restrict__ oa, ushort* __restrict__ ob,
    ushort* __restrict__ oc, ushort* __restrict__ od,
    float* __restrict__ pos)
{
  int i = blockIdx.x * 256 + threadIdx.x;  // 262144 total
  if (i < 196608) { int r = i >> 8, k = i & 255; oa[(r << 8) + swz(k, r & 7)] = f2bf(a[i]); }
  if (i <  65536) { int r = i >> 8, k = i & 255; ob[(r << 8) + swz(k, r & 7)] = f2bf(b[i]); }
  { int r = i >> 8,  k = i & 255;  oc[(r << 8)  + swz(k, r & 7)] = f2bf(c[i]); }
  { int r = i >> 10, k = i & 1023; od[(r << 10) + swz(k, r & 7)] = f2bf(d[i]); }
  // pos
  {
    int s = i >> 8, cc = i & 255;
    int hh = s >> 5, w = s & 31;
    const float sc = 6.28318530717958647692f / (32.0f + 1e-6f);
    float e;
    int c2 = cc;
    if (c2 < 128) { e = (float)(hh + 1) * sc; }
    else          { e = (float)(w  + 1) * sc; c2 -= 128; }
    int j = c2 >> 1;
    float arg = e * exp2f((float)j * -0.20762050593046014f);  // 10000^(-j/64)
    pos[i] = (c2 & 1) ? cosf(arg) : sinf(arg);
  }
}

// -------- 1. f_bf[row][swz(c)] = transpose(x/y) + 0.1*pos  (bf16 only) --------
__global__ __launch_bounds__(256) void build_f_kernel(
    const float* __restrict__ x, const float* __restrict__ y,
    const float* __restrict__ pos, ushort* __restrict__ fb)
{
  __shared__ float T[64][65];
  int bx = blockIdx.x;                    // 8b * 16st * 4ct = 512
  int b = bx >> 6, st = (bx >> 2) & 15, ct = bx & 3;
  const float* src = (b < 4) ? x : y;
  int bb = b & 3;
  int tid = threadIdx.x;
  {
    int sl = tid & 63, c4 = tid >> 6;
    int s = st * 64 + sl;
    #pragma unroll
    for (int k = 0; k < 16; ++k) {
      int cl = c4 * 16 + k;
      T[cl][sl] = src[((size_t)((bb << 8) + ct * 64 + cl) << 10) + s];
    }
  }
  __syncthreads();
  {
    int cl = tid & 63, s4 = tid >> 6;
    int c = ct * 64 + cl;
    #pragma unroll
    for (int k = 0; k < 16; ++k) {
      int sl = s4 * 16 + k;
      int s = st * 64 + sl;
      float v = T[cl][sl] + 0.1f * pos[s * 256 + c];
      size_t row = (size_t)b * 1024 + s;
      fb[row * 256 + swz(c, s & 7)] = f2bf(v);
    }
  }
}

// -------- 2. MFMA GEMM (BN=128), global_load_lds, pre-swizzled inputs --------
// OUT_MODE: 2 = bf16 swizzled, 3 = qkv fused (Q scaled + linear, K linear, V -> vt swizzled)
template<int BM, int OUT_MODE, int RELU>
__global__ __launch_bounds__(256) void gemm_mfma_kernel(
    const ushort* __restrict__ A, const ushort* __restrict__ B,
    const float* __restrict__ bias, void* __restrict__ Cout,
    ushort* __restrict__ Vout, int M, int N, int K)
{
  constexpr int MI = BM / 32;
  __shared__ ushort Asw[BM * 64];
  __shared__ ushort Bsw[128 * 64];
  const int tid = threadIdx.x, lane = tid & 63, w = tid >> 6;
  const int m0 = blockIdx.y * BM, n0 = blockIdx.x * 128;
  const int wm0 = (w & 1) * (BM / 2), wn0 = (w >> 1) * 64;
  const int l15 = lane & 15, g = lane >> 4;
  const int r8 = lane >> 3, s8 = lane & 7;
  f32x4 acc[MI][4];
  #pragma unroll
  for (int i = 0; i < MI; ++i)
    #pragma unroll
    for (int j = 0; j < 4; ++j) acc[i][j] = (f32x4){0.f, 0.f, 0.f, 0.f};

  for (int kt = 0; kt < K; kt += 64) {
    __syncthreads();
    #pragma unroll
    for (int i = 0; i < BM / 32; ++i) {
      int row0 = w * (BM / 4) + i * 8;
      gld_lds16(A + (size_t)(m0 + row0 + r8) * K + kt + s8 * 8, &Asw[row0 * 64]);
    }
    #pragma unroll
    for (int i = 0; i < 4; ++i) {
      int row0 = w * 32 + i * 8;
      gld_lds16(B + (size_t)(n0 + row0 + r8) * K + kt + s8 * 8, &Bsw[row0 * 64]);
    }
    __syncthreads();
    #pragma unroll
    for (int ks = 0; ks < 2; ++ks) {
      bf16x8 af[MI], bfr[4];
      #pragma unroll
      for (int i = 0; i < MI; ++i) {
        int ra = wm0 + i * 16 + l15;
        af[i] = *(const bf16x8*)&Asw[ra * 64 + (((ks * 4 + g) ^ (ra & 7)) * 8)];
      }
      #pragma unroll
      for (int i = 0; i < 4; ++i) {
        int rb = wn0 + i * 16 + l15;
        bfr[i] = *(const bf16x8*)&Bsw[rb * 64 + (((ks * 4 + g) ^ (rb & 7)) * 8)];
      }
      __builtin_amdgcn_s_setprio(1);
      #pragma unroll
      for (int mi = 0; mi < MI; ++mi)
        #pragma unroll
        for (int ni = 0; ni < 4; ++ni)
          acc[mi][ni] = __builtin_amdgcn_mfma_f32_16x16x32_bf16(
              af[mi], bfr[ni], acc[mi][ni], 0, 0, 0);
      __builtin_amdgcn_s_setprio(0);
    }
  }

  float bv[4];
  #pragma unroll
  for (int ni = 0; ni < 4; ++ni) bv[ni] = bias[n0 + wn0 + ni * 16 + l15];
  #pragma unroll
  for (int mi = 0; mi < MI; ++mi)
    #pragma unroll
    for (int ni = 0; ni < 4; ++ni) {
      int n = n0 + wn0 + ni * 16 + l15;
      float qs = (OUT_MODE == 3 && n < 256) ? QSC : 1.0f;   // fold softmax scale into Q
      float v4[4];
      #pragma unroll
      for (int r = 0; r < 4; ++r) {
        float v = acc[mi][ni][r] + bv[ni];
        if (RELU) v = fmaxf(v, 0.0f);
        v4[r] = v * qs;
      }
      int mb = m0 + wm0 + mi * 16 + g * 4;       // first of 4 consecutive rows
      if (OUT_MODE == 3 && n >= 512) {
        // V column -> vt[bh][d][t], 8-block XOR swizzle on t within 64-groups
        int d = (n - 512) & 31, hh = (n - 512) >> 5;
        int bb = mb >> 10, t0 = mb & 1023;
        uint2 val;
        val.x = (unsigned)f2bf(v4[0]) | ((unsigned)f2bf(v4[1]) << 16);
        val.y = (unsigned)f2bf(v4[2]) | ((unsigned)f2bf(v4[3]) << 16);
        size_t idx = ((size_t)(bb * 8 + hh) * 32 + d) * 1024 + (t0 & ~63)
                   + ((((t0 >> 3) & 7) ^ (d & 7)) * 8) + (t0 & 7);
        *(uint2*)&Vout[idx] = val;
      } else {
        #pragma unroll
        for (int r = 0; r < 4; ++r) {
          size_t m = mb + r;
          if (OUT_MODE == 3) ((ushort*)Cout)[m * N + n] = f2bf(v4[r]);
          else               ((ushort*)Cout)[m * N + swz(n, (int)(m & 7))] = f2bf(v4[r]);
        }
      }
    }
}

// -------- 2b. GEMM (BM rows, BN=256=N) + fused residual + LayerNorm, 8 waves --------
// TRANS_OUT=0: outb = bf16 swizzled.  TRANS_OUT=1: transposed f32 d_out (coalesced via LDS).
template<int BM, int TRANS_OUT>
__global__ __launch_bounds__(512) void gemm_ln_kernel(
    const ushort* __restrict__ A, const ushort* __restrict__ B,
    const float* __restrict__ bias, const ushort* __restrict__ R,
    const float* __restrict__ gamma, const float* __restrict__ beta,
    float* __restrict__ out, ushort* __restrict__ outb, int K)
{
  constexpr int MI = BM / 16;          // m-frags (16 rows each)
  __shared__ ushort Asw[BM * 64];
  __shared__ ushort Bsw[256 * 64];     // 32 KB; reused as f32 transpose tile in epilogue
  __shared__ float red[8][BM][2];
  const int tid = threadIdx.x, lane = tid & 63, w = tid >> 6;   // w 0..7
  const int l15 = lane & 15, g4 = lane >> 4;
  const int r8 = lane >> 3, s8 = lane & 7;
  const int m0 = blockIdx.x * BM;
  const int wn0 = w * 32;
  f32x4 acc[MI][2];
  #pragma unroll
  for (int i = 0; i < MI; ++i)
    #pragma unroll
    for (int j = 0; j < 2; ++j) acc[i][j] = (f32x4){0.f, 0.f, 0.f, 0.f};

  for (int kt = 0; kt < K; kt += 64) {
    __syncthreads();
    if (w < BM / 8)
      gld_lds16(A + (size_t)(m0 + w * 8 + r8) * K + kt + s8 * 8, &Asw[(w * 8) * 64]);
    #pragma unroll
    for (int i = 0; i < 4; ++i) {
      int row0 = w * 32 + i * 8;
      gld_lds16(B + (size_t)(row0 + r8) * K + kt + s8 * 8, &Bsw[row0 * 64]);
    }
    __syncthreads();
    #pragma unroll
    for (int ks = 0; ks < 2; ++ks) {
      bf16x8 af[MI], bfr[2];
      #pragma unroll
      for (int mi = 0; mi < MI; ++mi) {
        int ra = mi * 16 + l15;
        af[mi] = *(const bf16x8*)&Asw[ra * 64 + (((ks * 4 + g4) ^ (ra & 7)) * 8)];
      }
      #pragma unroll
      for (int ni = 0; ni < 2; ++ni) {
        int rb = wn0 + ni * 16 + l15;
        bfr[ni] = *(const bf16x8*)&Bsw[rb * 64 + (((ks * 4 + g4) ^ (rb & 7)) * 8)];
      }
      __builtin_amdgcn_s_setprio(1);
      #pragma unroll
      for (int mi = 0; mi < MI; ++mi)
        #pragma unroll
        for (int ni = 0; ni < 2; ++ni)
          acc[mi][ni] = __builtin_amdgcn_mfma_f32_16x16x32_bf16(
              af[mi], bfr[ni], acc[mi][ni], 0, 0, 0);
      __builtin_amdgcn_s_setprio(0);
    }
  }

  float bv[2], gv[2], bev[2];
  #pragma unroll
  for (int ni = 0; ni < 2; ++ni) {
    int n = wn0 + ni * 16 + l15;
    bv[ni] = bias[n]; gv[ni] = gamma[n]; bev[ni] = beta[n];
  }
  float s1[MI][4], s2[MI][4];
  #pragma unroll
  for (int mi = 0; mi < MI; ++mi)
    #pragma unroll
    for (int r = 0; r < 4; ++r) { s1[mi][r] = 0.f; s2[mi][r] = 0.f; }
  #pragma unroll
  for (int mi = 0; mi < MI; ++mi)
    #pragma unroll
    for (int ni = 0; ni < 2; ++ni)
      #pragma unroll
      for (int r = 0; r < 4; ++r) {
        int row = m0 + mi * 16 + g4 * 4 + r;
        int col = wn0 + ni * 16 + l15;
        float v = acc[mi][ni][r] + bv[ni] + bf2f(R[(size_t)row * 256 + swz(col, row & 7)]);
        acc[mi][ni][r] = v;
        s1[mi][r] += v;
        s2[mi][r] += v * v;
      }
  #pragma unroll
  for (int mi = 0; mi < MI; ++mi)
    #pragma unroll
    for (int r = 0; r < 4; ++r) {
      #pragma unroll
      for (int d = 1; d < 16; d <<= 1) {
        s1[mi][r] += __shfl_xor(s1[mi][r], d);
        s2[mi][r] += __shfl_xor(s2[mi][r], d);
      }
    }
  if (l15 == 0) {
    #pragma unroll
    for (int mi = 0; mi < MI; ++mi)
      #pragma unroll
      for (int r = 0; r < 4; ++r) {
        int rl = mi * 16 + g4 * 4 + r;
        red[w][rl][0] = s1[mi][r];
        red[w][rl][1] = s2[mi][r];
      }
  }
  __syncthreads();     // also guards Bsw reuse below (all K-loop reads done)
  float* Tr = (float*)Bsw;
  #pragma unroll
  for (int mi = 0; mi < MI; ++mi)
    #pragma unroll
    for (int r = 0; r < 4; ++r) {
      int rl = mi * 16 + g4 * 4 + r;
      float t1 = 0.f, t2 = 0.f;
      #pragma unroll
      for (int ww = 0; ww < 8; ++ww) { t1 += red[ww][rl][0]; t2 += red[ww][rl][1]; }
      float mu = t1 * (1.0f / 256.0f);
      float var = t2 * (1.0f / 256.0f) - mu * mu;
      float rstd = rsqrtf(var + 1e-5f);
      int row = m0 + rl;
      #pragma unroll
      for (int ni = 0; ni < 2; ++ni) {
        int col = wn0 + ni * 16 + l15;
        float res = (acc[mi][ni][r] - mu) * rstd * gv[ni] + bev[ni];
        if (!TRANS_OUT) {
          outb[(size_t)row * 256 + swz(col, row & 7)] = f2bf(res);
        } else {
          Tr[rl * 256 + col] = res;
        }
      }
    }
  if (TRANS_OUT) {
    __syncthreads();
    int b = m0 >> 10, sq0 = m0 & 1023;
    int c = tid & 255, half = tid >> 8;
    float* dst = out + ((size_t)b << 18) + ((size_t)c << 10) + sq0 + half * (BM / 2);
    #pragma unroll
    for (int st = 0; st < BM / 8; ++st) {
      float4 v;
      v.x = Tr[(half * (BM / 2) + st * 4 + 0) * 256 + c];
      v.y = Tr[(half * (BM / 2) + st * 4 + 1) * 256 + c];
      v.z = Tr[(half * (BM / 2) + st * 4 + 2) * 256 + c];
      v.w = Tr[(half * (BM / 2) + st * 4 + 3) * 256 + c];
      *(float4*)(dst + st * 4) = v;
    }
  }
}

// -------- 3. MFMA flash attention: KVBLK=128, no-max softmax, LDS-P redistribution --------
// vb loads per half-pass (live-range cut); launch_bounds(256,4) pins VGPR <= 128.
__global__ __launch_bounds__(256, 4) void attn_mfma_kernel(
    const ushort* __restrict__ qkv, const ushort* __restrict__ vtg,
    ushort* __restrict__ att)
{
  __shared__ ushort Ks[2][64 * 64];    // 16 KB: [64 r2][64] view of 128 K rows
  __shared__ ushort Vt[2][32 * 128];   // 16 KB
  __shared__ ushort Ps[4][16 * 64];    // 8 KB: per-wave [q=16][t'=64], tblk XOR swizzle
  const int tid = threadIdx.x, lane = tid & 63, w = tid >> 6;
  const int l15 = lane & 15, g = lane >> 4;
  const int qt = blockIdx.x, h = blockIdx.y, b = blockIdx.z;
  const size_t base = (size_t)b * SEQ * 768;
  const int q0 = qt * 64;
  const int bh = b * 8 + h;

  // Q fragment (pre-scaled by log2e/sqrt(32) in the QKV epilogue)
  bf16x8 qf = *(const bf16x8*)&qkv[base + (size_t)(q0 + w * 16 + l15) * 768 + h * 32 + g * 8];

  // K staging lane map (per 16-row chunk): [r2][slot], slot' = slot ^ (r2&7)
  const int kr2l  = lane >> 3;
  const int kslot = (lane & 7) ^ kr2l;
  const int krow  = 2 * kr2l + (kslot >> 2);
  const int kdoff = (kslot & 3) * 8;
  const int vd    = lane >> 4;          // V: d sub-row 0..3
  const int vt8   = (lane & 15) * 8;    // V: t offset

  float l_ = 0.f;
  f32x4 o[2];
  o[0] = (f32x4){0.f, 0.f, 0.f, 0.f};
  o[1] = (f32x4){0.f, 0.f, 0.f, 0.f};
  const f32x4 zero = (f32x4){0.f, 0.f, 0.f, 0.f};

  // Ps addresses (q = l15); write: tblk = 2*tt + (g>>1), dword slot (g&1)
  ushort* psw = &Ps[w][0];
  const int ps_q = l15 * 64;

  // stage tile 0
  #pragma unroll
  for (int i = 0; i < 2; ++i) {
    gld_lds16(qkv + base + (size_t)(w * 32 + i * 16 + krow) * 768 + 256 + h * 32 + kdoff,
              &Ks[0][(w * 16 + i * 8) * 64]);
    gld_lds16(vtg + ((size_t)bh * 32 + w * 8 + i * 4 + vd) * 1024 + vt8,
              &Vt[0][(w * 8 + i * 4) * 128]);
  }
  __syncthreads();

  int cur = 0;
  for (int t = 0; t < 8; ++t) {
    if (t < 7) {                         // prefetch next 128-row K/V tile
      int nkv = (t + 1) * 128;
      #pragma unroll
      for (int i = 0; i < 2; ++i) {
        gld_lds16(qkv + base + (size_t)(nkv + w * 32 + i * 16 + krow) * 768 + 256 + h * 32 + kdoff,
                  &Ks[cur ^ 1][(w * 16 + i * 8) * 64]);
        gld_lds16(vtg + ((size_t)bh * 32 + w * 8 + i * 4 + vd) * 1024 + nkv + vt8,
                  &Vt[cur ^ 1][(w * 8 + i * 4) * 128]);
      }
    }
    // S^T = K . Q^T : lane owns q = l15, t-rows ti*16 + g*4 + r, ti 0..7
    f32x4 s[8];
    __builtin_amdgcn_s_setprio(1);
    #pragma unroll
    for (int ti = 0; ti < 8; ++ti) {
      int r2   = ti * 8 + (l15 >> 1);
      int slot = (((l15 & 1) * 4 + g)) ^ (l15 >> 1);
      bf16x8 kf = *(const bf16x8*)&Ks[cur][r2 * 64 + slot * 8];
      s[ti] = __builtin_amdgcn_mfma_f32_16x16x32_bf16(kf, qf, zero, 0, 0, 0);
    }
    __builtin_amdgcn_s_setprio(0);

    // no-max softmax: scores are log2-scaled with |s| << 127 (Q pre-scaled, tiny
    // score variance) -> exp2 cannot overflow; m==0 cancels in P/l exactly.
    float rs = 0.f;
    #pragma unroll
    for (int ti = 0; ti < 8; ++ti)
      #pragma unroll
      for (int r = 0; r < 4; ++r) {
        float p = __builtin_amdgcn_exp2f(s[ti][r]);
        s[ti][r] = p;
        rs += p;
      }
    rs += __shfl_xor(rs, 16);
    rs += __shfl_xor(rs, 32);
    l_ += rs;

    // two half-passes over t: pack P -> wave-private swizzled LDS -> b128 A-frags;
    // V fragments loaded per-pass (halves vb live range vs all-up-front)
    #pragma unroll
    for (int p = 0; p < 2; ++p) {
      #pragma unroll
      for (int tt = 0; tt < 4; ++tt) {
        int ti = p * 4 + tt;
        unsigned lo, hi;
        asm("v_cvt_pk_bf16_f32 %0, %1, %2" : "=v"(lo) : "v"(s[ti][0]), "v"(s[ti][1]));
        asm("v_cvt_pk_bf16_f32 %0, %1, %2" : "=v"(hi) : "v"(s[ti][2]), "v"(s[ti][3]));
        uint2 val; val.x = lo; val.y = hi;
        int tblk = 2 * tt + (g >> 1);
        *(uint2*)&psw[ps_q + ((tblk ^ (l15 & 7)) << 3) + ((g & 1) << 2)] = val;
      }
      bf16x8 vb2[2][2];
      #pragma unroll
      for (int ksp = 0; ksp < 2; ++ksp)
        #pragma unroll
        for (int di = 0; di < 2; ++di) {
          int d = di * 16 + l15;
          vb2[ksp][di] = *(const bf16x8*)&Vt[cur][d * 128 + p * 64 +
                                                 (((ksp * 4 + g) ^ (d & 7)) * 8)];
        }
      __builtin_amdgcn_s_setprio(1);
      #pragma unroll
      for (int ksp = 0; ksp < 2; ++ksp) {
        int tblk = 4 * ksp + g;
        bf16x8 pa = *(const bf16x8*)&psw[ps_q + ((tblk ^ (l15 & 7)) << 3)];
        #pragma unroll
        for (int di = 0; di < 2; ++di)
          o[di] = __builtin_amdgcn_mfma_f32_16x16x32_bf16(pa, vb2[ksp][di], o[di], 0, 0, 0);
      }
      __builtin_amdgcn_s_setprio(0);
    }
    __syncthreads();
    cur ^= 1;
  }

  // normalized store, swizzled bf16 [8192][256]
  #pragma unroll
  for (int r = 0; r < 4; ++r) {
    float lr = __shfl(l_, g * 4 + r);
    float inv = __builtin_amdgcn_rcpf(lr);
    size_t row = (size_t)b * SEQ + q0 + w * 16 + g * 4 + r;
    int rw7 = (g * 4 + r) & 7;
    #pragma unroll
    for (int di = 0; di < 2; ++di) {
      int col = h * 32 + di * 16 + l15;
      att[row * 256 + swz(col, rw7)] = f2bf(o[di][r] * inv);
    }
  }
}

extern "C" void kernel_launch(void* const* d_in, const int* in_sizes, int n_in,
                              void* d_out, int out_size, void* d_ws, size_t ws_size,
                              hipStream_t stream)
{
  const float* x    = (const float*)d_in[0];
  const float* y    = (const float*)d_in[1];
  const float* Wqkv = (const float*)d_in[3];
  const float* bqkv = (const float*)d_in[4];
  const float* Wo   = (const float*)d_in[5];
  const float* bo   = (const float*)d_in[6];
  const float* W1   = (const float*)d_in[7];
  const float* b1   = (const float*)d_in[8];
  const float* W2   = (const float*)d_in[9];
  const float* b2   = (const float*)d_in[10];
  const float* g1   = (const float*)d_in[11];
  const float* be1  = (const float*)d_in[12];
  const float* g2   = (const float*)d_in[13];
  const float* be2  = (const float*)d_in[14];

  float* ws = (float*)d_ws;
  ushort* f_bf   = (ushort*)(ws);                 // [0, 1M) floats: swizzled bf16
  ushort* qkv_bf = (ushort*)(ws + 1048576);       // [1M, 4M): Q(scaled),K linear
  ushort* vt_g   = (ushort*)(ws + 4194304);       // [4M, 5M): vt[bh][32][1024] swizzled
  ushort* att_bf = (ushort*)(ws + 5242880);       // [5M, 6M) swizzled
  ushort* f1_bf  = (ushort*)(ws + 6291456);       // [6M, 7M) swizzled
  ushort* h_bf   = (ushort*)(ws + 7340032);       // [7M, 11M) swizzled
  float*  pos    = ws + 11534336;                 // [11M, +1M) full table
  ushort* wq_bf  = (ushort*)(ws + 12582912);
  ushort* wo_bf  = wq_bf + 196608;
  ushort* w1_bf  = wo_bf + 65536;
  ushort* w2_bf  = w1_bf + 262144;

  prep_kernel<<<1024, 256, 0, stream>>>(Wqkv, Wo, W1, W2, wq_bf, wo_bf, w1_bf, w2_bf, pos);
  build_f_kernel<<<512, 256, 0, stream>>>(x, y, pos, f_bf);
  gemm_mfma_kernel<64, 3, 0><<<dim3(6, 128), 256, 0, stream>>>(
      f_bf, wq_bf, bqkv, qkv_bf, vt_g, NROWS, 768, 256);
  attn_mfma_kernel<<<dim3(16, 8, 8), 256, 0, stream>>>(qkv_bf, vt_g, att_bf);
  gemm_ln_kernel<16, 0><<<512, 512, 0, stream>>>(att_bf, wo_bf, bo, f_bf, g1, be1, nullptr, f1_bf, 256);
  gemm_mfma_kernel<64, 2, 1><<<dim3(8, 128), 256, 0, stream>>>(
      f1_bf, w1_bf, b1, h_bf, nullptr, NROWS, 1024, 256);
  gemm_ln_kernel<16, 1><<<512, 512, 0, stream>>>(h_bf, w2_bf, b2, f1_bf, g2, be2, (float*)d_out, nullptr, 1024);
}

// Round 18
// 86.796 us; speedup vs baseline: 1.2543x; 1.0039x over previous
//
#include <hip/hip_runtime.h>

typedef __attribute__((ext_vector_type(8))) short bf16x8;
typedef __attribute__((ext_vector_type(4))) float f32x4;

#define D_MODEL 256
#define SEQ     1024
#define NROWS   8192

__device__ __forceinline__ ushort f2bf(float f) {
  unsigned u = __float_as_uint(f);
  unsigned r = (u + 0x7FFFu + ((u >> 16) & 1u)) >> 16;
  return (ushort)r;
}
__device__ __forceinline__ float bf2f(ushort b) {
  return __uint_as_float(((unsigned)b) << 16);
}

// async global->LDS, 16B per lane; dst = wave-uniform base + lane*16
__device__ __forceinline__ void gld_lds16(const void* g, void* l) {
  __builtin_amdgcn_global_load_lds(
      (const __attribute__((address_space(1))) void*)g,
      (__attribute__((address_space(3))) void*)l, 16, 0, 0);
}

// XOR-swizzle of 8-element blocks within 64-col groups
__device__ __forceinline__ int swz(int col, int row7) {
  return (col & ~63) | ((((col >> 3) & 7) ^ row7) << 3) | (col & 7);
}

#define QSC 0.25507964954389985f   // log2(e) / sqrt(32)

// -------- 0. prep: weights fp32 -> bf16 pre-swizzled  +  pos table --------
__global__ __launch_bounds__(256) void prep_kernel(
    const float* __restrict__ a, const float* __restrict__ b,
    const float* __restrict__ c, const float* __restrict__ d,
    ushort* __restrict__ oa, ushort* __restrict__ ob,
    ushort* __restrict__ oc, ushort* __restrict__ od,
    float* __restrict__ pos)
{
  int i = blockIdx.x * 256 + threadIdx.x;  // 262144 total
  if (i < 196608) { int r = i >> 8, k = i & 255; oa[(r << 8) + swz(k, r & 7)] = f2bf(a[i]); }
  if (i <  65536) { int r = i >> 8, k = i & 255; ob[(r << 8) + swz(k, r & 7)] = f2bf(b[i]); }
  { int r = i >> 8,  k = i & 255;  oc[(r << 8)  + swz(k, r & 7)] = f2bf(c[i]); }
  { int r = i >> 10, k = i & 1023; od[(r << 10) + swz(k, r & 7)] = f2bf(d[i]); }
  // pos
  {
    int s = i >> 8, cc = i & 255;
    int hh = s >> 5, w = s & 31;
    const float sc = 6.28318530717958647692f / (32.0f + 1e-6f);
    float e;
    int c2 = cc;
    if (c2 < 128) { e = (float)(hh + 1) * sc; }
    else          { e = (float)(w  + 1) * sc; c2 -= 128; }
    int j = c2 >> 1;
    float arg = e * exp2f((float)j * -0.20762050593046014f);  // 10000^(-j/64)
    pos[i] = (c2 & 1) ? cosf(arg) : sinf(arg);
  }
}

// -------- 1. f_bf[row][swz(c)] = transpose(x/y) + 0.1*pos  (bf16 only) --------
__global__ __launch_bounds__(256) void build_f_kernel(
    const float* __restrict__ x, const float* __restrict__ y,
    const float* __restrict__ pos, ushort* __restrict__ fb)
{
  __shared__ float T[64][65];
  int bx = blockIdx.x;                    // 8b * 16st * 4ct = 512
  int b = bx >> 6, st = (bx >> 2) & 15, ct = bx & 3;
  const float* src = (b < 4) ? x : y;
  int bb = b & 3;
  int tid = threadIdx.x;
  {
    int sl = tid & 63, c4 = tid >> 6;
    int s = st * 64 + sl;
    #pragma unroll
    for (int k = 0; k < 16; ++k) {
      int cl = c4 * 16 + k;
      T[cl][sl] = src[((size_t)((bb << 8) + ct * 64 + cl) << 10) + s];
    }
  }
  __syncthreads();
  {
    int cl = tid & 63, s4 = tid >> 6;
    int c = ct * 64 + cl;
    #pragma unroll
    for (int k = 0; k < 16; ++k) {
      int sl = s4 * 16 + k;
      int s = st * 64 + sl;
      float v = T[cl][sl] + 0.1f * pos[s * 256 + c];
      size_t row = (size_t)b * 1024 + s;
      fb[row * 256 + swz(c, s & 7)] = f2bf(v);
    }
  }
}

// -------- 2. MFMA GEMM (BN=128), global_load_lds, pre-swizzled inputs --------
// OUT_MODE: 2 = bf16 swizzled, 3 = qkv fused (Q scaled + linear, K linear, V -> vt swizzled)
template<int BM, int OUT_MODE, int RELU>
__global__ __launch_bounds__(256) void gemm_mfma_kernel(
    const ushort* __restrict__ A, const ushort* __restrict__ B,
    const float* __restrict__ bias, void* __restrict__ Cout,
    ushort* __restrict__ Vout, int M, int N, int K)
{
  constexpr int MI = BM / 32;
  __shared__ ushort Asw[BM * 64];
  __shared__ ushort Bsw[128 * 64];
  const int tid = threadIdx.x, lane = tid & 63, w = tid >> 6;
  const int m0 = blockIdx.y * BM, n0 = blockIdx.x * 128;
  const int wm0 = (w & 1) * (BM / 2), wn0 = (w >> 1) * 64;
  const int l15 = lane & 15, g = lane >> 4;
  const int r8 = lane >> 3, s8 = lane & 7;
  f32x4 acc[MI][4];
  #pragma unroll
  for (int i = 0; i < MI; ++i)
    #pragma unroll
    for (int j = 0; j < 4; ++j) acc[i][j] = (f32x4){0.f, 0.f, 0.f, 0.f};

  for (int kt = 0; kt < K; kt += 64) {
    __syncthreads();
    #pragma unroll
    for (int i = 0; i < BM / 32; ++i) {
      int row0 = w * (BM / 4) + i * 8;
      gld_lds16(A + (size_t)(m0 + row0 + r8) * K + kt + s8 * 8, &Asw[row0 * 64]);
    }
    #pragma unroll
    for (int i = 0; i < 4; ++i) {
      int row0 = w * 32 + i * 8;
      gld_lds16(B + (size_t)(n0 + row0 + r8) * K + kt + s8 * 8, &Bsw[row0 * 64]);
    }
    __syncthreads();
    #pragma unroll
    for (int ks = 0; ks < 2; ++ks) {
      bf16x8 af[MI], bfr[4];
      #pragma unroll
      for (int i = 0; i < MI; ++i) {
        int ra = wm0 + i * 16 + l15;
        af[i] = *(const bf16x8*)&Asw[ra * 64 + (((ks * 4 + g) ^ (ra & 7)) * 8)];
      }
      #pragma unroll
      for (int i = 0; i < 4; ++i) {
        int rb = wn0 + i * 16 + l15;
        bfr[i] = *(const bf16x8*)&Bsw[rb * 64 + (((ks * 4 + g) ^ (rb & 7)) * 8)];
      }
      __builtin_amdgcn_s_setprio(1);
      #pragma unroll
      for (int mi = 0; mi < MI; ++mi)
        #pragma unroll
        for (int ni = 0; ni < 4; ++ni)
          acc[mi][ni] = __builtin_amdgcn_mfma_f32_16x16x32_bf16(
              af[mi], bfr[ni], acc[mi][ni], 0, 0, 0);
      __builtin_amdgcn_s_setprio(0);
    }
  }

  float bv[4];
  #pragma unroll
  for (int ni = 0; ni < 4; ++ni) bv[ni] = bias[n0 + wn0 + ni * 16 + l15];
  #pragma unroll
  for (int mi = 0; mi < MI; ++mi)
    #pragma unroll
    for (int ni = 0; ni < 4; ++ni) {
      int n = n0 + wn0 + ni * 16 + l15;
      float qs = (OUT_MODE == 3 && n < 256) ? QSC : 1.0f;   // fold softmax scale into Q
      float v4[4];
      #pragma unroll
      for (int r = 0; r < 4; ++r) {
        float v = acc[mi][ni][r] + bv[ni];
        if (RELU) v = fmaxf(v, 0.0f);
        v4[r] = v * qs;
      }
      int mb = m0 + wm0 + mi * 16 + g * 4;       // first of 4 consecutive rows
      if (OUT_MODE == 3 && n >= 512) {
        // V column -> vt[bh][d][t], 8-block XOR swizzle on t within 64-groups
        int d = (n - 512) & 31, hh = (n - 512) >> 5;
        int bb = mb >> 10, t0 = mb & 1023;
        uint2 val;
        val.x = (unsigned)f2bf(v4[0]) | ((unsigned)f2bf(v4[1]) << 16);
        val.y = (unsigned)f2bf(v4[2]) | ((unsigned)f2bf(v4[3]) << 16);
        size_t idx = ((size_t)(bb * 8 + hh) * 32 + d) * 1024 + (t0 & ~63)
                   + ((((t0 >> 3) & 7) ^ (d & 7)) * 8) + (t0 & 7);
        *(uint2*)&Vout[idx] = val;
      } else {
        #pragma unroll
        for (int r = 0; r < 4; ++r) {
          size_t m = mb + r;
          if (OUT_MODE == 3) ((ushort*)Cout)[m * N + n] = f2bf(v4[r]);
          else               ((ushort*)Cout)[m * N + swz(n, (int)(m & 7))] = f2bf(v4[r]);
        }
      }
    }
}

// -------- 2b. GEMM (BM rows, BN=256=N) + fused residual + LayerNorm, 8 waves --------
// TRANS_OUT=0: outb = bf16 swizzled.  TRANS_OUT=1: transposed f32 d_out (coalesced via LDS).
template<int BM, int TRANS_OUT>
__global__ __launch_bounds__(512) void gemm_ln_kernel(
    const ushort* __restrict__ A, const ushort* __restrict__ B,
    const float* __restrict__ bias, const ushort* __restrict__ R,
    const float* __restrict__ gamma, const float* __restrict__ beta,
    float* __restrict__ out, ushort* __restrict__ outb, int K)
{
  constexpr int MI = BM / 16;          // m-frags (16 rows each)
  __shared__ ushort Asw[BM * 64];
  __shared__ ushort Bsw[256 * 64];     // 32 KB; reused as f32 transpose tile in epilogue
  __shared__ float red[8][BM][2];
  const int tid = threadIdx.x, lane = tid & 63, w = tid >> 6;   // w 0..7
  const int l15 = lane & 15, g4 = lane >> 4;
  const int r8 = lane >> 3, s8 = lane & 7;
  const int m0 = blockIdx.x * BM;
  const int wn0 = w * 32;
  f32x4 acc[MI][2];
  #pragma unroll
  for (int i = 0; i < MI; ++i)
    #pragma unroll
    for (int j = 0; j < 2; ++j) acc[i][j] = (f32x4){0.f, 0.f, 0.f, 0.f};

  for (int kt = 0; kt < K; kt += 64) {
    __syncthreads();
    if (w < BM / 8)
      gld_lds16(A + (size_t)(m0 + w * 8 + r8) * K + kt + s8 * 8, &Asw[(w * 8) * 64]);
    #pragma unroll
    for (int i = 0; i < 4; ++i) {
      int row0 = w * 32 + i * 8;
      gld_lds16(B + (size_t)(row0 + r8) * K + kt + s8 * 8, &Bsw[row0 * 64]);
    }
    __syncthreads();
    #pragma unroll
    for (int ks = 0; ks < 2; ++ks) {
      bf16x8 af[MI], bfr[2];
      #pragma unroll
      for (int mi = 0; mi < MI; ++mi) {
        int ra = mi * 16 + l15;
        af[mi] = *(const bf16x8*)&Asw[ra * 64 + (((ks * 4 + g4) ^ (ra & 7)) * 8)];
      }
      #pragma unroll
      for (int ni = 0; ni < 2; ++ni) {
        int rb = wn0 + ni * 16 + l15;
        bfr[ni] = *(const bf16x8*)&Bsw[rb * 64 + (((ks * 4 + g4) ^ (rb & 7)) * 8)];
      }
      __builtin_amdgcn_s_setprio(1);
      #pragma unroll
      for (int mi = 0; mi < MI; ++mi)
        #pragma unroll
        for (int ni = 0; ni < 2; ++ni)
          acc[mi][ni] = __builtin_amdgcn_mfma_f32_16x16x32_bf16(
              af[mi], bfr[ni], acc[mi][ni], 0, 0, 0);
      __builtin_amdgcn_s_setprio(0);
    }
  }

  float bv[2], gv[2], bev[2];
  #pragma unroll
  for (int ni = 0; ni < 2; ++ni) {
    int n = wn0 + ni * 16 + l15;
    bv[ni] = bias[n]; gv[ni] = gamma[n]; bev[ni] = beta[n];
  }
  float s1[MI][4], s2[MI][4];
  #pragma unroll
  for (int mi = 0; mi < MI; ++mi)
    #pragma unroll
    for (int r = 0; r < 4; ++r) { s1[mi][r] = 0.f; s2[mi][r] = 0.f; }
  #pragma unroll
  for (int mi = 0; mi < MI; ++mi)
    #pragma unroll
    for (int ni = 0; ni < 2; ++ni)
      #pragma unroll
      for (int r = 0; r < 4; ++r) {
        int row = m0 + mi * 16 + g4 * 4 + r;
        int col = wn0 + ni * 16 + l15;
        float v = acc[mi][ni][r] + bv[ni] + bf2f(R[(size_t)row * 256 + swz(col, row & 7)]);
        acc[mi][ni][r] = v;
        s1[mi][r] += v;
        s2[mi][r] += v * v;
      }
  #pragma unroll
  for (int mi = 0; mi < MI; ++mi)
    #pragma unroll
    for (int r = 0; r < 4; ++r) {
      #pragma unroll
      for (int d = 1; d < 16; d <<= 1) {
        s1[mi][r] += __shfl_xor(s1[mi][r], d);
        s2[mi][r] += __shfl_xor(s2[mi][r], d);
      }
    }
  if (l15 == 0) {
    #pragma unroll
    for (int mi = 0; mi < MI; ++mi)
      #pragma unroll
      for (int r = 0; r < 4; ++r) {
        int rl = mi * 16 + g4 * 4 + r;
        red[w][rl][0] = s1[mi][r];
        red[w][rl][1] = s2[mi][r];
      }
  }
  __syncthreads();     // also guards Bsw reuse below (all K-loop reads done)
  float* Tr = (float*)Bsw;
  #pragma unroll
  for (int mi = 0; mi < MI; ++mi)
    #pragma unroll
    for (int r = 0; r < 4; ++r) {
      int rl = mi * 16 + g4 * 4 + r;
      float t1 = 0.f, t2 = 0.f;
      #pragma unroll
      for (int ww = 0; ww < 8; ++ww) { t1 += red[ww][rl][0]; t2 += red[ww][rl][1]; }
      float mu = t1 * (1.0f / 256.0f);
      float var = t2 * (1.0f / 256.0f) - mu * mu;
      float rstd = rsqrtf(var + 1e-5f);
      int row = m0 + rl;
      #pragma unroll
      for (int ni = 0; ni < 2; ++ni) {
        int col = wn0 + ni * 16 + l15;
        float res = (acc[mi][ni][r] - mu) * rstd * gv[ni] + bev[ni];
        if (!TRANS_OUT) {
          outb[(size_t)row * 256 + swz(col, row & 7)] = f2bf(res);
        } else {
          Tr[rl * 256 + col] = res;
        }
      }
    }
  if (TRANS_OUT) {
    __syncthreads();
    int b = m0 >> 10, sq0 = m0 & 1023;
    int c = tid & 255, half = tid >> 8;
    float* dst = out + ((size_t)b << 18) + ((size_t)c << 10) + sq0 + half * (BM / 2);
    #pragma unroll
    for (int st = 0; st < BM / 8; ++st) {
      float4 v;
      v.x = Tr[(half * (BM / 2) + st * 4 + 0) * 256 + c];
      v.y = Tr[(half * (BM / 2) + st * 4 + 1) * 256 + c];
      v.z = Tr[(half * (BM / 2) + st * 4 + 2) * 256 + c];
      v.w = Tr[(half * (BM / 2) + st * 4 + 3) * 256 + c];
      *(float4*)(dst + st * 4) = v;
    }
  }
}

// -------- 3. MFMA flash attention: 8 waves, 128 q-rows, KVBLK=128, per-tile reduce --------
// launch_bounds(512, 2): 256-VGPR budget -> no spill (r13's failure mode fixed).
__global__ __launch_bounds__(512, 2) void attn_mfma_kernel(
    const ushort* __restrict__ qkv, const ushort* __restrict__ vtg,
    ushort* __restrict__ att)
{
  __shared__ ushort Ks[2][64 * 64];    // 16 KB: [64 r2][64] view of 128 K rows
  __shared__ ushort Vt[2][32 * 128];   // 16 KB
  __shared__ ushort Ps[8][16 * 64];    // 16 KB: per-wave [q=16][t'=64], tblk XOR swizzle
  const int tid = threadIdx.x, lane = tid & 63, w = tid >> 6;   // w 0..7
  const int l15 = lane & 15, g = lane >> 4;
  const int qt = blockIdx.x, h = blockIdx.y, b = blockIdx.z;
  const size_t base = (size_t)b * SEQ * 768;
  const int q0 = qt * 128;
  const int bh = b * 8 + h;

  // Q fragment (pre-scaled by log2e/sqrt(32) in the QKV epilogue)
  bf16x8 qf = *(const bf16x8*)&qkv[base + (size_t)(q0 + w * 16 + l15) * 768 + h * 32 + g * 8];

  // K staging lane map (wave w stages K rows w*16..w*16+15): [r2][slot], slot'=slot^(r2&7)
  const int kr2l  = lane >> 3;
  const int kslot = (lane & 7) ^ kr2l;
  const int krow  = 2 * kr2l + (kslot >> 2);
  const int kdoff = (kslot & 3) * 8;
  const int vd    = lane >> 4;          // V: wave w stages d-rows w*4 + vd
  const int vt8   = (lane & 15) * 8;    // V: t offset

  float l_ = 0.f;
  f32x4 o[2];
  o[0] = (f32x4){0.f, 0.f, 0.f, 0.f};
  o[1] = (f32x4){0.f, 0.f, 0.f, 0.f};
  const f32x4 zero = (f32x4){0.f, 0.f, 0.f, 0.f};

  // Ps addresses (q = l15); write: tblk = 2*tt + (g>>1), dword slot (g&1)
  ushort* psw = &Ps[w][0];
  const int ps_q = l15 * 64;

  // stage tile 0 (each wave: 1 K-gld + 1 V-gld)
  gld_lds16(qkv + base + (size_t)(w * 16 + krow) * 768 + 256 + h * 32 + kdoff,
            &Ks[0][(w * 8) * 64]);
  gld_lds16(vtg + ((size_t)bh * 32 + w * 4 + vd) * 1024 + vt8,
            &Vt[0][(w * 4) * 128]);
  __syncthreads();

  int cur = 0;
  for (int t = 0; t < 8; ++t) {
    if (t < 7) {                         // prefetch next 128-row K/V tile
      int nkv = (t + 1) * 128;
      gld_lds16(qkv + base + (size_t)(nkv + w * 16 + krow) * 768 + 256 + h * 32 + kdoff,
                &Ks[cur ^ 1][(w * 8) * 64]);
      gld_lds16(vtg + ((size_t)bh * 32 + w * 4 + vd) * 1024 + nkv + vt8,
                &Vt[cur ^ 1][(w * 4) * 128]);
    }
    // S^T = K . Q^T : lane owns q = l15, t-rows ti*16 + g*4 + r, ti 0..7
    f32x4 s[8];
    __builtin_amdgcn_s_setprio(1);
    #pragma unroll
    for (int ti = 0; ti < 8; ++ti) {
      int r2   = ti * 8 + (l15 >> 1);
      int slot = (((l15 & 1) * 4 + g)) ^ (l15 >> 1);
      bf16x8 kf = *(const bf16x8*)&Ks[cur][r2 * 64 + slot * 8];
      s[ti] = __builtin_amdgcn_mfma_f32_16x16x32_bf16(kf, qf, zero, 0, 0, 0);
    }
    __builtin_amdgcn_s_setprio(0);

    // no-max softmax: scores are log2-scaled with |s| << 127 (Q pre-scaled, tiny
    // score variance) -> exp2 cannot overflow; m==0 cancels in P/l exactly.
    // Per-tile rs reduce kept (r14: deferring it wrecks regalloc).
    float rs = 0.f;
    #pragma unroll
    for (int ti = 0; ti < 8; ++ti)
      #pragma unroll
      for (int r = 0; r < 4; ++r) {
        float p = __builtin_amdgcn_exp2f(s[ti][r]);
        s[ti][r] = p;
        rs += p;
      }
    rs += __shfl_xor(rs, 16);
    rs += __shfl_xor(rs, 32);
    l_ += rs;

    // two half-passes over t: pack P -> wave-private swizzled LDS -> b128 A-frags;
    // V fragments loaded per-pass (live-range cut)
    #pragma unroll
    for (int p = 0; p < 2; ++p) {
      #pragma unroll
      for (int tt = 0; tt < 4; ++tt) {
        int ti = p * 4 + tt;
        unsigned lo, hi;
        asm("v_cvt_pk_bf16_f32 %0, %1, %2" : "=v"(lo) : "v"(s[ti][0]), "v"(s[ti][1]));
        asm("v_cvt_pk_bf16_f32 %0, %1, %2" : "=v"(hi) : "v"(s[ti][2]), "v"(s[ti][3]));
        uint2 val; val.x = lo; val.y = hi;
        int tblk = 2 * tt + (g >> 1);
        *(uint2*)&psw[ps_q + ((tblk ^ (l15 & 7)) << 3) + ((g & 1) << 2)] = val;
      }
      bf16x8 vb2[2][2];
      #pragma unroll
      for (int ksp = 0; ksp < 2; ++ksp)
        #pragma unroll
        for (int di = 0; di < 2; ++di) {
          int d = di * 16 + l15;
          vb2[ksp][di] = *(const bf16x8*)&Vt[cur][d * 128 + p * 64 +
                                                 (((ksp * 4 + g) ^ (d & 7)) * 8)];
        }
      __builtin_amdgcn_s_setprio(1);
      #pragma unroll
      for (int ksp = 0; ksp < 2; ++ksp) {
        int tblk = 4 * ksp + g;
        bf16x8 pa = *(const bf16x8*)&psw[ps_q + ((tblk ^ (l15 & 7)) << 3)];
        #pragma unroll
        for (int di = 0; di < 2; ++di)
          o[di] = __builtin_amdgcn_mfma_f32_16x16x32_bf16(pa, vb2[ksp][di], o[di], 0, 0, 0);
      }
      __builtin_amdgcn_s_setprio(0);
    }
    __syncthreads();
    cur ^= 1;
  }

  // normalized store, swizzled bf16 [8192][256]
  #pragma unroll
  for (int r = 0; r < 4; ++r) {
    float lr = __shfl(l_, g * 4 + r);
    float inv = __builtin_amdgcn_rcpf(lr);
    size_t row = (size_t)b * SEQ + q0 + w * 16 + g * 4 + r;
    int rw7 = (g * 4 + r) & 7;
    #pragma unroll
    for (int di = 0; di < 2; ++di) {
      int col = h * 32 + di * 16 + l15;
      att[row * 256 + swz(col, rw7)] = f2bf(o[di][r] * inv);
    }
  }
}

extern "C" void kernel_launch(void* const* d_in, const int* in_sizes, int n_in,
                              void* d_out, int out_size, void* d_ws, size_t ws_size,
                              hipStream_t stream)
{
  const float* x    = (const float*)d_in[0];
  const float* y    = (const float*)d_in[1];
  const float* Wqkv = (const float*)d_in[3];
  const float* bqkv = (const float*)d_in[4];
  const float* Wo   = (const float*)d_in[5];
  const float* bo   = (const float*)d_in[6];
  const float* W1   = (const float*)d_in[7];
  const float* b1   = (const float*)d_in[8];
  const float* W2   = (const float*)d_in[9];
  const float* b2   = (const float*)d_in[10];
  const float* g1   = (const float*)d_in[11];
  const float* be1  = (const float*)d_in[12];
  const float* g2   = (const float*)d_in[13];
  const float* be2  = (const float*)d_in[14];

  float* ws = (float*)d_ws;
  ushort* f_bf   = (ushort*)(ws);                 // [0, 1M) floats: swizzled bf16
  ushort* qkv_bf = (ushort*)(ws + 1048576);       // [1M, 4M): Q(scaled),K linear
  ushort* vt_g   = (ushort*)(ws + 4194304);       // [4M, 5M): vt[bh][32][1024] swizzled
  ushort* att_bf = (ushort*)(ws + 5242880);       // [5M, 6M) swizzled
  ushort* f1_bf  = (ushort*)(ws + 6291456);       // [6M, 7M) swizzled
  ushort* h_bf   = (ushort*)(ws + 7340032);       // [7M, 11M) swizzled
  float*  pos    = ws + 11534336;                 // [11M, +1M) full table
  ushort* wq_bf  = (ushort*)(ws + 12582912);
  ushort* wo_bf  = wq_bf + 196608;
  ushort* w1_bf  = wo_bf + 65536;
  ushort* w2_bf  = w1_bf + 262144;

  prep_kernel<<<1024, 256, 0, stream>>>(Wqkv, Wo, W1, W2, wq_bf, wo_bf, w1_bf, w2_bf, pos);
  build_f_kernel<<<512, 256, 0, stream>>>(x, y, pos, f_bf);
  gemm_mfma_kernel<64, 3, 0><<<dim3(6, 128), 256, 0, stream>>>(
      f_bf, wq_bf, bqkv, qkv_bf, vt_g, NROWS, 768, 256);
  attn_mfma_kernel<<<dim3(8, 8, 8), 512, 0, stream>>>(qkv_bf, vt_g, att_bf);
  gemm_ln_kernel<16, 0><<<512, 512, 0, stream>>>(att_bf, wo_bf, bo, f_bf, g1, be1, nullptr, f1_bf, 256);
  gemm_mfma_kernel<64, 2, 1><<<dim3(8, 128), 256, 0, stream>>>(
      f1_bf, w1_bf, b1, h_bf, nullptr, NROWS, 1024, 256);
  gemm_ln_kernel<16, 1><<<512, 512, 0, stream>>>(h_bf, w2_bf, b2, f1_bf, g2, be2, (float*)d_out, nullptr, 1024);
}

// Round 19
// 85.777 us; speedup vs baseline: 1.2692x; 1.0119x over previous
//
#include <hip/hip_runtime.h>

typedef __attribute__((ext_vector_type(8))) short bf16x8;
typedef __attribute__((ext_vector_type(4))) float f32x4;

#define D_MODEL 256
#define SEQ     1024
#define NROWS   8192

__device__ __forceinline__ ushort f2bf(float f) {
  unsigned u = __float_as_uint(f);
  unsigned r = (u + 0x7FFFu + ((u >> 16) & 1u)) >> 16;
  return (ushort)r;
}
__device__ __forceinline__ float bf2f(ushort b) {
  return __uint_as_float(((unsigned)b) << 16);
}

// async global->LDS, 16B per lane; dst = wave-uniform base + lane*16
__device__ __forceinline__ void gld_lds16(const void* g, void* l) {
  __builtin_amdgcn_global_load_lds(
      (const __attribute__((address_space(1))) void*)g,
      (__attribute__((address_space(3))) void*)l, 16, 0, 0);
}

// XOR-swizzle of 8-element blocks within 64-col groups
__device__ __forceinline__ int swz(int col, int row7) {
  return (col & ~63) | ((((col >> 3) & 7) ^ row7) << 3) | (col & 7);
}

#define QSC 0.25507964954389985f   // log2(e) / sqrt(32)

// -------- 0. prep: weights fp32 -> bf16 pre-swizzled  +  pos2 table (8K distinct) --------
__global__ __launch_bounds__(256) void prep_kernel(
    const float* __restrict__ a, const float* __restrict__ b,
    const float* __restrict__ c, const float* __restrict__ d,
    ushort* __restrict__ oa, ushort* __restrict__ ob,
    ushort* __restrict__ oc, ushort* __restrict__ od,
    float* __restrict__ pos2)
{
  int i = blockIdx.x * 256 + threadIdx.x;  // 262144 total
  if (i < 196608) { int r = i >> 8, k = i & 255; oa[(r << 8) + swz(k, r & 7)] = f2bf(a[i]); }
  if (i <  65536) { int r = i >> 8, k = i & 255; ob[(r << 8) + swz(k, r & 7)] = f2bf(b[i]); }
  { int r = i >> 8,  k = i & 255;  oc[(r << 8)  + swz(k, r & 7)] = f2bf(c[i]); }
  { int r = i >> 10, k = i & 1023; od[(r << 10) + swz(k, r & 7)] = f2bf(d[i]); }
  // pos2[part][hw][cidx]: part 0 = y-enc (uses h = s>>5), part 1 = x-enc (uses w = s&31)
  if (i < 8192) {
    int rem = i & 4095, hw = rem >> 7, cidx = rem & 127;
    const float sc = 6.28318530717958647692f / (32.0f + 1e-6f);
    float e = (float)(hw + 1) * sc;
    int j = cidx >> 1;
    float arg = e * exp2f((float)j * -0.20762050593046014f);  // 10000^(-j/64)
    pos2[i] = (cidx & 1) ? cosf(arg) : sinf(arg);
  }
}

// -------- 1. f_bf[row][swz(c)] = transpose(x/y) + 0.1*pos  (bf16 only) --------
__global__ __launch_bounds__(256) void build_f_kernel(
    const float* __restrict__ x, const float* __restrict__ y,
    const float* __restrict__ pos2, ushort* __restrict__ fb)
{
  __shared__ float T[64][65];
  int bx = blockIdx.x;                    // 8b * 16st * 4ct = 512
  int b = bx >> 6, st = (bx >> 2) & 15, ct = bx & 3;
  const float* src = (b < 4) ? x : y;
  int bb = b & 3;
  int tid = threadIdx.x;
  {
    int sl = tid & 63, c4 = tid >> 6;
    int s = st * 64 + sl;
    #pragma unroll
    for (int k = 0; k < 16; ++k) {
      int cl = c4 * 16 + k;
      T[cl][sl] = src[((size_t)((bb << 8) + ct * 64 + cl) << 10) + s];
    }
  }
  __syncthreads();
  {
    int cl = tid & 63, s4 = tid >> 6;
    int c = ct * 64 + cl;
    const float* pt = pos2 + (c >= 128 ? 4096 : 0) + (c & 127);
    #pragma unroll
    for (int k = 0; k < 16; ++k) {
      int sl = s4 * 16 + k;
      int s = st * 64 + sl;
      int hw = (c >= 128) ? (s & 31) : (s >> 5);
      float v = T[cl][sl] + 0.1f * pt[hw * 128];
      size_t row = (size_t)b * 1024 + s;
      fb[row * 256 + swz(c, s & 7)] = f2bf(v);
    }
  }
}

// -------- 2. MFMA GEMM (BN=128), global_load_lds, pre-swizzled inputs --------
// OUT_MODE: 2 = bf16 swizzled, 3 = qkv fused (Q scaled + linear, K linear, V -> vt swizzled)
template<int BM, int OUT_MODE, int RELU>
__global__ __launch_bounds__(256) void gemm_mfma_kernel(
    const ushort* __restrict__ A, const ushort* __restrict__ B,
    const float* __restrict__ bias, void* __restrict__ Cout,
    ushort* __restrict__ Vout, int M, int N, int K)
{
  constexpr int MI = BM / 32;
  __shared__ ushort Asw[BM * 64];
  __shared__ ushort Bsw[128 * 64];
  const int tid = threadIdx.x, lane = tid & 63, w = tid >> 6;
  const int m0 = blockIdx.y * BM, n0 = blockIdx.x * 128;
  const int wm0 = (w & 1) * (BM / 2), wn0 = (w >> 1) * 64;
  const int l15 = lane & 15, g = lane >> 4;
  const int r8 = lane >> 3, s8 = lane & 7;
  f32x4 acc[MI][4];
  #pragma unroll
  for (int i = 0; i < MI; ++i)
    #pragma unroll
    for (int j = 0; j < 4; ++j) acc[i][j] = (f32x4){0.f, 0.f, 0.f, 0.f};

  for (int kt = 0; kt < K; kt += 64) {
    __syncthreads();
    #pragma unroll
    for (int i = 0; i < BM / 32; ++i) {
      int row0 = w * (BM / 4) + i * 8;
      gld_lds16(A + (size_t)(m0 + row0 + r8) * K + kt + s8 * 8, &Asw[row0 * 64]);
    }
    #pragma unroll
    for (int i = 0; i < 4; ++i) {
      int row0 = w * 32 + i * 8;
      gld_lds16(B + (size_t)(n0 + row0 + r8) * K + kt + s8 * 8, &Bsw[row0 * 64]);
    }
    __syncthreads();
    #pragma unroll
    for (int ks = 0; ks < 2; ++ks) {
      bf16x8 af[MI], bfr[4];
      #pragma unroll
      for (int i = 0; i < MI; ++i) {
        int ra = wm0 + i * 16 + l15;
        af[i] = *(const bf16x8*)&Asw[ra * 64 + (((ks * 4 + g) ^ (ra & 7)) * 8)];
      }
      #pragma unroll
      for (int i = 0; i < 4; ++i) {
        int rb = wn0 + i * 16 + l15;
        bfr[i] = *(const bf16x8*)&Bsw[rb * 64 + (((ks * 4 + g) ^ (rb & 7)) * 8)];
      }
      __builtin_amdgcn_s_setprio(1);
      #pragma unroll
      for (int mi = 0; mi < MI; ++mi)
        #pragma unroll
        for (int ni = 0; ni < 4; ++ni)
          acc[mi][ni] = __builtin_amdgcn_mfma_f32_16x16x32_bf16(
              af[mi], bfr[ni], acc[mi][ni], 0, 0, 0);
      __builtin_amdgcn_s_setprio(0);
    }
  }

  float bv[4];
  #pragma unroll
  for (int ni = 0; ni < 4; ++ni) bv[ni] = bias[n0 + wn0 + ni * 16 + l15];
  #pragma unroll
  for (int mi = 0; mi < MI; ++mi)
    #pragma unroll
    for (int ni = 0; ni < 4; ++ni) {
      int n = n0 + wn0 + ni * 16 + l15;
      float qs = (OUT_MODE == 3 && n < 256) ? QSC : 1.0f;   // fold softmax scale into Q
      float v4[4];
      #pragma unroll
      for (int r = 0; r < 4; ++r) {
        float v = acc[mi][ni][r] + bv[ni];
        if (RELU) v = fmaxf(v, 0.0f);
        v4[r] = v * qs;
      }
      int mb = m0 + wm0 + mi * 16 + g * 4;       // first of 4 consecutive rows
      if (OUT_MODE == 3 && n >= 512) {
        // V column -> vt[bh][d][t], 8-block XOR swizzle on t within 64-groups
        int d = (n - 512) & 31, hh = (n - 512) >> 5;
        int bb = mb >> 10, t0 = mb & 1023;
        uint2 val;
        val.x = (unsigned)f2bf(v4[0]) | ((unsigned)f2bf(v4[1]) << 16);
        val.y = (unsigned)f2bf(v4[2]) | ((unsigned)f2bf(v4[3]) << 16);
        size_t idx = ((size_t)(bb * 8 + hh) * 32 + d) * 1024 + (t0 & ~63)
                   + ((((t0 >> 3) & 7) ^ (d & 7)) * 8) + (t0 & 7);
        *(uint2*)&Vout[idx] = val;
      } else {
        #pragma unroll
        for (int r = 0; r < 4; ++r) {
          size_t m = mb + r;
          if (OUT_MODE == 3) ((ushort*)Cout)[m * N + n] = f2bf(v4[r]);
          else               ((ushort*)Cout)[m * N + swz(n, (int)(m & 7))] = f2bf(v4[r]);
        }
      }
    }
}

// -------- 2b. GEMM (BM rows, BN=256=N) + fused residual + LayerNorm, 8 waves --------
// TRANS_OUT=0: outb = bf16 swizzled.  TRANS_OUT=1: transposed f32 d_out (coalesced via LDS).
template<int BM, int TRANS_OUT>
__global__ __launch_bounds__(512) void gemm_ln_kernel(
    const ushort* __restrict__ A, const ushort* __restrict__ B,
    const float* __restrict__ bias, const ushort* __restrict__ R,
    const float* __restrict__ gamma, const float* __restrict__ beta,
    float* __restrict__ out, ushort* __restrict__ outb, int K)
{
  constexpr int MI = BM / 16;          // m-frags (16 rows each)
  __shared__ ushort Asw[BM * 64];
  __shared__ ushort Bsw[256 * 64];     // 32 KB; reused as f32 transpose tile in epilogue
  __shared__ float red[8][BM][2];
  const int tid = threadIdx.x, lane = tid & 63, w = tid >> 6;   // w 0..7
  const int l15 = lane & 15, g4 = lane >> 4;
  const int r8 = lane >> 3, s8 = lane & 7;
  const int m0 = blockIdx.x * BM;
  const int wn0 = w * 32;
  f32x4 acc[MI][2];
  #pragma unroll
  for (int i = 0; i < MI; ++i)
    #pragma unroll
    for (int j = 0; j < 2; ++j) acc[i][j] = (f32x4){0.f, 0.f, 0.f, 0.f};

  for (int kt = 0; kt < K; kt += 64) {
    __syncthreads();
    if (w < BM / 8)
      gld_lds16(A + (size_t)(m0 + w * 8 + r8) * K + kt + s8 * 8, &Asw[(w * 8) * 64]);
    #pragma unroll
    for (int i = 0; i < 4; ++i) {
      int row0 = w * 32 + i * 8;
      gld_lds16(B + (size_t)(row0 + r8) * K + kt + s8 * 8, &Bsw[row0 * 64]);
    }
    __syncthreads();
    #pragma unroll
    for (int ks = 0; ks < 2; ++ks) {
      bf16x8 af[MI], bfr[2];
      #pragma unroll
      for (int mi = 0; mi < MI; ++mi) {
        int ra = mi * 16 + l15;
        af[mi] = *(const bf16x8*)&Asw[ra * 64 + (((ks * 4 + g4) ^ (ra & 7)) * 8)];
      }
      #pragma unroll
      for (int ni = 0; ni < 2; ++ni) {
        int rb = wn0 + ni * 16 + l15;
        bfr[ni] = *(const bf16x8*)&Bsw[rb * 64 + (((ks * 4 + g4) ^ (rb & 7)) * 8)];
      }
      __builtin_amdgcn_s_setprio(1);
      #pragma unroll
      for (int mi = 0; mi < MI; ++mi)
        #pragma unroll
        for (int ni = 0; ni < 2; ++ni)
          acc[mi][ni] = __builtin_amdgcn_mfma_f32_16x16x32_bf16(
              af[mi], bfr[ni], acc[mi][ni], 0, 0, 0);
      __builtin_amdgcn_s_setprio(0);
    }
  }

  float bv[2], gv[2], bev[2];
  #pragma unroll
  for (int ni = 0; ni < 2; ++ni) {
    int n = wn0 + ni * 16 + l15;
    bv[ni] = bias[n]; gv[ni] = gamma[n]; bev[ni] = beta[n];
  }
  float s1[MI][4], s2[MI][4];
  #pragma unroll
  for (int mi = 0; mi < MI; ++mi)
    #pragma unroll
    for (int r = 0; r < 4; ++r) { s1[mi][r] = 0.f; s2[mi][r] = 0.f; }
  #pragma unroll
  for (int mi = 0; mi < MI; ++mi)
    #pragma unroll
    for (int ni = 0; ni < 2; ++ni)
      #pragma unroll
      for (int r = 0; r < 4; ++r) {
        int row = m0 + mi * 16 + g4 * 4 + r;
        int col = wn0 + ni * 16 + l15;
        float v = acc[mi][ni][r] + bv[ni] + bf2f(R[(size_t)row * 256 + swz(col, row & 7)]);
        acc[mi][ni][r] = v;
        s1[mi][r] += v;
        s2[mi][r] += v * v;
      }
  #pragma unroll
  for (int mi = 0; mi < MI; ++mi)
    #pragma unroll
    for (int r = 0; r < 4; ++r) {
      #pragma unroll
      for (int d = 1; d < 16; d <<= 1) {
        s1[mi][r] += __shfl_xor(s1[mi][r], d);
        s2[mi][r] += __shfl_xor(s2[mi][r], d);
      }
    }
  if (l15 == 0) {
    #pragma unroll
    for (int mi = 0; mi < MI; ++mi)
      #pragma unroll
      for (int r = 0; r < 4; ++r) {
        int rl = mi * 16 + g4 * 4 + r;
        red[w][rl][0] = s1[mi][r];
        red[w][rl][1] = s2[mi][r];
      }
  }
  __syncthreads();     // also guards Bsw reuse below (all K-loop reads done)
  float* Tr = (float*)Bsw;
  #pragma unroll
  for (int mi = 0; mi < MI; ++mi)
    #pragma unroll
    for (int r = 0; r < 4; ++r) {
      int rl = mi * 16 + g4 * 4 + r;
      float t1 = 0.f, t2 = 0.f;
      #pragma unroll
      for (int ww = 0; ww < 8; ++ww) { t1 += red[ww][rl][0]; t2 += red[ww][rl][1]; }
      float mu = t1 * (1.0f / 256.0f);
      float var = t2 * (1.0f / 256.0f) - mu * mu;
      float rstd = rsqrtf(var + 1e-5f);
      int row = m0 + rl;
      #pragma unroll
      for (int ni = 0; ni < 2; ++ni) {
        int col = wn0 + ni * 16 + l15;
        float res = (acc[mi][ni][r] - mu) * rstd * gv[ni] + bev[ni];
        if (!TRANS_OUT) {
          outb[(size_t)row * 256 + swz(col, row & 7)] = f2bf(res);
        } else {
          Tr[rl * 256 + col] = res;
        }
      }
    }
  if (TRANS_OUT) {
    __syncthreads();
    int b = m0 >> 10, sq0 = m0 & 1023;
    int c = tid & 255, half = tid >> 8;
    float* dst = out + ((size_t)b << 18) + ((size_t)c << 10) + sq0 + half * (BM / 2);
    #pragma unroll
    for (int st = 0; st < BM / 8; ++st) {
      float4 v;
      v.x = Tr[(half * (BM / 2) + st * 4 + 0) * 256 + c];
      v.y = Tr[(half * (BM / 2) + st * 4 + 1) * 256 + c];
      v.z = Tr[(half * (BM / 2) + st * 4 + 2) * 256 + c];
      v.w = Tr[(half * (BM / 2) + st * 4 + 3) * 256 + c];
      *(float4*)(dst + st * 4) = v;
    }
  }
}

// -------- 3. MFMA flash attention: 8 waves, 128 q-rows, KVBLK=128, per-tile reduce --------
// Grid (bh, qt): all qt-blocks of one (b,h) map to the same XCD (linear id mod 8 = h)
// -> K/V fetched once per L2 instead of 8x.  launch_bounds(512,2): no-spill budget.
__global__ __launch_bounds__(512, 2) void attn_mfma_kernel(
    const ushort* __restrict__ qkv, const ushort* __restrict__ vtg,
    ushort* __restrict__ att)
{
  __shared__ ushort Ks[2][64 * 64];    // 16 KB: [64 r2][64] view of 128 K rows
  __shared__ ushort Vt[2][32 * 128];   // 16 KB
  __shared__ ushort Ps[8][16 * 64];    // 16 KB: per-wave [q=16][t'=64], tblk XOR swizzle
  const int tid = threadIdx.x, lane = tid & 63, w = tid >> 6;   // w 0..7
  const int l15 = lane & 15, g = lane >> 4;
  const int bh = blockIdx.x, qt = blockIdx.y;
  const int b = bh >> 3, h = bh & 7;
  const size_t base = (size_t)b * SEQ * 768;
  const int q0 = qt * 128;

  // Q fragment (pre-scaled by log2e/sqrt(32) in the QKV epilogue)
  bf16x8 qf = *(const bf16x8*)&qkv[base + (size_t)(q0 + w * 16 + l15) * 768 + h * 32 + g * 8];

  // K staging lane map (wave w stages K rows w*16..w*16+15): [r2][slot], slot'=slot^(r2&7)
  const int kr2l  = lane >> 3;
  const int kslot = (lane & 7) ^ kr2l;
  const int krow  = 2 * kr2l + (kslot >> 2);
  const int kdoff = (kslot & 3) * 8;
  const int vd    = lane >> 4;          // V: wave w stages d-rows w*4 + vd
  const int vt8   = (lane & 15) * 8;    // V: t offset

  float l_ = 0.f;
  f32x4 o[2];
  o[0] = (f32x4){0.f, 0.f, 0.f, 0.f};
  o[1] = (f32x4){0.f, 0.f, 0.f, 0.f};
  const f32x4 zero = (f32x4){0.f, 0.f, 0.f, 0.f};

  // Ps addresses (q = l15); write: tblk = 2*tt + (g>>1), dword slot (g&1)
  ushort* psw = &Ps[w][0];
  const int ps_q = l15 * 64;

  // stage tile 0 (each wave: 1 K-gld + 1 V-gld)
  gld_lds16(qkv + base + (size_t)(w * 16 + krow) * 768 + 256 + h * 32 + kdoff,
            &Ks[0][(w * 8) * 64]);
  gld_lds16(vtg + ((size_t)bh * 32 + w * 4 + vd) * 1024 + vt8,
            &Vt[0][(w * 4) * 128]);
  __syncthreads();

  int cur = 0;
  for (int t = 0; t < 8; ++t) {
    if (t < 7) {                         // prefetch next 128-row K/V tile
      int nkv = (t + 1) * 128;
      gld_lds16(qkv + base + (size_t)(nkv + w * 16 + krow) * 768 + 256 + h * 32 + kdoff,
                &Ks[cur ^ 1][(w * 8) * 64]);
      gld_lds16(vtg + ((size_t)bh * 32 + w * 4 + vd) * 1024 + nkv + vt8,
                &Vt[cur ^ 1][(w * 4) * 128]);
    }
    // S^T = K . Q^T : lane owns q = l15, t-rows ti*16 + g*4 + r, ti 0..7
    f32x4 s[8];
    __builtin_amdgcn_s_setprio(1);
    #pragma unroll
    for (int ti = 0; ti < 8; ++ti) {
      int r2   = ti * 8 + (l15 >> 1);
      int slot = (((l15 & 1) * 4 + g)) ^ (l15 >> 1);
      bf16x8 kf = *(const bf16x8*)&Ks[cur][r2 * 64 + slot * 8];
      s[ti] = __builtin_amdgcn_mfma_f32_16x16x32_bf16(kf, qf, zero, 0, 0, 0);
    }
    __builtin_amdgcn_s_setprio(0);

    // no-max softmax: scores are log2-scaled with |s| << 127 (Q pre-scaled, tiny
    // score variance) -> exp2 cannot overflow; m==0 cancels in P/l exactly.
    // Per-tile rs reduce kept (r14: deferring it wrecks regalloc).
    float rs = 0.f;
    #pragma unroll
    for (int ti = 0; ti < 8; ++ti)
      #pragma unroll
      for (int r = 0; r < 4; ++r) {
        float p = __builtin_amdgcn_exp2f(s[ti][r]);
        s[ti][r] = p;
        rs += p;
      }
    rs += __shfl_xor(rs, 16);
    rs += __shfl_xor(rs, 32);
    l_ += rs;

    // two half-passes over t: pack P -> wave-private swizzled LDS -> b128 A-frags;
    // V fragments loaded per-pass (live-range cut)
    #pragma unroll
    for (int p = 0; p < 2; ++p) {
      #pragma unroll
      for (int tt = 0; tt < 4; ++tt) {
        int ti = p * 4 + tt;
        unsigned lo, hi;
        asm("v_cvt_pk_bf16_f32 %0, %1, %2" : "=v"(lo) : "v"(s[ti][0]), "v"(s[ti][1]));
        asm("v_cvt_pk_bf16_f32 %0, %1, %2" : "=v"(hi) : "v"(s[ti][2]), "v"(s[ti][3]));
        uint2 val; val.x = lo; val.y = hi;
        int tblk = 2 * tt + (g >> 1);
        *(uint2*)&psw[ps_q + ((tblk ^ (l15 & 7)) << 3) + ((g & 1) << 2)] = val;
      }
      bf16x8 vb2[2][2];
      #pragma unroll
      for (int ksp = 0; ksp < 2; ++ksp)
        #pragma unroll
        for (int di = 0; di < 2; ++di) {
          int d = di * 16 + l15;
          vb2[ksp][di] = *(const bf16x8*)&Vt[cur][d * 128 + p * 64 +
                                                 (((ksp * 4 + g) ^ (d & 7)) * 8)];
        }
      __builtin_amdgcn_s_setprio(1);
      #pragma unroll
      for (int ksp = 0; ksp < 2; ++ksp) {
        int tblk = 4 * ksp + g;
        bf16x8 pa = *(const bf16x8*)&psw[ps_q + ((tblk ^ (l15 & 7)) << 3)];
        #pragma unroll
        for (int di = 0; di < 2; ++di)
          o[di] = __builtin_amdgcn_mfma_f32_16x16x32_bf16(pa, vb2[ksp][di], o[di], 0, 0, 0);
      }
      __builtin_amdgcn_s_setprio(0);
    }
    __syncthreads();
    cur ^= 1;
  }

  // normalized store, swizzled bf16 [8192][256]
  #pragma unroll
  for (int r = 0; r < 4; ++r) {
    float lr = __shfl(l_, g * 4 + r);
    float inv = __builtin_amdgcn_rcpf(lr);
    size_t row = (size_t)b * SEQ + q0 + w * 16 + g * 4 + r;
    int rw7 = (g * 4 + r) & 7;
    #pragma unroll
    for (int di = 0; di < 2; ++di) {
      int col = h * 32 + di * 16 + l15;
      att[row * 256 + swz(col, rw7)] = f2bf(o[di][r] * inv);
    }
  }
}

extern "C" void kernel_launch(void* const* d_in, const int* in_sizes, int n_in,
                              void* d_out, int out_size, void* d_ws, size_t ws_size,
                              hipStream_t stream)
{
  const float* x    = (const float*)d_in[0];
  const float* y    = (const float*)d_in[1];
  const float* Wqkv = (const float*)d_in[3];
  const float* bqkv = (const float*)d_in[4];
  const float* Wo   = (const float*)d_in[5];
  const float* bo   = (const float*)d_in[6];
  const float* W1   = (const float*)d_in[7];
  const float* b1   = (const float*)d_in[8];
  const float* W2   = (const float*)d_in[9];
  const float* b2   = (const float*)d_in[10];
  const float* g1   = (const float*)d_in[11];
  const float* be1  = (const float*)d_in[12];
  const float* g2   = (const float*)d_in[13];
  const float* be2  = (const float*)d_in[14];

  float* ws = (float*)d_ws;
  ushort* f_bf   = (ushort*)(ws);                 // [0, 1M) floats: swizzled bf16
  ushort* qkv_bf = (ushort*)(ws + 1048576);       // [1M, 4M): Q(scaled),K linear
  ushort* vt_g   = (ushort*)(ws + 4194304);       // [4M, 5M): vt[bh][32][1024] swizzled
  ushort* att_bf = (ushort*)(ws + 5242880);       // [5M, 6M) swizzled
  ushort* f1_bf  = (ushort*)(ws + 6291456);       // [6M, 7M) swizzled
  ushort* h_bf   = (ushort*)(ws + 7340032);       // [7M, 11M) swizzled
  float*  pos    = ws + 11534336;                 // [11M, +8K) distinct-value table
  ushort* wq_bf  = (ushort*)(ws + 12582912);
  ushort* wo_bf  = wq_bf + 196608;
  ushort* w1_bf  = wo_bf + 65536;
  ushort* w2_bf  = w1_bf + 262144;

  prep_kernel<<<1024, 256, 0, stream>>>(Wqkv, Wo, W1, W2, wq_bf, wo_bf, w1_bf, w2_bf, pos);
  build_f_kernel<<<512, 256, 0, stream>>>(x, y, pos, f_bf);
  gemm_mfma_kernel<64, 3, 0><<<dim3(6, 128), 256, 0, stream>>>(
      f_bf, wq_bf, bqkv, qkv_bf, vt_g, NROWS, 768, 256);
  attn_mfma_kernel<<<dim3(64, 8), 512, 0, stream>>>(qkv_bf, vt_g, att_bf);
  gemm_ln_kernel<16, 0><<<512, 512, 0, stream>>>(att_bf, wo_bf, bo, f_bf, g1, be1, nullptr, f1_bf, 256);
  gemm_mfma_kernel<64, 2, 1><<<dim3(8, 128), 256, 0, stream>>>(
      f1_bf, w1_bf, b1, h_bf, nullptr, NROWS, 1024, 256);
  gemm_ln_kernel<16, 1><<<512, 512, 0, stream>>>(h_bf, w2_bf, b2, f1_bf, g2, be2, (float*)d_out, nullptr, 1024);
}

// Round 20
// 84.958 us; speedup vs baseline: 1.2814x; 1.0096x over previous
//
#include <hip/hip_runtime.h>

typedef __attribute__((ext_vector_type(8))) short bf16x8;
typedef __attribute__((ext_vector_type(4))) float f32x4;

#define D_MODEL 256
#define SEQ     1024
#define NROWS   8192

__device__ __forceinline__ ushort f2bf(float f) {
  unsigned u = __float_as_uint(f);
  unsigned r = (u + 0x7FFFu + ((u >> 16) & 1u)) >> 16;
  return (ushort)r;
}
__device__ __forceinline__ float bf2f(ushort b) {
  return __uint_as_float(((unsigned)b) << 16);
}

// async global->LDS, 16B per lane; dst = wave-uniform base + lane*16
__device__ __forceinline__ void gld_lds16(const void* g, void* l) {
  __builtin_amdgcn_global_load_lds(
      (const __attribute__((address_space(1))) void*)g,
      (__attribute__((address_space(3))) void*)l, 16, 0, 0);
}

// XOR-swizzle of 8-element blocks within 64-col groups
__device__ __forceinline__ int swz(int col, int row7) {
  return (col & ~63) | ((((col >> 3) & 7) ^ row7) << 3) | (col & 7);
}

#define QSC 0.25507964954389985f   // log2(e) / sqrt(32)

// -------- 0. prep: weights fp32 -> bf16 pre-swizzled  +  pos2 table (8K distinct) --------
__global__ __launch_bounds__(256) void prep_kernel(
    const float* __restrict__ a, const float* __restrict__ b,
    const float* __restrict__ c, const float* __restrict__ d,
    ushort* __restrict__ oa, ushort* __restrict__ ob,
    ushort* __restrict__ oc, ushort* __restrict__ od,
    float* __restrict__ pos2)
{
  int i = blockIdx.x * 256 + threadIdx.x;  // 262144 total
  if (i < 196608) { int r = i >> 8, k = i & 255; oa[(r << 8) + swz(k, r & 7)] = f2bf(a[i]); }
  if (i <  65536) { int r = i >> 8, k = i & 255; ob[(r << 8) + swz(k, r & 7)] = f2bf(b[i]); }
  { int r = i >> 8,  k = i & 255;  oc[(r << 8)  + swz(k, r & 7)] = f2bf(c[i]); }
  { int r = i >> 10, k = i & 1023; od[(r << 10) + swz(k, r & 7)] = f2bf(d[i]); }
  // pos2[part][hw][cidx]: part 0 = y-enc (uses h = s>>5), part 1 = x-enc (uses w = s&31)
  if (i < 8192) {
    int rem = i & 4095, hw = rem >> 7, cidx = rem & 127;
    const float sc = 6.28318530717958647692f / (32.0f + 1e-6f);
    float e = (float)(hw + 1) * sc;
    int j = cidx >> 1;
    float arg = e * exp2f((float)j * -0.20762050593046014f);  // 10000^(-j/64)
    pos2[i] = (cidx & 1) ? cosf(arg) : sinf(arg);
  }
}

// -------- 1. f_bf[row][swz(c)] = transpose(x/y) + 0.1*pos  (bf16 only) --------
__global__ __launch_bounds__(256) void build_f_kernel(
    const float* __restrict__ x, const float* __restrict__ y,
    const float* __restrict__ pos2, ushort* __restrict__ fb)
{
  __shared__ float T[64][65];
  int bx = blockIdx.x;                    // 8b * 16st * 4ct = 512
  int b = bx >> 6, st = (bx >> 2) & 15, ct = bx & 3;
  const float* src = (b < 4) ? x : y;
  int bb = b & 3;
  int tid = threadIdx.x;
  {
    int sl = tid & 63, c4 = tid >> 6;
    int s = st * 64 + sl;
    #pragma unroll
    for (int k = 0; k < 16; ++k) {
      int cl = c4 * 16 + k;
      T[cl][sl] = src[((size_t)((bb << 8) + ct * 64 + cl) << 10) + s];
    }
  }
  __syncthreads();
  {
    int cl = tid & 63, s4 = tid >> 6;
    int c = ct * 64 + cl;
    const float* pt = pos2 + (c >= 128 ? 4096 : 0) + (c & 127);
    #pragma unroll
    for (int k = 0; k < 16; ++k) {
      int sl = s4 * 16 + k;
      int s = st * 64 + sl;
      int hw = (c >= 128) ? (s & 31) : (s >> 5);
      float v = T[cl][sl] + 0.1f * pt[hw * 128];
      size_t row = (size_t)b * 1024 + s;
      fb[row * 256 + swz(c, s & 7)] = f2bf(v);
    }
  }
}

// -------- 2. MFMA GEMM (BN=128), global_load_lds, pre-swizzled inputs --------
// OUT_MODE: 2 = bf16 swizzled, 3 = qkv fused (Q scaled + linear, K linear, V -> vt swizzled)
template<int BM, int OUT_MODE, int RELU>
__global__ __launch_bounds__(256) void gemm_mfma_kernel(
    const ushort* __restrict__ A, const ushort* __restrict__ B,
    const float* __restrict__ bias, void* __restrict__ Cout,
    ushort* __restrict__ Vout, int M, int N, int K)
{
  constexpr int MI = BM / 32;
  __shared__ ushort Asw[BM * 64];
  __shared__ ushort Bsw[128 * 64];
  const int tid = threadIdx.x, lane = tid & 63, w = tid >> 6;
  const int m0 = blockIdx.y * BM, n0 = blockIdx.x * 128;
  const int wm0 = (w & 1) * (BM / 2), wn0 = (w >> 1) * 64;
  const int l15 = lane & 15, g = lane >> 4;
  const int r8 = lane >> 3, s8 = lane & 7;
  f32x4 acc[MI][4];
  #pragma unroll
  for (int i = 0; i < MI; ++i)
    #pragma unroll
    for (int j = 0; j < 4; ++j) acc[i][j] = (f32x4){0.f, 0.f, 0.f, 0.f};

  for (int kt = 0; kt < K; kt += 64) {
    __syncthreads();
    #pragma unroll
    for (int i = 0; i < BM / 32; ++i) {
      int row0 = w * (BM / 4) + i * 8;
      gld_lds16(A + (size_t)(m0 + row0 + r8) * K + kt + s8 * 8, &Asw[row0 * 64]);
    }
    #pragma unroll
    for (int i = 0; i < 4; ++i) {
      int row0 = w * 32 + i * 8;
      gld_lds16(B + (size_t)(n0 + row0 + r8) * K + kt + s8 * 8, &Bsw[row0 * 64]);
    }
    __syncthreads();
    #pragma unroll
    for (int ks = 0; ks < 2; ++ks) {
      bf16x8 af[MI], bfr[4];
      #pragma unroll
      for (int i = 0; i < MI; ++i) {
        int ra = wm0 + i * 16 + l15;
        af[i] = *(const bf16x8*)&Asw[ra * 64 + (((ks * 4 + g) ^ (ra & 7)) * 8)];
      }
      #pragma unroll
      for (int i = 0; i < 4; ++i) {
        int rb = wn0 + i * 16 + l15;
        bfr[i] = *(const bf16x8*)&Bsw[rb * 64 + (((ks * 4 + g) ^ (rb & 7)) * 8)];
      }
      __builtin_amdgcn_s_setprio(1);
      #pragma unroll
      for (int mi = 0; mi < MI; ++mi)
        #pragma unroll
        for (int ni = 0; ni < 4; ++ni)
          acc[mi][ni] = __builtin_amdgcn_mfma_f32_16x16x32_bf16(
              af[mi], bfr[ni], acc[mi][ni], 0, 0, 0);
      __builtin_amdgcn_s_setprio(0);
    }
  }

  float bv[4];
  #pragma unroll
  for (int ni = 0; ni < 4; ++ni) bv[ni] = bias[n0 + wn0 + ni * 16 + l15];
  #pragma unroll
  for (int mi = 0; mi < MI; ++mi)
    #pragma unroll
    for (int ni = 0; ni < 4; ++ni) {
      int n = n0 + wn0 + ni * 16 + l15;
      float qs = (OUT_MODE == 3 && n < 256) ? QSC : 1.0f;   // fold softmax scale into Q
      float v4[4];
      #pragma unroll
      for (int r = 0; r < 4; ++r) {
        float v = acc[mi][ni][r] + bv[ni];
        if (RELU) v = fmaxf(v, 0.0f);
        v4[r] = v * qs;
      }
      int mb = m0 + wm0 + mi * 16 + g * 4;       // first of 4 consecutive rows
      if (OUT_MODE == 3 && n >= 512) {
        // V column -> vt[bh][d][t], 8-block XOR swizzle on t within 64-groups
        int d = (n - 512) & 31, hh = (n - 512) >> 5;
        int bb = mb >> 10, t0 = mb & 1023;
        uint2 val;
        val.x = (unsigned)f2bf(v4[0]) | ((unsigned)f2bf(v4[1]) << 16);
        val.y = (unsigned)f2bf(v4[2]) | ((unsigned)f2bf(v4[3]) << 16);
        size_t idx = ((size_t)(bb * 8 + hh) * 32 + d) * 1024 + (t0 & ~63)
                   + ((((t0 >> 3) & 7) ^ (d & 7)) * 8) + (t0 & 7);
        *(uint2*)&Vout[idx] = val;
      } else {
        #pragma unroll
        for (int r = 0; r < 4; ++r) {
          size_t m = mb + r;
          if (OUT_MODE == 3) ((ushort*)Cout)[m * N + n] = f2bf(v4[r]);
          else               ((ushort*)Cout)[m * N + swz(n, (int)(m & 7))] = f2bf(v4[r]);
        }
      }
    }
}

// -------- 2b. GEMM (BM rows, BN=256=N) + fused residual + LayerNorm, 8 waves --------
// TRANS_OUT=0: outb = bf16 swizzled.  TRANS_OUT=1: transposed f32 d_out (coalesced via LDS).
template<int BM, int TRANS_OUT>
__global__ __launch_bounds__(512) void gemm_ln_kernel(
    const ushort* __restrict__ A, const ushort* __restrict__ B,
    const float* __restrict__ bias, const ushort* __restrict__ R,
    const float* __restrict__ gamma, const float* __restrict__ beta,
    float* __restrict__ out, ushort* __restrict__ outb, int K)
{
  constexpr int MI = BM / 16;          // m-frags (16 rows each)
  __shared__ ushort Asw[BM * 64];
  __shared__ ushort Bsw[256 * 64];     // 32 KB; reused as f32 transpose tile in epilogue
  __shared__ float red[8][BM][2];
  const int tid = threadIdx.x, lane = tid & 63, w = tid >> 6;   // w 0..7
  const int l15 = lane & 15, g4 = lane >> 4;
  const int r8 = lane >> 3, s8 = lane & 7;
  const int m0 = blockIdx.x * BM;
  const int wn0 = w * 32;
  f32x4 acc[MI][2];
  #pragma unroll
  for (int i = 0; i < MI; ++i)
    #pragma unroll
    for (int j = 0; j < 2; ++j) acc[i][j] = (f32x4){0.f, 0.f, 0.f, 0.f};

  for (int kt = 0; kt < K; kt += 64) {
    __syncthreads();
    if (w < BM / 8)
      gld_lds16(A + (size_t)(m0 + w * 8 + r8) * K + kt + s8 * 8, &Asw[(w * 8) * 64]);
    #pragma unroll
    for (int i = 0; i < 4; ++i) {
      int row0 = w * 32 + i * 8;
      gld_lds16(B + (size_t)(row0 + r8) * K + kt + s8 * 8, &Bsw[row0 * 64]);
    }
    __syncthreads();
    #pragma unroll
    for (int ks = 0; ks < 2; ++ks) {
      bf16x8 af[MI], bfr[2];
      #pragma unroll
      for (int mi = 0; mi < MI; ++mi) {
        int ra = mi * 16 + l15;
        af[mi] = *(const bf16x8*)&Asw[ra * 64 + (((ks * 4 + g4) ^ (ra & 7)) * 8)];
      }
      #pragma unroll
      for (int ni = 0; ni < 2; ++ni) {
        int rb = wn0 + ni * 16 + l15;
        bfr[ni] = *(const bf16x8*)&Bsw[rb * 64 + (((ks * 4 + g4) ^ (rb & 7)) * 8)];
      }
      __builtin_amdgcn_s_setprio(1);
      #pragma unroll
      for (int mi = 0; mi < MI; ++mi)
        #pragma unroll
        for (int ni = 0; ni < 2; ++ni)
          acc[mi][ni] = __builtin_amdgcn_mfma_f32_16x16x32_bf16(
              af[mi], bfr[ni], acc[mi][ni], 0, 0, 0);
      __builtin_amdgcn_s_setprio(0);
    }
  }

  float bv[2], gv[2], bev[2];
  #pragma unroll
  for (int ni = 0; ni < 2; ++ni) {
    int n = wn0 + ni * 16 + l15;
    bv[ni] = bias[n]; gv[ni] = gamma[n]; bev[ni] = beta[n];
  }
  float s1[MI][4], s2[MI][4];
  #pragma unroll
  for (int mi = 0; mi < MI; ++mi)
    #pragma unroll
    for (int r = 0; r < 4; ++r) { s1[mi][r] = 0.f; s2[mi][r] = 0.f; }
  #pragma unroll
  for (int mi = 0; mi < MI; ++mi)
    #pragma unroll
    for (int ni = 0; ni < 2; ++ni)
      #pragma unroll
      for (int r = 0; r < 4; ++r) {
        int row = m0 + mi * 16 + g4 * 4 + r;
        int col = wn0 + ni * 16 + l15;
        float v = acc[mi][ni][r] + bv[ni] + bf2f(R[(size_t)row * 256 + swz(col, row & 7)]);
        acc[mi][ni][r] = v;
        s1[mi][r] += v;
        s2[mi][r] += v * v;
      }
  #pragma unroll
  for (int mi = 0; mi < MI; ++mi)
    #pragma unroll
    for (int r = 0; r < 4; ++r) {
      #pragma unroll
      for (int d = 1; d < 16; d <<= 1) {
        s1[mi][r] += __shfl_xor(s1[mi][r], d);
        s2[mi][r] += __shfl_xor(s2[mi][r], d);
      }
    }
  if (l15 == 0) {
    #pragma unroll
    for (int mi = 0; mi < MI; ++mi)
      #pragma unroll
      for (int r = 0; r < 4; ++r) {
        int rl = mi * 16 + g4 * 4 + r;
        red[w][rl][0] = s1[mi][r];
        red[w][rl][1] = s2[mi][r];
      }
  }
  __syncthreads();     // also guards Bsw reuse below (all K-loop reads done)
  float* Tr = (float*)Bsw;
  #pragma unroll
  for (int mi = 0; mi < MI; ++mi)
    #pragma unroll
    for (int r = 0; r < 4; ++r) {
      int rl = mi * 16 + g4 * 4 + r;
      float t1 = 0.f, t2 = 0.f;
      #pragma unroll
      for (int ww = 0; ww < 8; ++ww) { t1 += red[ww][rl][0]; t2 += red[ww][rl][1]; }
      float mu = t1 * (1.0f / 256.0f);
      float var = t2 * (1.0f / 256.0f) - mu * mu;
      float rstd = rsqrtf(var + 1e-5f);
      int row = m0 + rl;
      #pragma unroll
      for (int ni = 0; ni < 2; ++ni) {
        int col = wn0 + ni * 16 + l15;
        float res = (acc[mi][ni][r] - mu) * rstd * gv[ni] + bev[ni];
        if (!TRANS_OUT) {
          outb[(size_t)row * 256 + swz(col, row & 7)] = f2bf(res);
        } else {
          Tr[rl * 256 + col] = res;
        }
      }
    }
  if (TRANS_OUT) {
    __syncthreads();
    int b = m0 >> 10, sq0 = m0 & 1023;
    int c = tid & 255, half = tid >> 8;
    float* dst = out + ((size_t)b << 18) + ((size_t)c << 10) + sq0 + half * (BM / 2);
    #pragma unroll
    for (int st = 0; st < BM / 8; ++st) {
      float4 v;
      v.x = Tr[(half * (BM / 2) + st * 4 + 0) * 256 + c];
      v.y = Tr[(half * (BM / 2) + st * 4 + 1) * 256 + c];
      v.z = Tr[(half * (BM / 2) + st * 4 + 2) * 256 + c];
      v.w = Tr[(half * (BM / 2) + st * 4 + 3) * 256 + c];
      *(float4*)(dst + st * 4) = v;
    }
  }
}

// -------- 3. MFMA flash attention: 8 waves, 128 q-rows, KVBLK=128, per-tile reduce --------
// Grid (bh, qt): all qt-blocks of one (b,h) map to the same XCD (linear id mod 8 = h)
// -> K/V fetched once per L2 instead of 8x.  launch_bounds(512,2): no-spill budget.
__global__ __launch_bounds__(512, 2) void attn_mfma_kernel(
    const ushort* __restrict__ qkv, const ushort* __restrict__ vtg,
    ushort* __restrict__ att)
{
  __shared__ ushort Ks[2][64 * 64];    // 16 KB: [64 r2][64] view of 128 K rows
  __shared__ ushort Vt[2][32 * 128];   // 16 KB
  __shared__ ushort Ps[8][16 * 64];    // 16 KB: per-wave [q=16][t'=64], tblk XOR swizzle
  const int tid = threadIdx.x, lane = tid & 63, w = tid >> 6;   // w 0..7
  const int l15 = lane & 15, g = lane >> 4;
  const int bh = blockIdx.x, qt = blockIdx.y;
  const int b = bh >> 3, h = bh & 7;
  const size_t base = (size_t)b * SEQ * 768;
  const int q0 = qt * 128;

  // Q fragment (pre-scaled by log2e/sqrt(32) in the QKV epilogue)
  bf16x8 qf = *(const bf16x8*)&qkv[base + (size_t)(q0 + w * 16 + l15) * 768 + h * 32 + g * 8];

  // K staging lane map (wave w stages K rows w*16..w*16+15): [r2][slot], slot'=slot^(r2&7)
  const int kr2l  = lane >> 3;
  const int kslot = (lane & 7) ^ kr2l;
  const int krow  = 2 * kr2l + (kslot >> 2);
  const int kdoff = (kslot & 3) * 8;
  const int vd    = lane >> 4;          // V: wave w stages d-rows w*4 + vd
  const int vt8   = (lane & 15) * 8;    // V: t offset

  float l_ = 0.f;
  f32x4 o[2];
  o[0] = (f32x4){0.f, 0.f, 0.f, 0.f};
  o[1] = (f32x4){0.f, 0.f, 0.f, 0.f};
  const f32x4 zero = (f32x4){0.f, 0.f, 0.f, 0.f};

  // Ps addresses (q = l15); write: tblk = 2*tt + (g>>1), dword slot (g&1)
  ushort* psw = &Ps[w][0];
  const int ps_q = l15 * 64;

  // stage tile 0 (each wave: 1 K-gld + 1 V-gld)
  gld_lds16(qkv + base + (size_t)(w * 16 + krow) * 768 + 256 + h * 32 + kdoff,
            &Ks[0][(w * 8) * 64]);
  gld_lds16(vtg + ((size_t)bh * 32 + w * 4 + vd) * 1024 + vt8,
            &Vt[0][(w * 4) * 128]);
  __syncthreads();

  int cur = 0;
  for (int t = 0; t < 8; ++t) {
    if (t < 7) {                         // prefetch next 128-row K/V tile
      int nkv = (t + 1) * 128;
      gld_lds16(qkv + base + (size_t)(nkv + w * 16 + krow) * 768 + 256 + h * 32 + kdoff,
                &Ks[cur ^ 1][(w * 8) * 64]);
      gld_lds16(vtg + ((size_t)bh * 32 + w * 4 + vd) * 1024 + nkv + vt8,
                &Vt[cur ^ 1][(w * 4) * 128]);
    }
    // S^T = K . Q^T : lane owns q = l15, t-rows ti*16 + g*4 + r, ti 0..7
    f32x4 s[8];
    __builtin_amdgcn_s_setprio(1);
    #pragma unroll
    for (int ti = 0; ti < 8; ++ti) {
      int r2   = ti * 8 + (l15 >> 1);
      int slot = (((l15 & 1) * 4 + g)) ^ (l15 >> 1);
      bf16x8 kf = *(const bf16x8*)&Ks[cur][r2 * 64 + slot * 8];
      s[ti] = __builtin_amdgcn_mfma_f32_16x16x32_bf16(kf, qf, zero, 0, 0, 0);
    }
    __builtin_amdgcn_s_setprio(0);

    // no-max softmax: scores log2-scaled, |s| << 127 -> exp2 cannot overflow.
    // 4 independent accumulators (dep chain 32 -> 8); per-tile reduce kept (r14).
    float rsA[4] = {0.f, 0.f, 0.f, 0.f};
    #pragma unroll
    for (int ti = 0; ti < 8; ++ti)
      #pragma unroll
      for (int r = 0; r < 4; ++r) {
        float p = __builtin_amdgcn_exp2f(s[ti][r]);
        s[ti][r] = p;
        rsA[r] += p;
      }
    float rs = (rsA[0] + rsA[1]) + (rsA[2] + rsA[3]);
    rs += __shfl_xor(rs, 16);
    rs += __shfl_xor(rs, 32);
    l_ += rs;

    // two half-passes over t: pack P -> wave-private swizzled LDS -> b128 A-frags;
    // V fragments loaded per-pass (live-range cut)
    #pragma unroll
    for (int p = 0; p < 2; ++p) {
      #pragma unroll
      for (int tt = 0; tt < 4; ++tt) {
        int ti = p * 4 + tt;
        unsigned lo, hi;
        asm("v_cvt_pk_bf16_f32 %0, %1, %2" : "=v"(lo) : "v"(s[ti][0]), "v"(s[ti][1]));
        asm("v_cvt_pk_bf16_f32 %0, %1, %2" : "=v"(hi) : "v"(s[ti][2]), "v"(s[ti][3]));
        uint2 val; val.x = lo; val.y = hi;
        int tblk = 2 * tt + (g >> 1);
        *(uint2*)&psw[ps_q + ((tblk ^ (l15 & 7)) << 3) + ((g & 1) << 2)] = val;
      }
      bf16x8 vb2[2][2];
      #pragma unroll
      for (int ksp = 0; ksp < 2; ++ksp)
        #pragma unroll
        for (int di = 0; di < 2; ++di) {
          int d = di * 16 + l15;
          vb2[ksp][di] = *(const bf16x8*)&Vt[cur][d * 128 + p * 64 +
                                                 (((ksp * 4 + g) ^ (d & 7)) * 8)];
        }
      __builtin_amdgcn_s_setprio(1);
      #pragma unroll
      for (int ksp = 0; ksp < 2; ++ksp) {
        int tblk = 4 * ksp + g;
        bf16x8 pa = *(const bf16x8*)&psw[ps_q + ((tblk ^ (l15 & 7)) << 3)];
        #pragma unroll
        for (int di = 0; di < 2; ++di)
          o[di] = __builtin_amdgcn_mfma_f32_16x16x32_bf16(pa, vb2[ksp][di], o[di], 0, 0, 0);
      }
      __builtin_amdgcn_s_setprio(0);
    }
    __syncthreads();
    cur ^= 1;
  }

  // normalized store, swizzled bf16 [8192][256]
  #pragma unroll
  for (int r = 0; r < 4; ++r) {
    float lr = __shfl(l_, g * 4 + r);
    float inv = __builtin_amdgcn_rcpf(lr);
    size_t row = (size_t)b * SEQ + q0 + w * 16 + g * 4 + r;
    int rw7 = (g * 4 + r) & 7;
    #pragma unroll
    for (int di = 0; di < 2; ++di) {
      int col = h * 32 + di * 16 + l15;
      att[row * 256 + swz(col, rw7)] = f2bf(o[di][r] * inv);
    }
  }
}

extern "C" void kernel_launch(void* const* d_in, const int* in_sizes, int n_in,
                              void* d_out, int out_size, void* d_ws, size_t ws_size,
                              hipStream_t stream)
{
  const float* x    = (const float*)d_in[0];
  const float* y    = (const float*)d_in[1];
  const float* Wqkv = (const float*)d_in[3];
  const float* bqkv = (const float*)d_in[4];
  const float* Wo   = (const float*)d_in[5];
  const float* bo   = (const float*)d_in[6];
  const float* W1   = (const float*)d_in[7];
  const float* b1   = (const float*)d_in[8];
  const float* W2   = (const float*)d_in[9];
  const float* b2   = (const float*)d_in[10];
  const float* g1   = (const float*)d_in[11];
  const float* be1  = (const float*)d_in[12];
  const float* g2   = (const float*)d_in[13];
  const float* be2  = (const float*)d_in[14];

  float* ws = (float*)d_ws;
  ushort* f_bf   = (ushort*)(ws);                 // [0, 1M) floats: swizzled bf16
  ushort* qkv_bf = (ushort*)(ws + 1048576);       // [1M, 4M): Q(scaled),K linear
  ushort* vt_g   = (ushort*)(ws + 4194304);       // [4M, 5M): vt[bh][32][1024] swizzled
  ushort* att_bf = (ushort*)(ws + 5242880);       // [5M, 6M) swizzled
  ushort* f1_bf  = (ushort*)(ws + 6291456);       // [6M, 7M) swizzled
  ushort* h_bf   = (ushort*)(ws + 7340032);       // [7M, 11M) swizzled
  float*  pos    = ws + 11534336;                 // [11M, +8K) distinct-value table
  ushort* wq_bf  = (ushort*)(ws + 12582912);
  ushort* wo_bf  = wq_bf + 196608;
  ushort* w1_bf  = wo_bf + 65536;
  ushort* w2_bf  = w1_bf + 262144;

  prep_kernel<<<1024, 256, 0, stream>>>(Wqkv, Wo, W1, W2, wq_bf, wo_bf, w1_bf, w2_bf, pos);
  build_f_kernel<<<512, 256, 0, stream>>>(x, y, pos, f_bf);
  gemm_mfma_kernel<64, 3, 0><<<dim3(6, 128), 256, 0, stream>>>(
      f_bf, wq_bf, bqkv, qkv_bf, vt_g, NROWS, 768, 256);
  attn_mfma_kernel<<<dim3(64, 8), 512, 0, stream>>>(qkv_bf, vt_g, att_bf);
  gemm_ln_kernel<16, 0><<<512, 512, 0, stream>>>(att_bf, wo_bf, bo, f_bf, g1, be1, nullptr, f1_bf, 256);
  gemm_mfma_kernel<64, 2, 1><<<dim3(8, 128), 256, 0, stream>>>(
      f1_bf, w1_bf, b1, h_bf, nullptr, NROWS, 1024, 256);
  gemm_ln_kernel<16, 1><<<512, 512, 0, stream>>>(h_bf, w2_bf, b2, f1_bf, g2, be2, (float*)d_out, nullptr, 1024);
}

// Round 22
// 82.221 us; speedup vs baseline: 1.3241x; 1.0333x over previous
//
#include <hip/hip_runtime.h>

typedef __attribute__((ext_vector_type(8))) short bf16x8;
typedef __attribute__((ext_vector_type(4))) float f32x4;

#define D_MODEL 256
#define SEQ     1024
#define NROWS   8192

__device__ __forceinline__ ushort f2bf(float f) {
  unsigned u = __float_as_uint(f);
  unsigned r = (u + 0x7FFFu + ((u >> 16) & 1u)) >> 16;
  return (ushort)r;
}
__device__ __forceinline__ float bf2f(ushort b) {
  return __uint_as_float(((unsigned)b) << 16);
}

// async global->LDS, 16B per lane; dst = wave-uniform base + lane*16
__device__ __forceinline__ void gld_lds16(const void* g, void* l) {
  __builtin_amdgcn_global_load_lds(
      (const __attribute__((address_space(1))) void*)g,
      (__attribute__((address_space(3))) void*)l, 16, 0, 0);
}

// XOR-swizzle of 8-element blocks within 64-col groups
__device__ __forceinline__ int swz(int col, int row7) {
  return (col & ~63) | ((((col >> 3) & 7) ^ row7) << 3) | (col & 7);
}

#define QSC 0.25507964954389985f   // log2(e) / sqrt(32)

// -------- 0. prep+build fused: blocks [0,1024) convert weights; [1024,1536) build f --------
// build_f computes pos inline: c<128 -> hw = s>>5 is constant per thread's 16-run
// (one sincos); c>=128 -> hw = s&31 increments by 1 (sincos + angle-addition recurrence).
__global__ __launch_bounds__(256) void prep_build_kernel(
    const float* __restrict__ wa, const float* __restrict__ wb,
    const float* __restrict__ wc, const float* __restrict__ wd,
    ushort* __restrict__ oa, ushort* __restrict__ ob,
    ushort* __restrict__ oc, ushort* __restrict__ od,
    const float* __restrict__ x, const float* __restrict__ y,
    ushort* __restrict__ fb)
{
  __shared__ float T[64][65];
  int bxr = blockIdx.x;
  if (bxr < 1024) {
    int i = bxr * 256 + threadIdx.x;  // 262144 total
    if (i < 196608) { int r = i >> 8, k = i & 255; oa[(r << 8) + swz(k, r & 7)] = f2bf(wa[i]); }
    if (i <  65536) { int r = i >> 8, k = i & 255; ob[(r << 8) + swz(k, r & 7)] = f2bf(wb[i]); }
    { int r = i >> 8,  k = i & 255;  oc[(r << 8)  + swz(k, r & 7)] = f2bf(wc[i]); }
    { int r = i >> 10, k = i & 1023; od[(r << 10) + swz(k, r & 7)] = f2bf(wd[i]); }
    return;
  }
  int bx = bxr - 1024;                  // 8b * 16st * 4ct = 512
  int b = bx >> 6, st = (bx >> 2) & 15, ct = bx & 3;
  const float* src = (b < 4) ? x : y;
  int bb = b & 3;
  int tid = threadIdx.x;
  {
    int sl = tid & 63, c4 = tid >> 6;
    int s = st * 64 + sl;
    #pragma unroll
    for (int k = 0; k < 16; ++k) {
      int cl = c4 * 16 + k;
      T[cl][sl] = src[((size_t)((bb << 8) + ct * 64 + cl) << 10) + s];
    }
  }
  __syncthreads();
  {
    int cl = tid & 63, s4 = tid >> 6;
    int c = ct * 64 + cl;
    const float scb = 6.28318530717958647692f / (32.0f + 1e-6f);
    int j = (c & 127) >> 1;
    float csc = scb * exp2f((float)j * -0.20762050593046014f);  // 10000^(-j/64) * scale
    float pvk[16];
    if (c < 128) {
      int hw = st * 2 + (s4 >> 1);      // s>>5 constant over the 16-run
      float arg = (float)(hw + 1) * csc;
      float v1 = (c & 1) ? cosf(arg) : sinf(arg);
      #pragma unroll
      for (int k = 0; k < 16; ++k) pvk[k] = v1;
    } else {
      int w0 = (s4 * 16) & 31;          // s&31 = w0 + k, no wrap within the run
      float arg0 = (float)(w0 + 1) * csc;
      float sv = sinf(arg0), cv = cosf(arg0);
      float sd = sinf(csc),  cd = cosf(csc);
      #pragma unroll
      for (int k = 0; k < 16; ++k) {
        pvk[k] = (c & 1) ? cv : sv;
        float sn = sv * cd + cv * sd;   // rotate by csc
        float cn = cv * cd - sv * sd;
        sv = sn; cv = cn;
      }
    }
    #pragma unroll
    for (int k = 0; k < 16; ++k) {
      int sl = s4 * 16 + k;
      int s = st * 64 + sl;
      float v = T[cl][sl] + 0.1f * pvk[k];
      size_t row = (size_t)b * 1024 + s;
      fb[row * 256 + swz(c, s & 7)] = f2bf(v);
    }
  }
}

// -------- 2. MFMA GEMM (BN=128), global_load_lds, pre-swizzled inputs --------
// OUT_MODE: 2 = bf16 swizzled, 3 = qkv fused (Q scaled + linear, K linear, V -> vt swizzled)
template<int BM, int OUT_MODE, int RELU>
__global__ __launch_bounds__(256) void gemm_mfma_kernel(
    const ushort* __restrict__ A, const ushort* __restrict__ B,
    const float* __restrict__ bias, void* __restrict__ Cout,
    ushort* __restrict__ Vout, int M, int N, int K)
{
  constexpr int MI = BM / 32;
  __shared__ ushort Asw[BM * 64];
  __shared__ ushort Bsw[128 * 64];
  const int tid = threadIdx.x, lane = tid & 63, w = tid >> 6;
  const int m0 = blockIdx.y * BM, n0 = blockIdx.x * 128;
  const int wm0 = (w & 1) * (BM / 2), wn0 = (w >> 1) * 64;
  const int l15 = lane & 15, g = lane >> 4;
  const int r8 = lane >> 3, s8 = lane & 7;
  f32x4 acc[MI][4];
  #pragma unroll
  for (int i = 0; i < MI; ++i)
    #pragma unroll
    for (int j = 0; j < 4; ++j) acc[i][j] = (f32x4){0.f, 0.f, 0.f, 0.f};

  for (int kt = 0; kt < K; kt += 64) {
    __syncthreads();
    #pragma unroll
    for (int i = 0; i < BM / 32; ++i) {
      int row0 = w * (BM / 4) + i * 8;
      gld_lds16(A + (size_t)(m0 + row0 + r8) * K + kt + s8 * 8, &Asw[row0 * 64]);
    }
    #pragma unroll
    for (int i = 0; i < 4; ++i) {
      int row0 = w * 32 + i * 8;
      gld_lds16(B + (size_t)(n0 + row0 + r8) * K + kt + s8 * 8, &Bsw[row0 * 64]);
    }
    __syncthreads();
    #pragma unroll
    for (int ks = 0; ks < 2; ++ks) {
      bf16x8 af[MI], bfr[4];
      #pragma unroll
      for (int i = 0; i < MI; ++i) {
        int ra = wm0 + i * 16 + l15;
        af[i] = *(const bf16x8*)&Asw[ra * 64 + (((ks * 4 + g) ^ (ra & 7)) * 8)];
      }
      #pragma unroll
      for (int i = 0; i < 4; ++i) {
        int rb = wn0 + i * 16 + l15;
        bfr[i] = *(const bf16x8*)&Bsw[rb * 64 + (((ks * 4 + g) ^ (rb & 7)) * 8)];
      }
      __builtin_amdgcn_s_setprio(1);
      #pragma unroll
      for (int mi = 0; mi < MI; ++mi)
        #pragma unroll
        for (int ni = 0; ni < 4; ++ni)
          acc[mi][ni] = __builtin_amdgcn_mfma_f32_16x16x32_bf16(
              af[mi], bfr[ni], acc[mi][ni], 0, 0, 0);
      __builtin_amdgcn_s_setprio(0);
    }
  }

  float bv[4];
  #pragma unroll
  for (int ni = 0; ni < 4; ++ni) bv[ni] = bias[n0 + wn0 + ni * 16 + l15];
  #pragma unroll
  for (int mi = 0; mi < MI; ++mi)
    #pragma unroll
    for (int ni = 0; ni < 4; ++ni) {
      int n = n0 + wn0 + ni * 16 + l15;
      float qs = (OUT_MODE == 3 && n < 256) ? QSC : 1.0f;   // fold softmax scale into Q
      float v4[4];
      #pragma unroll
      for (int r = 0; r < 4; ++r) {
        float v = acc[mi][ni][r] + bv[ni];
        if (RELU) v = fmaxf(v, 0.0f);
        v4[r] = v * qs;
      }
      int mb = m0 + wm0 + mi * 16 + g * 4;       // first of 4 consecutive rows
      if (OUT_MODE == 3 && n >= 512) {
        // V column -> vt[bh][d][t], 8-block XOR swizzle on t within 64-groups
        int d = (n - 512) & 31, hh = (n - 512) >> 5;
        int bb = mb >> 10, t0 = mb & 1023;
        uint2 val;
        val.x = (unsigned)f2bf(v4[0]) | ((unsigned)f2bf(v4[1]) << 16);
        val.y = (unsigned)f2bf(v4[2]) | ((unsigned)f2bf(v4[3]) << 16);
        size_t idx = ((size_t)(bb * 8 + hh) * 32 + d) * 1024 + (t0 & ~63)
                   + ((((t0 >> 3) & 7) ^ (d & 7)) * 8) + (t0 & 7);
        *(uint2*)&Vout[idx] = val;
      } else {
        #pragma unroll
        for (int r = 0; r < 4; ++r) {
          size_t m = mb + r;
          if (OUT_MODE == 3) ((ushort*)Cout)[m * N + n] = f2bf(v4[r]);
          else               ((ushort*)Cout)[m * N + swz(n, (int)(m & 7))] = f2bf(v4[r]);
        }
      }
    }
}

// -------- 2b. GEMM (BM rows, BN=256=N) + fused residual + LayerNorm, 8 waves --------
// TRANS_OUT=0: outb = bf16 swizzled.  TRANS_OUT=1: transposed f32 d_out (coalesced via LDS).
template<int BM, int TRANS_OUT>
__global__ __launch_bounds__(512) void gemm_ln_kernel(
    const ushort* __restrict__ A, const ushort* __restrict__ B,
    const float* __restrict__ bias, const ushort* __restrict__ R,
    const float* __restrict__ gamma, const float* __restrict__ beta,
    float* __restrict__ out, ushort* __restrict__ outb, int K)
{
  constexpr int MI = BM / 16;          // m-frags (16 rows each)
  __shared__ ushort Asw[BM * 64];
  __shared__ ushort Bsw[256 * 64];     // 32 KB; reused as f32 transpose tile in epilogue
  __shared__ float red[8][BM][2];
  const int tid = threadIdx.x, lane = tid & 63, w = tid >> 6;   // w 0..7
  const int l15 = lane & 15, g4 = lane >> 4;
  const int r8 = lane >> 3, s8 = lane & 7;
  const int m0 = blockIdx.x * BM;
  const int wn0 = w * 32;
  f32x4 acc[MI][2];
  #pragma unroll
  for (int i = 0; i < MI; ++i)
    #pragma unroll
    for (int j = 0; j < 2; ++j) acc[i][j] = (f32x4){0.f, 0.f, 0.f, 0.f};

  for (int kt = 0; kt < K; kt += 64) {
    __syncthreads();
    if (w < BM / 8)
      gld_lds16(A + (size_t)(m0 + w * 8 + r8) * K + kt + s8 * 8, &Asw[(w * 8) * 64]);
    #pragma unroll
    for (int i = 0; i < 4; ++i) {
      int row0 = w * 32 + i * 8;
      gld_lds16(B + (size_t)(row0 + r8) * K + kt + s8 * 8, &Bsw[row0 * 64]);
    }
    __syncthreads();
    #pragma unroll
    for (int ks = 0; ks < 2; ++ks) {
      bf16x8 af[MI], bfr[2];
      #pragma unroll
      for (int mi = 0; mi < MI; ++mi) {
        int ra = mi * 16 + l15;
        af[mi] = *(const bf16x8*)&Asw[ra * 64 + (((ks * 4 + g4) ^ (ra & 7)) * 8)];
      }
      #pragma unroll
      for (int ni = 0; ni < 2; ++ni) {
        int rb = wn0 + ni * 16 + l15;
        bfr[ni] = *(const bf16x8*)&Bsw[rb * 64 + (((ks * 4 + g4) ^ (rb & 7)) * 8)];
      }
      __builtin_amdgcn_s_setprio(1);
      #pragma unroll
      for (int mi = 0; mi < MI; ++mi)
        #pragma unroll
        for (int ni = 0; ni < 2; ++ni)
          acc[mi][ni] = __builtin_amdgcn_mfma_f32_16x16x32_bf16(
              af[mi], bfr[ni], acc[mi][ni], 0, 0, 0);
      __builtin_amdgcn_s_setprio(0);
    }
  }

  float bv[2], gv[2], bev[2];
  #pragma unroll
  for (int ni = 0; ni < 2; ++ni) {
    int n = wn0 + ni * 16 + l15;
    bv[ni] = bias[n]; gv[ni] = gamma[n]; bev[ni] = beta[n];
  }
  float s1[MI][4], s2[MI][4];
  #pragma unroll
  for (int mi = 0; mi < MI; ++mi)
    #pragma unroll
    for (int r = 0; r < 4; ++r) { s1[mi][r] = 0.f; s2[mi][r] = 0.f; }
  #pragma unroll
  for (int mi = 0; mi < MI; ++mi)
    #pragma unroll
    for (int ni = 0; ni < 2; ++ni)
      #pragma unroll
      for (int r = 0; r < 4; ++r) {
        int row = m0 + mi * 16 + g4 * 4 + r;
        int col = wn0 + ni * 16 + l15;
        float v = acc[mi][ni][r] + bv[ni] + bf2f(R[(size_t)row * 256 + swz(col, row & 7)]);
        acc[mi][ni][r] = v;
        s1[mi][r] += v;
        s2[mi][r] += v * v;
      }
  #pragma unroll
  for (int mi = 0; mi < MI; ++mi)
    #pragma unroll
    for (int r = 0; r < 4; ++r) {
      #pragma unroll
      for (int d = 1; d < 16; d <<= 1) {
        s1[mi][r] += __shfl_xor(s1[mi][r], d);
        s2[mi][r] += __shfl_xor(s2[mi][r], d);
      }
    }
  if (l15 == 0) {
    #pragma unroll
    for (int mi = 0; mi < MI; ++mi)
      #pragma unroll
      for (int r = 0; r < 4; ++r) {
        int rl = mi * 16 + g4 * 4 + r;
        red[w][rl][0] = s1[mi][r];
        red[w][rl][1] = s2[mi][r];
      }
  }
  __syncthreads();     // also guards Bsw reuse below (all K-loop reads done)
  float* Tr = (float*)Bsw;
  #pragma unroll
  for (int mi = 0; mi < MI; ++mi)
    #pragma unroll
    for (int r = 0; r < 4; ++r) {
      int rl = mi * 16 + g4 * 4 + r;
      float t1 = 0.f, t2 = 0.f;
      #pragma unroll
      for (int ww = 0; ww < 8; ++ww) { t1 += red[ww][rl][0]; t2 += red[ww][rl][1]; }
      float mu = t1 * (1.0f / 256.0f);
      float var = t2 * (1.0f / 256.0f) - mu * mu;
      float rstd = rsqrtf(var + 1e-5f);
      int row = m0 + rl;
      #pragma unroll
      for (int ni = 0; ni < 2; ++ni) {
        int col = wn0 + ni * 16 + l15;
        float res = (acc[mi][ni][r] - mu) * rstd * gv[ni] + bev[ni];
        if (!TRANS_OUT) {
          outb[(size_t)row * 256 + swz(col, row & 7)] = f2bf(res);
        } else {
          Tr[rl * 256 + col] = res;
        }
      }
    }
  if (TRANS_OUT) {
    __syncthreads();
    int b = m0 >> 10, sq0 = m0 & 1023;
    int c = tid & 255, half = tid >> 8;
    float* dst = out + ((size_t)b << 18) + ((size_t)c << 10) + sq0 + half * (BM / 2);
    #pragma unroll
    for (int st = 0; st < BM / 8; ++st) {
      float4 v;
      v.x = Tr[(half * (BM / 2) + st * 4 + 0) * 256 + c];
      v.y = Tr[(half * (BM / 2) + st * 4 + 1) * 256 + c];
      v.z = Tr[(half * (BM / 2) + st * 4 + 2) * 256 + c];
      v.w = Tr[(half * (BM / 2) + st * 4 + 3) * 256 + c];
      *(float4*)(dst + st * 4) = v;
    }
  }
}

// -------- 3. MFMA flash attention: 8 waves, 128 q-rows, KVBLK=128, per-tile reduce --------
// Grid (bh, qt): all qt-blocks of one (b,h) map to the same XCD (linear id mod 8 = h)
// -> K/V fetched once per L2 instead of 8x.  launch_bounds(512,2): no-spill budget.
__global__ __launch_bounds__(512, 2) void attn_mfma_kernel(
    const ushort* __restrict__ qkv, const ushort* __restrict__ vtg,
    ushort* __restrict__ att)
{
  __shared__ ushort Ks[2][64 * 64];    // 16 KB: [64 r2][64] view of 128 K rows
  __shared__ ushort Vt[2][32 * 128];   // 16 KB
  __shared__ ushort Ps[8][16 * 64];    // 16 KB: per-wave [q=16][t'=64], tblk XOR swizzle
  const int tid = threadIdx.x, lane = tid & 63, w = tid >> 6;   // w 0..7
  const int l15 = lane & 15, g = lane >> 4;
  const int bh = blockIdx.x, qt = blockIdx.y;
  const int b = bh >> 3, h = bh & 7;
  const size_t base = (size_t)b * SEQ * 768;
  const int q0 = qt * 128;

  // Q fragment (pre-scaled by log2e/sqrt(32) in the QKV epilogue)
  bf16x8 qf = *(const bf16x8*)&qkv[base + (size_t)(q0 + w * 16 + l15) * 768 + h * 32 + g * 8];

  // K staging lane map (wave w stages K rows w*16..w*16+15): [r2][slot], slot'=slot^(r2&7)
  const int kr2l  = lane >> 3;
  const int kslot = (lane & 7) ^ kr2l;
  const int krow  = 2 * kr2l + (kslot >> 2);
  const int kdoff = (kslot & 3) * 8;
  const int vd    = lane >> 4;          // V: wave w stages d-rows w*4 + vd
  const int vt8   = (lane & 15) * 8;    // V: t offset

  float l_ = 0.f;
  f32x4 o[2];
  o[0] = (f32x4){0.f, 0.f, 0.f, 0.f};
  o[1] = (f32x4){0.f, 0.f, 0.f, 0.f};
  const f32x4 zero = (f32x4){0.f, 0.f, 0.f, 0.f};

  // Ps addresses (q = l15); write: tblk = 2*tt + (g>>1), dword slot (g&1)
  ushort* psw = &Ps[w][0];
  const int ps_q = l15 * 64;

  // stage tile 0 (each wave: 1 K-gld + 1 V-gld)
  gld_lds16(qkv + base + (size_t)(w * 16 + krow) * 768 + 256 + h * 32 + kdoff,
            &Ks[0][(w * 8) * 64]);
  gld_lds16(vtg + ((size_t)bh * 32 + w * 4 + vd) * 1024 + vt8,
            &Vt[0][(w * 4) * 128]);
  __syncthreads();

  int cur = 0;
  for (int t = 0; t < 8; ++t) {
    if (t < 7) {                         // prefetch next 128-row K/V tile
      int nkv = (t + 1) * 128;
      gld_lds16(qkv + base + (size_t)(nkv + w * 16 + krow) * 768 + 256 + h * 32 + kdoff,
                &Ks[cur ^ 1][(w * 8) * 64]);
      gld_lds16(vtg + ((size_t)bh * 32 + w * 4 + vd) * 1024 + nkv + vt8,
                &Vt[cur ^ 1][(w * 4) * 128]);
    }
    // S^T = K . Q^T : lane owns q = l15, t-rows ti*16 + g*4 + r, ti 0..7
    f32x4 s[8];
    __builtin_amdgcn_s_setprio(1);
    #pragma unroll
    for (int ti = 0; ti < 8; ++ti) {
      int r2   = ti * 8 + (l15 >> 1);
      int slot = (((l15 & 1) * 4 + g)) ^ (l15 >> 1);
      bf16x8 kf = *(const bf16x8*)&Ks[cur][r2 * 64 + slot * 8];
      s[ti] = __builtin_amdgcn_mfma_f32_16x16x32_bf16(kf, qf, zero, 0, 0, 0);
    }
    __builtin_amdgcn_s_setprio(0);

    // no-max softmax: scores log2-scaled, |s| << 127 -> exp2 cannot overflow.
    // 4 independent accumulators (dep chain 32 -> 8); per-tile reduce kept (r14).
    float rsA[4] = {0.f, 0.f, 0.f, 0.f};
    #pragma unroll
    for (int ti = 0; ti < 8; ++ti)
      #pragma unroll
      for (int r = 0; r < 4; ++r) {
        float p = __builtin_amdgcn_exp2f(s[ti][r]);
        s[ti][r] = p;
        rsA[r] += p;
      }
    float rs = (rsA[0] + rsA[1]) + (rsA[2] + rsA[3]);
    rs += __shfl_xor(rs, 16);
    rs += __shfl_xor(rs, 32);
    l_ += rs;

    // two half-passes over t: pack P -> wave-private swizzled LDS -> b128 A-frags;
    // V fragments loaded per-pass (live-range cut)
    #pragma unroll
    for (int p = 0; p < 2; ++p) {
      #pragma unroll
      for (int tt = 0; tt < 4; ++tt) {
        int ti = p * 4 + tt;
        unsigned lo, hi;
        asm("v_cvt_pk_bf16_f32 %0, %1, %2" : "=v"(lo) : "v"(s[ti][0]), "v"(s[ti][1]));
        asm("v_cvt_pk_bf16_f32 %0, %1, %2" : "=v"(hi) : "v"(s[ti][2]), "v"(s[ti][3]));
        uint2 val; val.x = lo; val.y = hi;
        int tblk = 2 * tt + (g >> 1);
        *(uint2*)&psw[ps_q + ((tblk ^ (l15 & 7)) << 3) + ((g & 1) << 2)] = val;
      }
      bf16x8 vb2[2][2];
      #pragma unroll
      for (int ksp = 0; ksp < 2; ++ksp)
        #pragma unroll
        for (int di = 0; di < 2; ++di) {
          int d = di * 16 + l15;
          vb2[ksp][di] = *(const bf16x8*)&Vt[cur][d * 128 + p * 64 +
                                                 (((ksp * 4 + g) ^ (d & 7)) * 8)];
        }
      __builtin_amdgcn_s_setprio(1);
      #pragma unroll
      for (int ksp = 0; ksp < 2; ++ksp) {
        int tblk = 4 * ksp + g;
        bf16x8 pa = *(const bf16x8*)&psw[ps_q + ((tblk ^ (l15 & 7)) << 3)];
        #pragma unroll
        for (int di = 0; di < 2; ++di)
          o[di] = __builtin_amdgcn_mfma_f32_16x16x32_bf16(pa, vb2[ksp][di], o[di], 0, 0, 0);
      }
      __builtin_amdgcn_s_setprio(0);
    }
    __syncthreads();
    cur ^= 1;
  }

  // normalized store, swizzled bf16 [8192][256]
  #pragma unroll
  for (int r = 0; r < 4; ++r) {
    float lr = __shfl(l_, g * 4 + r);
    float inv = __builtin_amdgcn_rcpf(lr);
    size_t row = (size_t)b * SEQ + q0 + w * 16 + g * 4 + r;
    int rw7 = (g * 4 + r) & 7;
    #pragma unroll
    for (int di = 0; di < 2; ++di) {
      int col = h * 32 + di * 16 + l15;
      att[row * 256 + swz(col, rw7)] = f2bf(o[di][r] * inv);
    }
  }
}

extern "C" void kernel_launch(void* const* d_in, const int* in_sizes, int n_in,
                              void* d_out, int out_size, void* d_ws, size_t ws_size,
                              hipStream_t stream)
{
  const float* x    = (const float*)d_in[0];
  const float* y    = (const float*)d_in[1];
  const float* Wqkv = (const float*)d_in[3];
  const float* bqkv = (const float*)d_in[4];
  const float* Wo   = (const float*)d_in[5];
  const float* bo   = (const float*)d_in[6];
  const float* W1   = (const float*)d_in[7];
  const float* b1   = (const float*)d_in[8];
  const float* W2   = (const float*)d_in[9];
  const float* b2   = (const float*)d_in[10];
  const float* g1   = (const float*)d_in[11];
  const float* be1  = (const float*)d_in[12];
  const float* g2   = (const float*)d_in[13];
  const float* be2  = (const float*)d_in[14];

  float* ws = (float*)d_ws;
  ushort* f_bf   = (ushort*)(ws);                 // [0, 1M) floats: swizzled bf16
  ushort* qkv_bf = (ushort*)(ws + 1048576);       // [1M, 4M): Q(scaled),K linear
  ushort* vt_g   = (ushort*)(ws + 4194304);       // [4M, 5M): vt[bh][32][1024] swizzled
  ushort* att_bf = (ushort*)(ws + 5242880);       // [5M, 6M) swizzled
  ushort* f1_bf  = (ushort*)(ws + 6291456);       // [6M, 7M) swizzled
  ushort* h_bf   = (ushort*)(ws + 7340032);       // [7M, 11M) swizzled
  ushort* wq_bf  = (ushort*)(ws + 12582912);
  ushort* wo_bf  = wq_bf + 196608;
  ushort* w1_bf  = wo_bf + 65536;
  ushort* w2_bf  = w1_bf + 262144;

  prep_build_kernel<<<1536, 256, 0, stream>>>(
      Wqkv, Wo, W1, W2, wq_bf, wo_bf, w1_bf, w2_bf, x, y, f_bf);
  gemm_mfma_kernel<64, 3, 0><<<dim3(6, 128), 256, 0, stream>>>(
      f_bf, wq_bf, bqkv, qkv_bf, vt_g, NROWS, 768, 256);
  attn_mfma_kernel<<<dim3(64, 8), 512, 0, stream>>>(qkv_bf, vt_g, att_bf);
  gemm_ln_kernel<16, 0><<<512, 512, 0, stream>>>(att_bf, wo_bf, bo, f_bf, g1, be1, nullptr, f1_bf, 256);
  gemm_mfma_kernel<64, 2, 1><<<dim3(8, 128), 256, 0, stream>>>(
      f1_bf, w1_bf, b1, h_bf, nullptr, NROWS, 1024, 256);
  gemm_ln_kernel<16, 1><<<512, 512, 0, stream>>>(h_bf, w2_bf, b2, f1_bf, g2, be2, (float*)d_out, nullptr, 1024);
}